// Round 1
// baseline (119.704 us; speedup 1.0000x reference)
//
#include <hip/hip_runtime.h>
#include <stdint.h>

#define B_ 8
#define L_ 1024
#define DM 512
#define H_ 8
#define HD 64
#define N3 1536
#define M_T (B_*L_)        // 8192

typedef __attribute__((ext_vector_type(8))) short short8;    // 8 x bf16 (4 VGPRs)
typedef __attribute__((ext_vector_type(4))) float f32x4;
typedef __attribute__((ext_vector_type(4))) float float4_t;
typedef __attribute__((ext_vector_type(4))) unsigned short ushort4_t;

#define MFMA16(a,b,c) __builtin_amdgcn_mfma_f32_16x16x32_bf16((a),(b),(c),0,0,0)

__device__ __forceinline__ short f2bf(float f){
  union { float f; unsigned u; } v; v.f = f;
  unsigned r = v.u + 0x7fffu + ((v.u >> 16) & 1u);   // RNE
  return (short)(r >> 16);
}

// ---------------- x fp32 -> bf16 (vectorized) ----------------
__global__ __launch_bounds__(256) void k_cvt(const float* __restrict__ x,
                                             short* __restrict__ xb, int n8){
  int i = blockIdx.x*256 + threadIdx.x;
  if (i >= n8) return;
  const float4_t* p = (const float4_t*)x + (size_t)i*2;
  float4_t a = p[0], b = p[1];
  short8 o;
  o[0]=f2bf(a[0]); o[1]=f2bf(a[1]); o[2]=f2bf(a[2]); o[3]=f2bf(a[3]);
  o[4]=f2bf(b[0]); o[5]=f2bf(b[1]); o[6]=f2bf(b[2]); o[7]=f2bf(b[3]);
  *((short8*)xb + i) = o;
}

// ---------------- W [K][N] fp32 -> WT [N][K] bf16 ----------------
__global__ __launch_bounds__(256) void k_tr(const float* __restrict__ W,
                                            short* __restrict__ WT, int K, int N){
  __shared__ float t[64][65];
  int n0 = blockIdx.x*64, k0 = blockIdx.y*64;
  int tid = threadIdx.x;
  int r = tid >> 4, c4 = (tid & 15) * 4;
  #pragma unroll
  for (int it=0; it<4; ++it){
    int rr = r + it*16;
    float4_t v = *(const float4_t*)(W + (size_t)(k0+rr)*N + n0 + c4);
    t[rr][c4+0]=v[0]; t[rr][c4+1]=v[1]; t[rr][c4+2]=v[2]; t[rr][c4+3]=v[3];
  }
  __syncthreads();
  #pragma unroll
  for (int it=0; it<4; ++it){
    int n = r + it*16;
    ushort4_t o;
    o[0]=(unsigned short)f2bf(t[c4+0][n]);
    o[1]=(unsigned short)f2bf(t[c4+1][n]);
    o[2]=(unsigned short)f2bf(t[c4+2][n]);
    o[3]=(unsigned short)f2bf(t[c4+3][n]);
    *(ushort4_t*)(WT + (size_t)(n0+n)*K + k0 + c4) = o;
  }
}

// ---------------- GEMM1: xb[8192,512] @ WqkvT[1536,512]^T + bqkv -> scatter Q/K/VT bf16 ----------------
__global__ __launch_bounds__(256) void k_gemm_qkv(
    const short* __restrict__ A, const short* __restrict__ Bt,
    const float* __restrict__ bias,
    short* __restrict__ Qo, short* __restrict__ Ko, short* __restrict__ VTo)
{
  __shared__ __align__(16) short As[2][128*40];
  __shared__ __align__(16) short Bs[2][128*40];
  const int m0 = blockIdx.x*128, n0 = blockIdx.y*128;
  const int tid = threadIdx.x;
  const int w = tid>>6, lane = tid&63, li = lane&15, lg = lane>>4;
  const int wr = (w>>1)*64, wc = (w&1)*64;

  int row[2], seg[2];
  #pragma unroll
  for (int c=0;c<2;++c){ int s = tid + c*256; row[c]=s>>2; seg[c]=s&3; }

  short8 ga[2], gb[2];
  #pragma unroll
  for (int c=0;c<2;++c){
    ga[c] = *(const short8*)(A  + (size_t)(m0+row[c])*DM + seg[c]*8);
    gb[c] = *(const short8*)(Bt + (size_t)(n0+row[c])*DM + seg[c]*8);
  }

  const f32x4 fz = {0.f,0.f,0.f,0.f};
  f32x4 acc[4][4];
  #pragma unroll
  for (int i=0;i<4;++i)
    #pragma unroll
    for (int j=0;j<4;++j) acc[i][j] = fz;

  for (int kt=0; kt<16; ++kt){
    short* as = As[kt&1]; short* bs = Bs[kt&1];
    #pragma unroll
    for (int c=0;c<2;++c){
      *(short8*)&as[row[c]*40 + seg[c]*8] = ga[c];
      *(short8*)&bs[row[c]*40 + seg[c]*8] = gb[c];
    }
    __syncthreads();
    if (kt < 15){
      int k0 = (kt+1)*32;
      #pragma unroll
      for (int c=0;c<2;++c){
        ga[c] = *(const short8*)(A  + (size_t)(m0+row[c])*DM + k0 + seg[c]*8);
        gb[c] = *(const short8*)(Bt + (size_t)(n0+row[c])*DM + k0 + seg[c]*8);
      }
    }
    short8 bfr[4];
    #pragma unroll
    for (int nf=0;nf<4;++nf)
      bfr[nf] = *(const short8*)&bs[(wc + nf*16 + li)*40 + lg*8];
    #pragma unroll
    for (int mf=0;mf<4;++mf){
      short8 af = *(const short8*)&as[(wr + mf*16 + li)*40 + lg*8];
      #pragma unroll
      for (int nf=0;nf<4;++nf)
        acc[mf][nf] = MFMA16(af, bfr[nf], acc[mf][nf]);
    }
    __syncthreads();
  }

  // epilogue: col n -> head h = n/192; within: [0,64)=Q, [64,128)=K, [128,192)=V(transposed store)
  #pragma unroll
  for (int nf=0;nf<4;++nf){
    int n = n0 + wc + nf*16 + li;
    float bv = bias[n];
    unsigned h  = (unsigned)n / 192u;
    unsigned wn = (unsigned)n % 192u;
    unsigned typ = wn >> 6, d = wn & 63u;
    #pragma unroll
    for (int mf=0;mf<4;++mf){
      #pragma unroll
      for (int j=0;j<4;++j){
        int m  = m0 + wr + mf*16 + lg*4 + j;
        int b  = m >> 10, lp = m & 1023;
        size_t bh = (size_t)(b*8 + (int)h);
        short val = f2bf(acc[mf][nf][j] + bv);
        if (typ == 0)      Qo [(bh<<16) + ((size_t)lp<<6)  + d]  = val;
        else if (typ == 1) Ko [(bh<<16) + ((size_t)lp<<6)  + d]  = val;
        else               VTo[(bh<<16) + ((size_t)d<<10)  + lp] = val;
      }
    }
  }
}

// ---------------- flash attention: per (bh, q-tile of 64); 4 waves x 16 q-rows ----------------
__global__ __launch_bounds__(256) void k_attn(
    const short* __restrict__ Q, const short* __restrict__ Kb,
    const short* __restrict__ VT, const float* __restrict__ mask,
    short* __restrict__ O2)
{
  __shared__ __align__(16) short Ks[64*72];
  __shared__ __align__(16) short Vs[64*72];
  __shared__ __align__(16) short Ps[4][16*72];
  const int bh = blockIdx.y;
  const int q0 = blockIdx.x*64;
  const int tid = threadIdx.x, w = tid>>6, lane = tid&63, li = lane&15, lg = lane>>4;
  const int qw = q0 + w*16;

  const short* Qp = Q  + ((size_t)bh<<16);
  const short* Kp = Kb + ((size_t)bh<<16);
  const short* Vp = VT + ((size_t)bh<<16);

  // Q fragments in registers (A-operand: row=li, k=d)
  short8 qf[2];
  #pragma unroll
  for (int t=0;t<2;++t)
    qf[t] = *(const short8*)(Qp + ((size_t)(qw+li)<<6) + t*32 + lg*8);

  const f32x4 fz = {0.f,0.f,0.f,0.f};
  f32x4 o[4];
  #pragma unroll
  for (int df=0;df<4;++df) o[df] = fz;
  float mrow[4] = {-1e30f,-1e30f,-1e30f,-1e30f};
  float lrow[4] = {0.f,0.f,0.f,0.f};

  int srow[2], sseg[2];
  #pragma unroll
  for (int c=0;c<2;++c){ int s = tid + c*256; srow[c]=s>>3; sseg[c]=s&7; }

  short8 gk[2], gv[2];
  #pragma unroll
  for (int c=0;c<2;++c){
    gk[c] = *(const short8*)(Kp + ((size_t)srow[c]<<6)  + sseg[c]*8);
    gv[c] = *(const short8*)(Vp + ((size_t)srow[c]<<10) + sseg[c]*8);
  }

  const float* mbase = mask + (size_t)(qw + lg*4)*1024 + li;

  for (int kv0=0; kv0<1024; kv0+=64){
    #pragma unroll
    for (int c=0;c<2;++c){
      *(short8*)&Ks[srow[c]*72 + sseg[c]*8] = gk[c];
      *(short8*)&Vs[srow[c]*72 + sseg[c]*8] = gv[c];
    }
    __syncthreads();
    if (kv0 < 960){
      int nx = kv0 + 64;
      #pragma unroll
      for (int c=0;c<2;++c){
        gk[c] = *(const short8*)(Kp + ((size_t)(nx+srow[c])<<6)  + sseg[c]*8);
        gv[c] = *(const short8*)(Vp + ((size_t)srow[c]<<10) + nx + sseg[c]*8);
      }
    }
    // mask prefetch (row = qw+lg*4+j, col = kv0+nf*16+li)
    float mk[4][4];
    #pragma unroll
    for (int nf=0;nf<4;++nf)
      #pragma unroll
      for (int j=0;j<4;++j)
        mk[nf][j] = mbase[(size_t)j*1024 + kv0 + nf*16];

    // QK^T: S[16q x 64kv]
    f32x4 s[4];
    #pragma unroll
    for (int nf=0;nf<4;++nf){
      s[nf] = fz;
      #pragma unroll
      for (int t=0;t<2;++t){
        short8 kf = *(const short8*)&Ks[(nf*16+li)*72 + t*32 + lg*8];
        s[nf] = MFMA16(qf[t], kf, s[nf]);
      }
    }
    // online softmax (rows = q live in j; cols spread over li & nf)
    float pv[4][4], rmax[4];
    #pragma unroll
    for (int j=0;j<4;++j) rmax[j] = -1e30f;
    #pragma unroll
    for (int nf=0;nf<4;++nf)
      #pragma unroll
      for (int j=0;j<4;++j){
        float v = s[nf][j]*0.125f + mk[nf][j];
        pv[nf][j] = v;
        rmax[j] = fmaxf(rmax[j], v);
      }
    #pragma unroll
    for (int off=1; off<16; off<<=1)
      #pragma unroll
      for (int j=0;j<4;++j)
        rmax[j] = fmaxf(rmax[j], __shfl_xor(rmax[j], off, 64));
    float corr[4], rsum[4];
    #pragma unroll
    for (int j=0;j<4;++j){
      float mnew = fmaxf(mrow[j], rmax[j]);
      corr[j] = exp2f((mrow[j]-mnew)*1.44269504f);
      mrow[j] = mnew;
      rsum[j] = 0.f;
    }
    #pragma unroll
    for (int nf=0;nf<4;++nf)
      #pragma unroll
      for (int j=0;j<4;++j){
        float p = exp2f((pv[nf][j]-mrow[j])*1.44269504f);
        pv[nf][j] = p;
        rsum[j] += p;
      }
    #pragma unroll
    for (int off=1; off<16; off<<=1)
      #pragma unroll
      for (int j=0;j<4;++j)
        rsum[j] += __shfl_xor(rsum[j], off, 64);
    #pragma unroll
    for (int j=0;j<4;++j) lrow[j] = lrow[j]*corr[j] + rsum[j];
    #pragma unroll
    for (int df=0;df<4;++df)
      #pragma unroll
      for (int j=0;j<4;++j)
        o[df][j] *= corr[j];

    // P -> per-wave LDS (bf16), re-layout C/D -> A-frag
    short* pw = Ps[w];
    #pragma unroll
    for (int nf=0;nf<4;++nf)
      #pragma unroll
      for (int j=0;j<4;++j)
        pw[(lg*4+j)*72 + nf*16 + li] = f2bf(pv[nf][j]);

    // PV: O[16q x 64d] += P @ V
    #pragma unroll
    for (int t=0;t<2;++t){
      short8 pf = *(const short8*)&pw[li*72 + t*32 + lg*8];
      #pragma unroll
      for (int df=0;df<4;++df){
        short8 vf = *(const short8*)&Vs[(df*16+li)*72 + t*32 + lg*8];
        o[df] = MFMA16(pf, vf, o[df]);
      }
    }
    __syncthreads();
  }

  // epilogue: O2[b, l, h*64+d] bf16
  int b = bh >> 3, h = bh & 7;
  #pragma unroll
  for (int df=0;df<4;++df)
    #pragma unroll
    for (int j=0;j<4;++j){
      int m   = b*1024 + qw + lg*4 + j;
      int col = h*64 + df*16 + li;
      float vv = o[df][j] / lrow[j];
      O2[(size_t)m*512 + col] = f2bf(vv);
    }
}

// ---------------- GEMM2: O2[8192,512] @ WoT[512,512]^T + bo -> out fp32 ----------------
__global__ __launch_bounds__(256) void k_gemm_out(
    const short* __restrict__ A, const short* __restrict__ Bt,
    const float* __restrict__ bias, float* __restrict__ out)
{
  __shared__ __align__(16) short As[2][128*40];
  __shared__ __align__(16) short Bs[2][128*40];
  const int m0 = blockIdx.x*128, n0 = blockIdx.y*128;
  const int tid = threadIdx.x;
  const int w = tid>>6, lane = tid&63, li = lane&15, lg = lane>>4;
  const int wr = (w>>1)*64, wc = (w&1)*64;

  int row[2], seg[2];
  #pragma unroll
  for (int c=0;c<2;++c){ int s = tid + c*256; row[c]=s>>2; seg[c]=s&3; }

  short8 ga[2], gb[2];
  #pragma unroll
  for (int c=0;c<2;++c){
    ga[c] = *(const short8*)(A  + (size_t)(m0+row[c])*DM + seg[c]*8);
    gb[c] = *(const short8*)(Bt + (size_t)(n0+row[c])*DM + seg[c]*8);
  }

  const f32x4 fz = {0.f,0.f,0.f,0.f};
  f32x4 acc[4][4];
  #pragma unroll
  for (int i=0;i<4;++i)
    #pragma unroll
    for (int j=0;j<4;++j) acc[i][j] = fz;

  for (int kt=0; kt<16; ++kt){
    short* as = As[kt&1]; short* bs = Bs[kt&1];
    #pragma unroll
    for (int c=0;c<2;++c){
      *(short8*)&as[row[c]*40 + seg[c]*8] = ga[c];
      *(short8*)&bs[row[c]*40 + seg[c]*8] = gb[c];
    }
    __syncthreads();
    if (kt < 15){
      int k0 = (kt+1)*32;
      #pragma unroll
      for (int c=0;c<2;++c){
        ga[c] = *(const short8*)(A  + (size_t)(m0+row[c])*DM + k0 + seg[c]*8);
        gb[c] = *(const short8*)(Bt + (size_t)(n0+row[c])*DM + k0 + seg[c]*8);
      }
    }
    short8 bfr[4];
    #pragma unroll
    for (int nf=0;nf<4;++nf)
      bfr[nf] = *(const short8*)&bs[(wc + nf*16 + li)*40 + lg*8];
    #pragma unroll
    for (int mf=0;mf<4;++mf){
      short8 af = *(const short8*)&as[(wr + mf*16 + li)*40 + lg*8];
      #pragma unroll
      for (int nf=0;nf<4;++nf)
        acc[mf][nf] = MFMA16(af, bfr[nf], acc[mf][nf]);
    }
    __syncthreads();
  }

  #pragma unroll
  for (int nf=0;nf<4;++nf){
    int n = n0 + wc + nf*16 + li;
    float bv = bias[n];
    #pragma unroll
    for (int mf=0;mf<4;++mf){
      #pragma unroll
      for (int j=0;j<4;++j){
        int m = m0 + wr + mf*16 + lg*4 + j;
        out[(size_t)m*DM + n] = acc[mf][nf][j] + bv;
      }
    }
  }
}

extern "C" void kernel_launch(void* const* d_in, const int* in_sizes, int n_in,
                              void* d_out, int out_size, void* d_ws, size_t ws_size,
                              hipStream_t stream)
{
  (void)in_sizes; (void)n_in; (void)out_size; (void)ws_size;
  const float* x    = (const float*)d_in[0];
  const float* mask = (const float*)d_in[1];
  const float* Wqkv = (const float*)d_in[2];
  const float* bqkv = (const float*)d_in[3];
  const float* Wo   = (const float*)d_in[4];
  const float* bo   = (const float*)d_in[5];
  float* out = (float*)d_out;

  short* xb    = (short*)d_ws;                    // [8192,512] bf16
  short* WqkvT = xb    + (size_t)M_T*DM;          // [1536,512] bf16
  short* WoT   = WqkvT + (size_t)N3*DM;           // [512,512]  bf16
  short* Qb    = WoT   + (size_t)DM*DM;           // [64][1024][64] bf16
  short* Kbf   = Qb    + (size_t)64*1024*64;      // [64][1024][64] bf16
  short* VTb   = Kbf   + (size_t)64*1024*64;      // [64][64][1024] bf16 (V^T)
  short* O2    = VTb   + (size_t)64*1024*64;      // [8192,512] bf16

  k_cvt<<<2048, 256, 0, stream>>>(x, xb, (M_T*DM)/8);
  k_tr <<<dim3(N3/64, DM/64), 256, 0, stream>>>(Wqkv, WqkvT, DM, N3);
  k_tr <<<dim3(DM/64, DM/64), 256, 0, stream>>>(Wo,   WoT,   DM, DM);
  k_gemm_qkv<<<dim3(M_T/128, N3/128), 256, 0, stream>>>(xb, WqkvT, bqkv, Qb, Kbf, VTb);
  k_attn    <<<dim3(L_/64, B_*H_),    256, 0, stream>>>(Qb, Kbf, VTb, mask, O2);
  k_gemm_out<<<dim3(M_T/128, DM/128), 256, 0, stream>>>(O2, WoT, bo, out);
}

// Round 2
// 102.151 us; speedup vs baseline: 1.1718x; 1.1718x over previous
//
#include <hip/hip_runtime.h>
#include <stdint.h>

#define B_ 8
#define L_ 1024
#define DM 512
#define H_ 8
#define HD 64
#define N3 1536
#define M_T (B_*L_)        // 8192

typedef __attribute__((ext_vector_type(8))) short short8;    // 8 x bf16 (4 VGPRs)
typedef __attribute__((ext_vector_type(4))) float f32x4;
typedef __attribute__((ext_vector_type(4))) float float4_t;
typedef __attribute__((ext_vector_type(4))) unsigned short ushort4_t;

#define MFMA16(a,b,c) __builtin_amdgcn_mfma_f32_16x16x32_bf16((a),(b),(c),0,0,0)

__device__ __forceinline__ short f2bf(float f){
  union { float f; unsigned u; } v; v.f = f;
  unsigned r = v.u + 0x7fffu + ((v.u >> 16) & 1u);   // RNE
  return (short)(r >> 16);
}

// ---------------- x fp32 -> bf16 (vectorized) ----------------
__global__ __launch_bounds__(256) void k_cvt(const float* __restrict__ x,
                                             short* __restrict__ xb, int n8){
  int i = blockIdx.x*256 + threadIdx.x;
  if (i >= n8) return;
  const float4_t* p = (const float4_t*)x + (size_t)i*2;
  float4_t a = p[0], b = p[1];
  short8 o;
  o[0]=f2bf(a[0]); o[1]=f2bf(a[1]); o[2]=f2bf(a[2]); o[3]=f2bf(a[3]);
  o[4]=f2bf(b[0]); o[5]=f2bf(b[1]); o[6]=f2bf(b[2]); o[7]=f2bf(b[3]);
  *((short8*)xb + i) = o;
}

// ---------------- W [K][N] fp32 -> WT [N][K] bf16 ----------------
__global__ __launch_bounds__(256) void k_tr(const float* __restrict__ W,
                                            short* __restrict__ WT, int K, int N){
  __shared__ float t[64][65];
  int n0 = blockIdx.x*64, k0 = blockIdx.y*64;
  int tid = threadIdx.x;
  int r = tid >> 4, c4 = (tid & 15) * 4;
  #pragma unroll
  for (int it=0; it<4; ++it){
    int rr = r + it*16;
    float4_t v = *(const float4_t*)(W + (size_t)(k0+rr)*N + n0 + c4);
    t[rr][c4+0]=v[0]; t[rr][c4+1]=v[1]; t[rr][c4+2]=v[2]; t[rr][c4+3]=v[3];
  }
  __syncthreads();
  #pragma unroll
  for (int it=0; it<4; ++it){
    int n = r + it*16;
    ushort4_t o;
    o[0]=(unsigned short)f2bf(t[c4+0][n]);
    o[1]=(unsigned short)f2bf(t[c4+1][n]);
    o[2]=(unsigned short)f2bf(t[c4+2][n]);
    o[3]=(unsigned short)f2bf(t[c4+3][n]);
    *(ushort4_t*)(WT + (size_t)(n0+n)*K + k0 + c4) = o;
  }
}

// ---------------- GEMM1: xb[8192,512] @ WqkvT[1536,512]^T + bqkv -> scatter Q/K/VT bf16 ----------------
// Q is pre-scaled by 0.125*log2(e) so attention logits come out of MFMA ready for exp2.
__global__ __launch_bounds__(256) void k_gemm_qkv(
    const short* __restrict__ A, const short* __restrict__ Bt,
    const float* __restrict__ bias,
    short* __restrict__ Qo, short* __restrict__ Ko, short* __restrict__ VTo)
{
  __shared__ __align__(16) short As[2][128*40];
  __shared__ __align__(16) short Bs[2][128*40];
  const int m0 = blockIdx.x*128, n0 = blockIdx.y*128;
  const int tid = threadIdx.x;
  const int w = tid>>6, lane = tid&63, li = lane&15, lg = lane>>4;
  const int wr = (w>>1)*64, wc = (w&1)*64;

  int row[2], seg[2];
  #pragma unroll
  for (int c=0;c<2;++c){ int s = tid + c*256; row[c]=s>>2; seg[c]=s&3; }

  short8 ga[2], gb[2];
  #pragma unroll
  for (int c=0;c<2;++c){
    ga[c] = *(const short8*)(A  + (size_t)(m0+row[c])*DM + seg[c]*8);
    gb[c] = *(const short8*)(Bt + (size_t)(n0+row[c])*DM + seg[c]*8);
  }

  const f32x4 fz = {0.f,0.f,0.f,0.f};
  f32x4 acc[4][4];
  #pragma unroll
  for (int i=0;i<4;++i)
    #pragma unroll
    for (int j=0;j<4;++j) acc[i][j] = fz;

  for (int kt=0; kt<16; ++kt){
    short* as = As[kt&1]; short* bs = Bs[kt&1];
    #pragma unroll
    for (int c=0;c<2;++c){
      *(short8*)&as[row[c]*40 + seg[c]*8] = ga[c];
      *(short8*)&bs[row[c]*40 + seg[c]*8] = gb[c];
    }
    __syncthreads();
    if (kt < 15){
      int k0 = (kt+1)*32;
      #pragma unroll
      for (int c=0;c<2;++c){
        ga[c] = *(const short8*)(A  + (size_t)(m0+row[c])*DM + k0 + seg[c]*8);
        gb[c] = *(const short8*)(Bt + (size_t)(n0+row[c])*DM + k0 + seg[c]*8);
      }
    }
    short8 bfr[4];
    #pragma unroll
    for (int nf=0;nf<4;++nf)
      bfr[nf] = *(const short8*)&bs[(wc + nf*16 + li)*40 + lg*8];
    #pragma unroll
    for (int mf=0;mf<4;++mf){
      short8 af = *(const short8*)&as[(wr + mf*16 + li)*40 + lg*8];
      #pragma unroll
      for (int nf=0;nf<4;++nf)
        acc[mf][nf] = MFMA16(af, bfr[nf], acc[mf][nf]);
    }
    __syncthreads();
  }

  // epilogue: col n -> head h = n/192; within: [0,64)=Q, [64,128)=K, [128,192)=V(transposed store)
  #pragma unroll
  for (int nf=0;nf<4;++nf){
    int n = n0 + wc + nf*16 + li;
    float bv = bias[n];
    unsigned h  = (unsigned)n / 192u;
    unsigned wn = (unsigned)n % 192u;
    unsigned typ = wn >> 6, d = wn & 63u;
    #pragma unroll
    for (int mf=0;mf<4;++mf){
      #pragma unroll
      for (int j=0;j<4;++j){
        int m  = m0 + wr + mf*16 + lg*4 + j;
        int b  = m >> 10, lp = m & 1023;
        size_t bh = (size_t)(b*8 + (int)h);
        float vf = acc[mf][nf][j] + bv;
        if (typ == 0)      Qo [(bh<<16) + ((size_t)lp<<6)  + d]  = f2bf(vf * 0.18033688f); // 0.125*log2e
        else if (typ == 1) Ko [(bh<<16) + ((size_t)lp<<6)  + d]  = f2bf(vf);
        else               VTo[(bh<<16) + ((size_t)d<<10)  + lp] = f2bf(vf);
      }
    }
  }
}

// ---------------- flash attention, fixed-max softmax ----------------
// logits (in exp2 domain) = qk*0.125*log2e + mask*log2e - 12*log2e; mask term folded
// into the MFMA C-operand init. p = exp2(s). Row sum via ones-column MFMA.
__global__ __launch_bounds__(256) void k_attn(
    const short* __restrict__ Q, const short* __restrict__ Kb,
    const short* __restrict__ VT, const float* __restrict__ mask,
    short* __restrict__ O2)
{
  __shared__ __align__(16) short Ks[64*72];
  __shared__ __align__(16) short Vs[64*72];
  __shared__ __align__(16) short Ps[4][16*72];
  const int bh = blockIdx.y;
  const int q0 = blockIdx.x*64;
  const int tid = threadIdx.x, w = tid>>6, lane = tid&63, li = lane&15, lg = lane>>4;
  const int qw = q0 + w*16;

  const short* Qp = Q  + ((size_t)bh<<16);
  const short* Kp = Kb + ((size_t)bh<<16);
  const short* Vp = VT + ((size_t)bh<<16);

  // Q fragments in registers (A-operand: row=li, k=d); Q pre-scaled in GEMM1
  short8 qf[2];
  #pragma unroll
  for (int t=0;t<2;++t)
    qf[t] = *(const short8*)(Qp + ((size_t)(qw+li)<<6) + t*32 + lg*8);

  short8 ones8;
  #pragma unroll
  for (int e=0;e<8;++e) ones8[e] = (short)0x3f80;   // bf16 1.0

  const f32x4 fz = {0.f,0.f,0.f,0.f};
  f32x4 o[4], osum = fz;
  #pragma unroll
  for (int df=0;df<4;++df) o[df] = fz;

  int srow[2], sseg[2];
  #pragma unroll
  for (int c=0;c<2;++c){ int s = tid + c*256; srow[c]=s>>3; sseg[c]=s&7; }

  short8 gk[2], gv[2];
  #pragma unroll
  for (int c=0;c<2;++c){
    gk[c] = *(const short8*)(Kp + ((size_t)srow[c]<<6)  + sseg[c]*8);
    gv[c] = *(const short8*)(Vp + ((size_t)srow[c]<<10) + sseg[c]*8);
  }

  const float* mbase = mask + (size_t)(qw + lg*4)*1024 + li;

  for (int kv0=0; kv0<1024; kv0+=64){
    #pragma unroll
    for (int c=0;c<2;++c){
      *(short8*)&Ks[srow[c]*72 + sseg[c]*8] = gk[c];
      *(short8*)&Vs[srow[c]*72 + sseg[c]*8] = gv[c];
    }
    __syncthreads();
    if (kv0 < 960){
      int nx = kv0 + 64;
      #pragma unroll
      for (int c=0;c<2;++c){
        gk[c] = *(const short8*)(Kp + ((size_t)(nx+srow[c])<<6)  + sseg[c]*8);
        gv[c] = *(const short8*)(Vp + ((size_t)srow[c]<<10) + nx + sseg[c]*8);
      }
    }

    // QK^T with mask folded into the accumulator init:
    // s_init[nf][j] = mask[q][kv]*log2e - 17.3123405 (= 12*log2e)
    f32x4 s[4];
    #pragma unroll
    for (int nf=0;nf<4;++nf)
      #pragma unroll
      for (int j=0;j<4;++j)
        s[nf][j] = fmaf(mbase[(size_t)j*1024 + kv0 + nf*16], 1.44269504f, -17.3123405f);

    #pragma unroll
    for (int nf=0;nf<4;++nf){
      #pragma unroll
      for (int t=0;t<2;++t){
        short8 kf = *(const short8*)&Ks[(nf*16+li)*72 + t*32 + lg*8];
        s[nf] = MFMA16(qf[t], kf, s[nf]);
      }
    }

    // p = exp2(s) -> bf16 -> per-wave LDS (re-layout C/D -> A-frag)
    short* pw = Ps[w];
    #pragma unroll
    for (int nf=0;nf<4;++nf)
      #pragma unroll
      for (int j=0;j<4;++j)
        pw[(lg*4+j)*72 + nf*16 + li] = f2bf(exp2f(s[nf][j]));

    // PV: O[16q x 64d] += P @ V ; row-sum via ones-column MFMA
    #pragma unroll
    for (int t=0;t<2;++t){
      short8 pf = *(const short8*)&pw[li*72 + t*32 + lg*8];
      osum = MFMA16(pf, ones8, osum);
      #pragma unroll
      for (int df=0;df<4;++df){
        short8 vf = *(const short8*)&Vs[(df*16+li)*72 + t*32 + lg*8];
        o[df] = MFMA16(pf, vf, o[df]);
      }
    }
    __syncthreads();
  }

  // epilogue: O2[b, l, h*64+d] bf16
  int b = bh >> 3, h = bh & 7;
  float rl[4];
  #pragma unroll
  for (int j=0;j<4;++j) rl[j] = 1.0f / osum[j];
  #pragma unroll
  for (int df=0;df<4;++df)
    #pragma unroll
    for (int j=0;j<4;++j){
      int m   = b*1024 + qw + lg*4 + j;
      int col = h*64 + df*16 + li;
      O2[(size_t)m*512 + col] = f2bf(o[df][j] * rl[j]);
    }
}

// ---------------- GEMM2: O2[8192,512] @ WoT[512,512]^T + bo -> out fp32 ----------------
__global__ __launch_bounds__(256) void k_gemm_out(
    const short* __restrict__ A, const short* __restrict__ Bt,
    const float* __restrict__ bias, float* __restrict__ out)
{
  __shared__ __align__(16) short As[2][128*40];
  __shared__ __align__(16) short Bs[2][128*40];
  const int m0 = blockIdx.x*128, n0 = blockIdx.y*128;
  const int tid = threadIdx.x;
  const int w = tid>>6, lane = tid&63, li = lane&15, lg = lane>>4;
  const int wr = (w>>1)*64, wc = (w&1)*64;

  int row[2], seg[2];
  #pragma unroll
  for (int c=0;c<2;++c){ int s = tid + c*256; row[c]=s>>2; seg[c]=s&3; }

  short8 ga[2], gb[2];
  #pragma unroll
  for (int c=0;c<2;++c){
    ga[c] = *(const short8*)(A  + (size_t)(m0+row[c])*DM + seg[c]*8);
    gb[c] = *(const short8*)(Bt + (size_t)(n0+row[c])*DM + seg[c]*8);
  }

  const f32x4 fz = {0.f,0.f,0.f,0.f};
  f32x4 acc[4][4];
  #pragma unroll
  for (int i=0;i<4;++i)
    #pragma unroll
    for (int j=0;j<4;++j) acc[i][j] = fz;

  for (int kt=0; kt<16; ++kt){
    short* as = As[kt&1]; short* bs = Bs[kt&1];
    #pragma unroll
    for (int c=0;c<2;++c){
      *(short8*)&as[row[c]*40 + seg[c]*8] = ga[c];
      *(short8*)&bs[row[c]*40 + seg[c]*8] = gb[c];
    }
    __syncthreads();
    if (kt < 15){
      int k0 = (kt+1)*32;
      #pragma unroll
      for (int c=0;c<2;++c){
        ga[c] = *(const short8*)(A  + (size_t)(m0+row[c])*DM + k0 + seg[c]*8);
        gb[c] = *(const short8*)(Bt + (size_t)(n0+row[c])*DM + k0 + seg[c]*8);
      }
    }
    short8 bfr[4];
    #pragma unroll
    for (int nf=0;nf<4;++nf)
      bfr[nf] = *(const short8*)&bs[(wc + nf*16 + li)*40 + lg*8];
    #pragma unroll
    for (int mf=0;mf<4;++mf){
      short8 af = *(const short8*)&as[(wr + mf*16 + li)*40 + lg*8];
      #pragma unroll
      for (int nf=0;nf<4;++nf)
        acc[mf][nf] = MFMA16(af, bfr[nf], acc[mf][nf]);
    }
    __syncthreads();
  }

  #pragma unroll
  for (int nf=0;nf<4;++nf){
    int n = n0 + wc + nf*16 + li;
    float bv = bias[n];
    #pragma unroll
    for (int mf=0;mf<4;++mf){
      #pragma unroll
      for (int j=0;j<4;++j){
        int m = m0 + wr + mf*16 + lg*4 + j;
        out[(size_t)m*DM + n] = acc[mf][nf][j] + bv;
      }
    }
  }
}

extern "C" void kernel_launch(void* const* d_in, const int* in_sizes, int n_in,
                              void* d_out, int out_size, void* d_ws, size_t ws_size,
                              hipStream_t stream)
{
  (void)in_sizes; (void)n_in; (void)out_size; (void)ws_size;
  const float* x    = (const float*)d_in[0];
  const float* mask = (const float*)d_in[1];
  const float* Wqkv = (const float*)d_in[2];
  const float* bqkv = (const float*)d_in[3];
  const float* Wo   = (const float*)d_in[4];
  const float* bo   = (const float*)d_in[5];
  float* out = (float*)d_out;

  short* xb    = (short*)d_ws;                    // [8192,512] bf16
  short* WqkvT = xb    + (size_t)M_T*DM;          // [1536,512] bf16
  short* WoT   = WqkvT + (size_t)N3*DM;           // [512,512]  bf16
  short* Qb    = WoT   + (size_t)DM*DM;           // [64][1024][64] bf16 (pre-scaled)
  short* Kbf   = Qb    + (size_t)64*1024*64;      // [64][1024][64] bf16
  short* VTb   = Kbf   + (size_t)64*1024*64;      // [64][64][1024] bf16 (V^T)
  short* O2    = VTb   + (size_t)64*1024*64;      // [8192,512] bf16

  k_cvt<<<2048, 256, 0, stream>>>(x, xb, (M_T*DM)/8);
  k_tr <<<dim3(N3/64, DM/64), 256, 0, stream>>>(Wqkv, WqkvT, DM, N3);
  k_tr <<<dim3(DM/64, DM/64), 256, 0, stream>>>(Wo,   WoT,   DM, DM);
  k_gemm_qkv<<<dim3(M_T/128, N3/128), 256, 0, stream>>>(xb, WqkvT, bqkv, Qb, Kbf, VTb);
  k_attn    <<<dim3(L_/64, B_*H_),    256, 0, stream>>>(Qb, Kbf, VTb, mask, O2);
  k_gemm_out<<<dim3(M_T/128, DM/128), 256, 0, stream>>>(O2, WoT, bo, out);
}

// Round 3
// 99.677 us; speedup vs baseline: 1.2009x; 1.0248x over previous
//
#include <hip/hip_runtime.h>
#include <hip/hip_bf16.h>
#include <stdint.h>

#define B_ 8
#define L_ 1024
#define DM 512
#define H_ 8
#define HD 64
#define N3 1536
#define M_T (B_*L_)        // 8192
#define LOG2E 1.44269504f

typedef __attribute__((ext_vector_type(8))) short short8;    // 8 x bf16 (4 VGPRs)
typedef __attribute__((ext_vector_type(4))) float f32x4;
typedef __attribute__((ext_vector_type(4))) float float4_t;
typedef __attribute__((ext_vector_type(4))) unsigned short ushort4_t;

#define MFMA16(a,b,c) __builtin_amdgcn_mfma_f32_16x16x32_bf16((a),(b),(c),0,0,0)

__device__ __forceinline__ short f2bf(float f){            // manual RNE (prep kernels)
  union { float f; unsigned u; } v; v.f = f;
  unsigned r = v.u + 0x7fffu + ((v.u >> 16) & 1u);
  return (short)(r >> 16);
}

__device__ __forceinline__ short f2bf_fast(float f){       // native cvt (hot paths; RNE, pairs to v_cvt_pk_bf16_f32)
  __hip_bfloat16 h = __float2bfloat16(f);
  short s; __builtin_memcpy(&s, &h, 2); return s;
}

// ---------------- x fp32 -> bf16 (vectorized) ----------------
__global__ __launch_bounds__(256) void k_cvt(const float* __restrict__ x,
                                             short* __restrict__ xb, int n8){
  int i = blockIdx.x*256 + threadIdx.x;
  if (i >= n8) return;
  const float4_t* p = (const float4_t*)x + (size_t)i*2;
  float4_t a = p[0], b = p[1];
  short8 o;
  o[0]=f2bf(a[0]); o[1]=f2bf(a[1]); o[2]=f2bf(a[2]); o[3]=f2bf(a[3]);
  o[4]=f2bf(b[0]); o[5]=f2bf(b[1]); o[6]=f2bf(b[2]); o[7]=f2bf(b[3]);
  *((short8*)xb + i) = o;
}

// ---------------- both weight transposes in one launch: W [512][N] fp32 -> WT [N][512] bf16 ----------------
__global__ __launch_bounds__(256) void k_tr2(const float* __restrict__ W0, short* __restrict__ WT0,
                                             const float* __restrict__ W1, short* __restrict__ WT1){
  __shared__ float t[64][65];
  const float* W; short* WT; int N, n0;
  if (blockIdx.x < 24){ W = W0; WT = WT0; N = N3; n0 = blockIdx.x*64; }
  else                { W = W1; WT = WT1; N = DM; n0 = (blockIdx.x-24)*64; }
  int k0 = blockIdx.y*64;
  int tid = threadIdx.x;
  int r = tid >> 4, c4 = (tid & 15) * 4;
  #pragma unroll
  for (int it=0; it<4; ++it){
    int rr = r + it*16;
    float4_t v = *(const float4_t*)(W + (size_t)(k0+rr)*N + n0 + c4);
    t[rr][c4+0]=v[0]; t[rr][c4+1]=v[1]; t[rr][c4+2]=v[2]; t[rr][c4+3]=v[3];
  }
  __syncthreads();
  #pragma unroll
  for (int it=0; it<4; ++it){
    int n = r + it*16;
    ushort4_t o;
    o[0]=(unsigned short)f2bf(t[c4+0][n]);
    o[1]=(unsigned short)f2bf(t[c4+1][n]);
    o[2]=(unsigned short)f2bf(t[c4+2][n]);
    o[3]=(unsigned short)f2bf(t[c4+3][n]);
    *(ushort4_t*)(WT + (size_t)(n0+n)*DM + k0 + c4) = o;
  }
}

// ---------------- GEMM1: xb[8192,512] @ WqkvT[1536,512]^T + bqkv -> scatter Q/K/VT bf16 ----------------
// Q is pre-scaled by 0.125*log2(e) so attention logits come out of MFMA ready for exp2.
__global__ __launch_bounds__(256) void k_gemm_qkv(
    const short* __restrict__ A, const short* __restrict__ Bt,
    const float* __restrict__ bias,
    short* __restrict__ Qo, short* __restrict__ Ko, short* __restrict__ VTo)
{
  __shared__ __align__(16) short As[2][128*40];
  __shared__ __align__(16) short Bs[2][128*40];
  const int m0 = blockIdx.x*128, n0 = blockIdx.y*128;
  const int tid = threadIdx.x;
  const int w = tid>>6, lane = tid&63, li = lane&15, lg = lane>>4;
  const int wr = (w>>1)*64, wc = (w&1)*64;

  int row[2], seg[2];
  #pragma unroll
  for (int c=0;c<2;++c){ int s = tid + c*256; row[c]=s>>2; seg[c]=s&3; }

  short8 ga[2], gb[2];
  #pragma unroll
  for (int c=0;c<2;++c){
    ga[c] = *(const short8*)(A  + (size_t)(m0+row[c])*DM + seg[c]*8);
    gb[c] = *(const short8*)(Bt + (size_t)(n0+row[c])*DM + seg[c]*8);
  }

  const f32x4 fz = {0.f,0.f,0.f,0.f};
  f32x4 acc[4][4];
  #pragma unroll
  for (int i=0;i<4;++i)
    #pragma unroll
    for (int j=0;j<4;++j) acc[i][j] = fz;

  for (int kt=0; kt<16; ++kt){
    short* as = As[kt&1]; short* bs = Bs[kt&1];
    #pragma unroll
    for (int c=0;c<2;++c){
      *(short8*)&as[row[c]*40 + seg[c]*8] = ga[c];
      *(short8*)&bs[row[c]*40 + seg[c]*8] = gb[c];
    }
    __syncthreads();
    if (kt < 15){
      int k0 = (kt+1)*32;
      #pragma unroll
      for (int c=0;c<2;++c){
        ga[c] = *(const short8*)(A  + (size_t)(m0+row[c])*DM + k0 + seg[c]*8);
        gb[c] = *(const short8*)(Bt + (size_t)(n0+row[c])*DM + k0 + seg[c]*8);
      }
    }
    short8 bfr[4];
    #pragma unroll
    for (int nf=0;nf<4;++nf)
      bfr[nf] = *(const short8*)&bs[(wc + nf*16 + li)*40 + lg*8];
    __builtin_amdgcn_s_setprio(1);
    #pragma unroll
    for (int mf=0;mf<4;++mf){
      short8 af = *(const short8*)&as[(wr + mf*16 + li)*40 + lg*8];
      #pragma unroll
      for (int nf=0;nf<4;++nf)
        acc[mf][nf] = MFMA16(af, bfr[nf], acc[mf][nf]);
    }
    __builtin_amdgcn_s_setprio(0);
    __syncthreads();
  }

  // epilogue: col n -> head h = n/192; within: [0,64)=Q, [64,128)=K, [128,192)=V(transposed store)
  #pragma unroll
  for (int nf=0;nf<4;++nf){
    int n = n0 + wc + nf*16 + li;
    float bv = bias[n];
    unsigned h  = (unsigned)n / 192u;
    unsigned wn = (unsigned)n % 192u;
    unsigned typ = wn >> 6, d = wn & 63u;
    #pragma unroll
    for (int mf=0;mf<4;++mf){
      #pragma unroll
      for (int j=0;j<4;++j){
        int m  = m0 + wr + mf*16 + lg*4 + j;
        int b  = m >> 10, lp = m & 1023;
        size_t bh = (size_t)(b*8 + (int)h);
        float vf = acc[mf][nf][j] + bv;
        if (typ == 0)      Qo [(bh<<16) + ((size_t)lp<<6)  + d]  = f2bf_fast(vf * 0.18033688f); // 0.125*log2e
        else if (typ == 1) Ko [(bh<<16) + ((size_t)lp<<6)  + d]  = f2bf_fast(vf);
        else               VTo[(bh<<16) + ((size_t)d<<10)  + lp] = f2bf_fast(vf);
      }
    }
  }
}

// ---------------- flash attention, fixed-max softmax, mask prefetched one tile ahead ----------------
__global__ __launch_bounds__(256) void k_attn(
    const short* __restrict__ Q, const short* __restrict__ Kb,
    const short* __restrict__ VT, const float* __restrict__ mask,
    short* __restrict__ O2)
{
  __shared__ __align__(16) short Ks[64*72];
  __shared__ __align__(16) short Vs[64*72];
  __shared__ __align__(16) short Ps[4][16*72];
  const int bh = blockIdx.y;
  const int q0 = blockIdx.x*64;
  const int tid = threadIdx.x, w = tid>>6, lane = tid&63, li = lane&15, lg = lane>>4;
  const int qw = q0 + w*16;

  const short* Qp = Q  + ((size_t)bh<<16);
  const short* Kp = Kb + ((size_t)bh<<16);
  const short* Vp = VT + ((size_t)bh<<16);

  // Q fragments in registers (A-operand: row=li, k=d); Q pre-scaled in GEMM1
  short8 qf[2];
  #pragma unroll
  for (int t=0;t<2;++t)
    qf[t] = *(const short8*)(Qp + ((size_t)(qw+li)<<6) + t*32 + lg*8);

  short8 ones8;
  #pragma unroll
  for (int e=0;e<8;++e) ones8[e] = (short)0x3f80;   // bf16 1.0

  const f32x4 fz = {0.f,0.f,0.f,0.f};
  f32x4 o[4], osum = fz;
  #pragma unroll
  for (int df=0;df<4;++df) o[df] = fz;

  int srow[2], sseg[2];
  #pragma unroll
  for (int c=0;c<2;++c){ int s = tid + c*256; srow[c]=s>>3; sseg[c]=s&7; }

  short8 gk[2], gv[2];
  #pragma unroll
  for (int c=0;c<2;++c){
    gk[c] = *(const short8*)(Kp + ((size_t)srow[c]<<6)  + sseg[c]*8);
    gv[c] = *(const short8*)(Vp + ((size_t)srow[c]<<10) + sseg[c]*8);
  }

  const float* mbase = mask + (size_t)(qw + lg*4)*1024 + li;

  // prologue: tile-0 mask, pre-folded into exp2 domain: s_init = mask*log2e - 12*log2e
  f32x4 sn[4];
  #pragma unroll
  for (int nf=0;nf<4;++nf)
    #pragma unroll
    for (int j=0;j<4;++j)
      sn[nf][j] = fmaf(mbase[(size_t)j*1024 + nf*16], LOG2E, -17.3123405f);

  short* pw = Ps[w];

  for (int kv0=0; kv0<1024; kv0+=64){
    #pragma unroll
    for (int c=0;c<2;++c){
      *(short8*)&Ks[srow[c]*72 + sseg[c]*8] = gk[c];
      *(short8*)&Vs[srow[c]*72 + sseg[c]*8] = gv[c];
    }
    __syncthreads();

    f32x4 s[4];
    #pragma unroll
    for (int nf=0;nf<4;++nf) s[nf] = sn[nf];

    const bool more = (kv0 < 960);
    float mt[4][4];
    if (more){
      int nx = kv0 + 64;
      #pragma unroll
      for (int c=0;c<2;++c){
        gk[c] = *(const short8*)(Kp + ((size_t)(nx+srow[c])<<6)  + sseg[c]*8);
        gv[c] = *(const short8*)(Vp + ((size_t)srow[c]<<10) + nx + sseg[c]*8);
      }
      #pragma unroll
      for (int nf=0;nf<4;++nf)
        #pragma unroll
        for (int j=0;j<4;++j)
          mt[nf][j] = mbase[(size_t)j*1024 + nx + nf*16];
    }

    // QK^T (C-operand = folded mask)
    __builtin_amdgcn_s_setprio(1);
    #pragma unroll
    for (int nf=0;nf<4;++nf){
      #pragma unroll
      for (int t=0;t<2;++t){
        short8 kf = *(const short8*)&Ks[(nf*16+li)*72 + t*32 + lg*8];
        s[nf] = MFMA16(qf[t], kf, s[nf]);
      }
    }
    __builtin_amdgcn_s_setprio(0);

    // p = exp2(s) -> bf16 -> per-wave LDS (re-layout C/D -> A-frag)
    #pragma unroll
    for (int nf=0;nf<4;++nf)
      #pragma unroll
      for (int j=0;j<4;++j)
        pw[(lg*4+j)*72 + nf*16 + li] = f2bf_fast(exp2f(s[nf][j]));

    // PV: O[16q x 64d] += P @ V ; row-sum via ones-column MFMA
    __builtin_amdgcn_s_setprio(1);
    #pragma unroll
    for (int t=0;t<2;++t){
      short8 pf = *(const short8*)&pw[li*72 + t*32 + lg*8];
      osum = MFMA16(pf, ones8, osum);
      #pragma unroll
      for (int df=0;df<4;++df){
        short8 vf = *(const short8*)&Vs[(df*16+li)*72 + t*32 + lg*8];
        o[df] = MFMA16(pf, vf, o[df]);
      }
    }
    __builtin_amdgcn_s_setprio(0);

    // fold next tile's mask (loads issued early; wait lands here, hidden by MFMA above)
    if (more){
      #pragma unroll
      for (int nf=0;nf<4;++nf)
        #pragma unroll
        for (int j=0;j<4;++j)
          sn[nf][j] = fmaf(mt[nf][j], LOG2E, -17.3123405f);
    }
    __syncthreads();
  }

  // epilogue: O2[b, l, h*64+d] bf16
  int b = bh >> 3, h = bh & 7;
  float rl[4];
  #pragma unroll
  for (int j=0;j<4;++j) rl[j] = 1.0f / osum[j];
  #pragma unroll
  for (int df=0;df<4;++df)
    #pragma unroll
    for (int j=0;j<4;++j){
      int m   = b*1024 + qw + lg*4 + j;
      int col = h*64 + df*16 + li;
      O2[(size_t)m*512 + col] = f2bf_fast(o[df][j] * rl[j]);
    }
}

// ---------------- GEMM2: O2[8192,512] @ WoT[512,512]^T + bo -> out fp32 ----------------
__global__ __launch_bounds__(256) void k_gemm_out(
    const short* __restrict__ A, const short* __restrict__ Bt,
    const float* __restrict__ bias, float* __restrict__ out)
{
  __shared__ __align__(16) short As[2][128*40];
  __shared__ __align__(16) short Bs[2][128*40];
  const int m0 = blockIdx.x*128, n0 = blockIdx.y*128;
  const int tid = threadIdx.x;
  const int w = tid>>6, lane = tid&63, li = lane&15, lg = lane>>4;
  const int wr = (w>>1)*64, wc = (w&1)*64;

  int row[2], seg[2];
  #pragma unroll
  for (int c=0;c<2;++c){ int s = tid + c*256; row[c]=s>>2; seg[c]=s&3; }

  short8 ga[2], gb[2];
  #pragma unroll
  for (int c=0;c<2;++c){
    ga[c] = *(const short8*)(A  + (size_t)(m0+row[c])*DM + seg[c]*8);
    gb[c] = *(const short8*)(Bt + (size_t)(n0+row[c])*DM + seg[c]*8);
  }

  const f32x4 fz = {0.f,0.f,0.f,0.f};
  f32x4 acc[4][4];
  #pragma unroll
  for (int i=0;i<4;++i)
    #pragma unroll
    for (int j=0;j<4;++j) acc[i][j] = fz;

  for (int kt=0; kt<16; ++kt){
    short* as = As[kt&1]; short* bs = Bs[kt&1];
    #pragma unroll
    for (int c=0;c<2;++c){
      *(short8*)&as[row[c]*40 + seg[c]*8] = ga[c];
      *(short8*)&bs[row[c]*40 + seg[c]*8] = gb[c];
    }
    __syncthreads();
    if (kt < 15){
      int k0 = (kt+1)*32;
      #pragma unroll
      for (int c=0;c<2;++c){
        ga[c] = *(const short8*)(A  + (size_t)(m0+row[c])*DM + k0 + seg[c]*8);
        gb[c] = *(const short8*)(Bt + (size_t)(n0+row[c])*DM + k0 + seg[c]*8);
      }
    }
    short8 bfr[4];
    #pragma unroll
    for (int nf=0;nf<4;++nf)
      bfr[nf] = *(const short8*)&bs[(wc + nf*16 + li)*40 + lg*8];
    __builtin_amdgcn_s_setprio(1);
    #pragma unroll
    for (int mf=0;mf<4;++mf){
      short8 af = *(const short8*)&as[(wr + mf*16 + li)*40 + lg*8];
      #pragma unroll
      for (int nf=0;nf<4;++nf)
        acc[mf][nf] = MFMA16(af, bfr[nf], acc[mf][nf]);
    }
    __builtin_amdgcn_s_setprio(0);
    __syncthreads();
  }

  #pragma unroll
  for (int nf=0;nf<4;++nf){
    int n = n0 + wc + nf*16 + li;
    float bv = bias[n];
    #pragma unroll
    for (int mf=0;mf<4;++mf){
      #pragma unroll
      for (int j=0;j<4;++j){
        int m = m0 + wr + mf*16 + lg*4 + j;
        out[(size_t)m*DM + n] = acc[mf][nf][j] + bv;
      }
    }
  }
}

extern "C" void kernel_launch(void* const* d_in, const int* in_sizes, int n_in,
                              void* d_out, int out_size, void* d_ws, size_t ws_size,
                              hipStream_t stream)
{
  (void)in_sizes; (void)n_in; (void)out_size; (void)ws_size;
  const float* x    = (const float*)d_in[0];
  const float* mask = (const float*)d_in[1];
  const float* Wqkv = (const float*)d_in[2];
  const float* bqkv = (const float*)d_in[3];
  const float* Wo   = (const float*)d_in[4];
  const float* bo   = (const float*)d_in[5];
  float* out = (float*)d_out;

  short* xb    = (short*)d_ws;                    // [8192,512] bf16
  short* WqkvT = xb    + (size_t)M_T*DM;          // [1536,512] bf16
  short* WoT   = WqkvT + (size_t)N3*DM;           // [512,512]  bf16
  short* Qb    = WoT   + (size_t)DM*DM;           // [64][1024][64] bf16 (pre-scaled)
  short* Kbf   = Qb    + (size_t)64*1024*64;      // [64][1024][64] bf16
  short* VTb   = Kbf   + (size_t)64*1024*64;      // [64][64][1024] bf16 (V^T)
  short* O2    = VTb   + (size_t)64*1024*64;      // [8192,512] bf16

  k_cvt<<<2048, 256, 0, stream>>>(x, xb, (M_T*DM)/8);
  k_tr2<<<dim3(32, 8), 256, 0, stream>>>(Wqkv, WqkvT, Wo, WoT);
  k_gemm_qkv<<<dim3(M_T/128, N3/128), 256, 0, stream>>>(xb, WqkvT, bqkv, Qb, Kbf, VTb);
  k_attn    <<<dim3(L_/64, B_*H_),    256, 0, stream>>>(Qb, Kbf, VTb, mask, O2);
  k_gemm_out<<<dim3(M_T/128, DM/128), 256, 0, stream>>>(O2, WoT, bo, out);
}

// Round 4
// 93.765 us; speedup vs baseline: 1.2766x; 1.0631x over previous
//
#include <hip/hip_runtime.h>
#include <hip/hip_bf16.h>
#include <stdint.h>

#define B_ 8
#define L_ 1024
#define DM 512
#define H_ 8
#define HD 64
#define N3 1536
#define M_T (B_*L_)        // 8192
#define LOG2E 1.44269504f

typedef __attribute__((ext_vector_type(8))) short short8;    // 8 x bf16 (4 VGPRs)
typedef __attribute__((ext_vector_type(4))) float f32x4;
typedef __attribute__((ext_vector_type(4))) float float4_t;
typedef __attribute__((ext_vector_type(4))) unsigned short ushort4_t;

#define MFMA16(a,b,c) __builtin_amdgcn_mfma_f32_16x16x32_bf16((a),(b),(c),0,0,0)

__device__ __forceinline__ short f2bf(float f){            // manual RNE (prep kernels)
  union { float f; unsigned u; } v; v.f = f;
  unsigned r = v.u + 0x7fffu + ((v.u >> 16) & 1u);
  return (short)(r >> 16);
}

__device__ __forceinline__ short f2bf_fast(float f){       // native cvt (hot paths)
  __hip_bfloat16 h = __float2bfloat16(f);
  short s; __builtin_memcpy(&s, &h, 2); return s;
}

// ---------------- x fp32 -> bf16 (vectorized) ----------------
__global__ __launch_bounds__(256) void k_cvt(const float* __restrict__ x,
                                             short* __restrict__ xb, int n8){
  int i = blockIdx.x*256 + threadIdx.x;
  if (i >= n8) return;
  const float4_t* p = (const float4_t*)x + (size_t)i*2;
  float4_t a = p[0], b = p[1];
  short8 o;
  o[0]=f2bf(a[0]); o[1]=f2bf(a[1]); o[2]=f2bf(a[2]); o[3]=f2bf(a[3]);
  o[4]=f2bf(b[0]); o[5]=f2bf(b[1]); o[6]=f2bf(b[2]); o[7]=f2bf(b[3]);
  *((short8*)xb + i) = o;
}

// ---------------- both weight transposes in one launch: W [512][N] fp32 -> WT [N][512] bf16 ----------------
__global__ __launch_bounds__(256) void k_tr2(const float* __restrict__ W0, short* __restrict__ WT0,
                                             const float* __restrict__ W1, short* __restrict__ WT1){
  __shared__ float t[64][65];
  const float* W; short* WT; int N, n0;
  if (blockIdx.x < 24){ W = W0; WT = WT0; N = N3; n0 = blockIdx.x*64; }
  else                { W = W1; WT = WT1; N = DM; n0 = (blockIdx.x-24)*64; }
  int k0 = blockIdx.y*64;
  int tid = threadIdx.x;
  int r = tid >> 4, c4 = (tid & 15) * 4;
  #pragma unroll
  for (int it=0; it<4; ++it){
    int rr = r + it*16;
    float4_t v = *(const float4_t*)(W + (size_t)(k0+rr)*N + n0 + c4);
    t[rr][c4+0]=v[0]; t[rr][c4+1]=v[1]; t[rr][c4+2]=v[2]; t[rr][c4+3]=v[3];
  }
  __syncthreads();
  #pragma unroll
  for (int it=0; it<4; ++it){
    int n = r + it*16;
    ushort4_t o;
    o[0]=(unsigned short)f2bf(t[c4+0][n]);
    o[1]=(unsigned short)f2bf(t[c4+1][n]);
    o[2]=(unsigned short)f2bf(t[c4+2][n]);
    o[3]=(unsigned short)f2bf(t[c4+3][n]);
    *(ushort4_t*)(WT + (size_t)(n0+n)*DM + k0 + c4) = o;
  }
}

// ---------------- mask -> prescaled, fragment-tiled layout ----------------
// maskP flat idx = qg*16384 + kvt*1024 + lane*16 + nf*4 + j
//   value = mask[qg*16 + lg*4 + j][kvt*64 + nf*16 + li] * LOG2E - 17.3123405
__global__ __launch_bounds__(256) void k_maskp(const float* __restrict__ mask,
                                               float* __restrict__ maskP){
  int gid = blockIdx.x*256 + threadIdx.x;        // 262144 threads, 4 floats each
  int nf  = gid & 3;
  int lane= (gid>>2) & 63;
  int kvt = (gid>>8) & 15;
  int qg  = gid>>12;
  int li = lane & 15, lg = lane >> 4;
  int r0 = qg*16 + lg*4;
  int col = kvt*64 + nf*16 + li;
  float4_t o;
  #pragma unroll
  for (int j=0;j<4;++j)
    o[j] = fmaf(mask[(size_t)(r0+j)*1024 + col], LOG2E, -17.3123405f);
  ((float4_t*)maskP)[gid] = o;
}

// ---------------- GEMM1: xb[8192,512] @ WqkvT[1536,512]^T + bqkv -> scatter Q/K/VT bf16 ----------------
// Q is pre-scaled by 0.125*log2(e) so attention logits come out of MFMA ready for exp2.
__global__ __launch_bounds__(256) void k_gemm_qkv(
    const short* __restrict__ A, const short* __restrict__ Bt,
    const float* __restrict__ bias,
    short* __restrict__ Qo, short* __restrict__ Ko, short* __restrict__ VTo)
{
  __shared__ __align__(16) short As[2][128*40];
  __shared__ __align__(16) short Bs[2][128*40];
  const int m0 = blockIdx.x*128, n0 = blockIdx.y*128;
  const int tid = threadIdx.x;
  const int w = tid>>6, lane = tid&63, li = lane&15, lg = lane>>4;
  const int wr = (w>>1)*64, wc = (w&1)*64;

  int row[2], seg[2];
  #pragma unroll
  for (int c=0;c<2;++c){ int s = tid + c*256; row[c]=s>>2; seg[c]=s&3; }

  short8 ga[2], gb[2];
  #pragma unroll
  for (int c=0;c<2;++c){
    ga[c] = *(const short8*)(A  + (size_t)(m0+row[c])*DM + seg[c]*8);
    gb[c] = *(const short8*)(Bt + (size_t)(n0+row[c])*DM + seg[c]*8);
  }

  const f32x4 fz = {0.f,0.f,0.f,0.f};
  f32x4 acc[4][4];
  #pragma unroll
  for (int i=0;i<4;++i)
    #pragma unroll
    for (int j=0;j<4;++j) acc[i][j] = fz;

  for (int kt=0; kt<16; ++kt){
    short* as = As[kt&1]; short* bs = Bs[kt&1];
    #pragma unroll
    for (int c=0;c<2;++c){
      *(short8*)&as[row[c]*40 + seg[c]*8] = ga[c];
      *(short8*)&bs[row[c]*40 + seg[c]*8] = gb[c];
    }
    __syncthreads();
    if (kt < 15){
      int k0 = (kt+1)*32;
      #pragma unroll
      for (int c=0;c<2;++c){
        ga[c] = *(const short8*)(A  + (size_t)(m0+row[c])*DM + k0 + seg[c]*8);
        gb[c] = *(const short8*)(Bt + (size_t)(n0+row[c])*DM + k0 + seg[c]*8);
      }
    }
    short8 bfr[4];
    #pragma unroll
    for (int nf=0;nf<4;++nf)
      bfr[nf] = *(const short8*)&bs[(wc + nf*16 + li)*40 + lg*8];
    __builtin_amdgcn_s_setprio(1);
    #pragma unroll
    for (int mf=0;mf<4;++mf){
      short8 af = *(const short8*)&as[(wr + mf*16 + li)*40 + lg*8];
      #pragma unroll
      for (int nf=0;nf<4;++nf)
        acc[mf][nf] = MFMA16(af, bfr[nf], acc[mf][nf]);
    }
    __builtin_amdgcn_s_setprio(0);
    __syncthreads();
  }

  // epilogue: col n -> head h = n/192; within: [0,64)=Q, [64,128)=K, [128,192)=V(transposed store)
  #pragma unroll
  for (int nf=0;nf<4;++nf){
    int n = n0 + wc + nf*16 + li;
    float bv = bias[n];
    unsigned h  = (unsigned)n / 192u;
    unsigned wn = (unsigned)n % 192u;
    unsigned typ = wn >> 6, d = wn & 63u;
    #pragma unroll
    for (int mf=0;mf<4;++mf){
      #pragma unroll
      for (int j=0;j<4;++j){
        int m  = m0 + wr + mf*16 + lg*4 + j;
        int b  = m >> 10, lp = m & 1023;
        size_t bh = (size_t)(b*8 + (int)h);
        float vf = acc[mf][nf][j] + bv;
        if (typ == 0)      Qo [(bh<<16) + ((size_t)lp<<6)  + d]  = f2bf_fast(vf * 0.18033688f); // 0.125*log2e
        else if (typ == 1) Ko [(bh<<16) + ((size_t)lp<<6)  + d]  = f2bf_fast(vf);
        else               VTo[(bh<<16) + ((size_t)d<<10)  + lp] = f2bf_fast(vf);
      }
    }
  }
}

// ---------------- flash attention: 8 waves, 128 q-rows/block, dbuf K/V, 1 barrier/tile ----------------
__global__ __launch_bounds__(512) void k_attn(
    const short* __restrict__ Q, const short* __restrict__ Kb,
    const short* __restrict__ VT, const float* __restrict__ maskP,
    short* __restrict__ O2)
{
  __shared__ __align__(16) short Ks[2][64*72];
  __shared__ __align__(16) short Vs[2][64*72];
  __shared__ __align__(16) short Ps[8][16*72];
  const int bh = blockIdx.y;
  const int q0 = blockIdx.x*128;
  const int tid = threadIdx.x, w = tid>>6, lane = tid&63, li = lane&15, lg = lane>>4;
  const int qw = q0 + w*16;

  const short* Qp = Q  + ((size_t)bh<<16);
  const short* Kp = Kb + ((size_t)bh<<16);
  const short* Vp = VT + ((size_t)bh<<16);

  // Q fragments in registers (A-operand: row=li, k=d); Q pre-scaled in GEMM1
  short8 qf[2];
  #pragma unroll
  for (int t=0;t<2;++t)
    qf[t] = *(const short8*)(Qp + ((size_t)(qw+li)<<6) + t*32 + lg*8);

  short8 ones8;
  #pragma unroll
  for (int e=0;e<8;++e) ones8[e] = (short)0x3f80;   // bf16 1.0

  const f32x4 fz = {0.f,0.f,0.f,0.f};
  f32x4 o[4], osum = fz;
  #pragma unroll
  for (int df=0;df<4;++df) o[df] = fz;

  // staging: 512 threads cover one 64x64 bf16 tile in single short8 per thread
  const int srow = tid>>3, sseg8 = (tid&7)*8;

  // prologue: stage tile 0 into buf0, prefetch tile 1
  short8 gk = *(const short8*)(Kp + ((size_t)srow<<6) + sseg8);
  short8 gv = *(const short8*)(Vp + ((size_t)srow<<10) + sseg8);
  *(short8*)&Ks[0][srow*72 + sseg8] = gk;
  *(short8*)&Vs[0][srow*72 + sseg8] = gv;
  gk = *(const short8*)(Kp + ((size_t)(64+srow)<<6) + sseg8);
  gv = *(const short8*)(Vp + ((size_t)srow<<10) + 64 + sseg8);
  __syncthreads();

  const float* mp0 = maskP + ((size_t)(qw>>4)<<14) + lane*16;
  short* pw = Ps[w];

  for (int kvt=0; kvt<16; ++kvt){
    const short* ks = Ks[kvt&1];
    const short* vs = Vs[kvt&1];
    if (kvt < 15){
      short* kd = Ks[(kvt&1)^1]; short* vd = Vs[(kvt&1)^1];
      *(short8*)&kd[srow*72 + sseg8] = gk;
      *(short8*)&vd[srow*72 + sseg8] = gv;
    }
    if (kvt < 14){
      int nx = (kvt+2)*64;
      gk = *(const short8*)(Kp + ((size_t)(nx+srow)<<6) + sseg8);
      gv = *(const short8*)(Vp + ((size_t)srow<<10) + nx + sseg8);
    }

    // s-init: prescaled mask, fragment-ordered, 4 coalesced dwordx4 loads
    const float* mp = mp0 + (size_t)kvt*1024;
    f32x4 s[4];
    #pragma unroll
    for (int nf=0;nf<4;++nf)
      s[nf] = *(const float4_t*)(mp + nf*4);

    // QK^T (C-operand = folded mask)
    __builtin_amdgcn_s_setprio(1);
    #pragma unroll
    for (int nf=0;nf<4;++nf){
      #pragma unroll
      for (int t=0;t<2;++t){
        short8 kf = *(const short8*)&ks[(nf*16+li)*72 + t*32 + lg*8];
        s[nf] = MFMA16(qf[t], kf, s[nf]);
      }
    }
    __builtin_amdgcn_s_setprio(0);

    // p = exp2(s) -> bf16 -> per-wave LDS (re-layout C/D -> A-frag)
    #pragma unroll
    for (int nf=0;nf<4;++nf)
      #pragma unroll
      for (int j=0;j<4;++j)
        pw[(lg*4+j)*72 + nf*16 + li] = f2bf_fast(exp2f(s[nf][j]));

    // PV: O[16q x 64d] += P @ V ; row-sum via ones-column MFMA
    __builtin_amdgcn_s_setprio(1);
    #pragma unroll
    for (int t=0;t<2;++t){
      short8 pf = *(const short8*)&pw[li*72 + t*32 + lg*8];
      osum = MFMA16(pf, ones8, osum);
      #pragma unroll
      for (int df=0;df<4;++df){
        short8 vf = *(const short8*)&vs[(df*16+li)*72 + t*32 + lg*8];
        o[df] = MFMA16(pf, vf, o[df]);
      }
    }
    __builtin_amdgcn_s_setprio(0);

    __syncthreads();   // buf[cur] reads done + buf[cur^1] stores visible
  }

  // epilogue: O2[b, l, h*64+d] bf16
  int b = bh >> 3, h = bh & 7;
  float rl[4];
  #pragma unroll
  for (int j=0;j<4;++j) rl[j] = 1.0f / osum[j];
  #pragma unroll
  for (int df=0;df<4;++df)
    #pragma unroll
    for (int j=0;j<4;++j){
      int m   = b*1024 + qw + lg*4 + j;
      int col = h*64 + df*16 + li;
      O2[(size_t)m*512 + col] = f2bf_fast(o[df][j] * rl[j]);
    }
}

// ---------------- GEMM2: O2[8192,512] @ WoT[512,512]^T + bo -> out fp32 ----------------
__global__ __launch_bounds__(256) void k_gemm_out(
    const short* __restrict__ A, const short* __restrict__ Bt,
    const float* __restrict__ bias, float* __restrict__ out)
{
  __shared__ __align__(16) short As[2][128*40];
  __shared__ __align__(16) short Bs[2][128*40];
  const int m0 = blockIdx.x*128, n0 = blockIdx.y*128;
  const int tid = threadIdx.x;
  const int w = tid>>6, lane = tid&63, li = lane&15, lg = lane>>4;
  const int wr = (w>>1)*64, wc = (w&1)*64;

  int row[2], seg[2];
  #pragma unroll
  for (int c=0;c<2;++c){ int s = tid + c*256; row[c]=s>>2; seg[c]=s&3; }

  short8 ga[2], gb[2];
  #pragma unroll
  for (int c=0;c<2;++c){
    ga[c] = *(const short8*)(A  + (size_t)(m0+row[c])*DM + seg[c]*8);
    gb[c] = *(const short8*)(Bt + (size_t)(n0+row[c])*DM + seg[c]*8);
  }

  const f32x4 fz = {0.f,0.f,0.f,0.f};
  f32x4 acc[4][4];
  #pragma unroll
  for (int i=0;i<4;++i)
    #pragma unroll
    for (int j=0;j<4;++j) acc[i][j] = fz;

  for (int kt=0; kt<16; ++kt){
    short* as = As[kt&1]; short* bs = Bs[kt&1];
    #pragma unroll
    for (int c=0;c<2;++c){
      *(short8*)&as[row[c]*40 + seg[c]*8] = ga[c];
      *(short8*)&bs[row[c]*40 + seg[c]*8] = gb[c];
    }
    __syncthreads();
    if (kt < 15){
      int k0 = (kt+1)*32;
      #pragma unroll
      for (int c=0;c<2;++c){
        ga[c] = *(const short8*)(A  + (size_t)(m0+row[c])*DM + k0 + seg[c]*8);
        gb[c] = *(const short8*)(Bt + (size_t)(n0+row[c])*DM + k0 + seg[c]*8);
      }
    }
    short8 bfr[4];
    #pragma unroll
    for (int nf=0;nf<4;++nf)
      bfr[nf] = *(const short8*)&bs[(wc + nf*16 + li)*40 + lg*8];
    __builtin_amdgcn_s_setprio(1);
    #pragma unroll
    for (int mf=0;mf<4;++mf){
      short8 af = *(const short8*)&as[(wr + mf*16 + li)*40 + lg*8];
      #pragma unroll
      for (int nf=0;nf<4;++nf)
        acc[mf][nf] = MFMA16(af, bfr[nf], acc[mf][nf]);
    }
    __builtin_amdgcn_s_setprio(0);
    __syncthreads();
  }

  #pragma unroll
  for (int nf=0;nf<4;++nf){
    int n = n0 + wc + nf*16 + li;
    float bv = bias[n];
    #pragma unroll
    for (int mf=0;mf<4;++mf){
      #pragma unroll
      for (int j=0;j<4;++j){
        int m = m0 + wr + mf*16 + lg*4 + j;
        out[(size_t)m*DM + n] = acc[mf][nf][j] + bv;
      }
    }
  }
}

extern "C" void kernel_launch(void* const* d_in, const int* in_sizes, int n_in,
                              void* d_out, int out_size, void* d_ws, size_t ws_size,
                              hipStream_t stream)
{
  (void)in_sizes; (void)n_in; (void)out_size; (void)ws_size;
  const float* x    = (const float*)d_in[0];
  const float* mask = (const float*)d_in[1];
  const float* Wqkv = (const float*)d_in[2];
  const float* bqkv = (const float*)d_in[3];
  const float* Wo   = (const float*)d_in[4];
  const float* bo   = (const float*)d_in[5];
  float* out = (float*)d_out;

  short* xb    = (short*)d_ws;                    // [8192,512] bf16 (dead after GEMM1)
  short* WqkvT = xb    + (size_t)M_T*DM;          // [1536,512] bf16
  short* WoT   = WqkvT + (size_t)N3*DM;           // [512,512]  bf16
  short* Qb    = WoT   + (size_t)DM*DM;           // [64][1024][64] bf16 (pre-scaled)
  short* Kbf   = Qb    + (size_t)64*1024*64;      // [64][1024][64] bf16
  short* VTb   = Kbf   + (size_t)64*1024*64;      // [64][64][1024] bf16 (V^T)
  short* O2    = VTb   + (size_t)64*1024*64;      // [8192,512] bf16
  float* maskP = (float*)xb;                      // 4MB, aliases xb AFTER GEMM1 consumed it

  k_cvt<<<2048, 256, 0, stream>>>(x, xb, (M_T*DM)/8);
  k_tr2<<<dim3(32, 8), 256, 0, stream>>>(Wqkv, WqkvT, Wo, WoT);
  k_gemm_qkv<<<dim3(M_T/128, N3/128), 256, 0, stream>>>(xb, WqkvT, bqkv, Qb, Kbf, VTb);
  k_maskp<<<1024, 256, 0, stream>>>(mask, maskP);
  k_attn    <<<dim3(L_/128, B_*H_),   512, 0, stream>>>(Qb, Kbf, VTb, maskP, O2);
  k_gemm_out<<<dim3(M_T/128, DM/128), 256, 0, stream>>>(O2, WoT, bo, out);
}

// Round 5
// 89.863 us; speedup vs baseline: 1.3321x; 1.0434x over previous
//
#include <hip/hip_runtime.h>
#include <hip/hip_bf16.h>
#include <stdint.h>

#define B_ 8
#define L_ 1024
#define DM 512
#define H_ 8
#define HD 64
#define N3 1536
#define M_T (B_*L_)        // 8192
#define LOG2E 1.44269504f

typedef __attribute__((ext_vector_type(8))) short short8;    // 8 x bf16 (4 VGPRs)
typedef __attribute__((ext_vector_type(4))) float f32x4;
typedef __attribute__((ext_vector_type(4))) float float4_t;
typedef __attribute__((ext_vector_type(4))) unsigned short ushort4_t;
typedef __attribute__((ext_vector_type(2))) unsigned int u32x2;

#define MFMA16(a,b,c) __builtin_amdgcn_mfma_f32_16x16x32_bf16((a),(b),(c),0,0,0)

__device__ __forceinline__ short f2bf(float f){            // manual RNE (prep kernels)
  union { float f; unsigned u; } v; v.f = f;
  unsigned r = v.u + 0x7fffu + ((v.u >> 16) & 1u);
  return (short)(r >> 16);
}

__device__ __forceinline__ short f2bf_fast(float f){       // native cvt (hot paths)
  __hip_bfloat16 h = __float2bfloat16(f);
  short s; __builtin_memcpy(&s, &h, 2); return s;
}

// ---------------- x fp32 -> bf16 (vectorized) ----------------
__global__ __launch_bounds__(256) void k_cvt(const float* __restrict__ x,
                                             short* __restrict__ xb, int n8){
  int i = blockIdx.x*256 + threadIdx.x;
  if (i >= n8) return;
  const float4_t* p = (const float4_t*)x + (size_t)i*2;
  float4_t a = p[0], b = p[1];
  short8 o;
  o[0]=f2bf(a[0]); o[1]=f2bf(a[1]); o[2]=f2bf(a[2]); o[3]=f2bf(a[3]);
  o[4]=f2bf(b[0]); o[5]=f2bf(b[1]); o[6]=f2bf(b[2]); o[7]=f2bf(b[3]);
  *((short8*)xb + i) = o;
}

// ---------------- both weight transposes in one launch: W [512][N] fp32 -> WT [N][512] bf16 ----------------
__global__ __launch_bounds__(256) void k_tr2(const float* __restrict__ W0, short* __restrict__ WT0,
                                             const float* __restrict__ W1, short* __restrict__ WT1){
  __shared__ float t[64][65];
  const float* W; short* WT; int N, n0;
  if (blockIdx.x < 24){ W = W0; WT = WT0; N = N3; n0 = blockIdx.x*64; }
  else                { W = W1; WT = WT1; N = DM; n0 = (blockIdx.x-24)*64; }
  int k0 = blockIdx.y*64;
  int tid = threadIdx.x;
  int r = tid >> 4, c4 = (tid & 15) * 4;
  #pragma unroll
  for (int it=0; it<4; ++it){
    int rr = r + it*16;
    float4_t v = *(const float4_t*)(W + (size_t)(k0+rr)*N + n0 + c4);
    t[rr][c4+0]=v[0]; t[rr][c4+1]=v[1]; t[rr][c4+2]=v[2]; t[rr][c4+3]=v[3];
  }
  __syncthreads();
  #pragma unroll
  for (int it=0; it<4; ++it){
    int n = r + it*16;
    ushort4_t o;
    o[0]=(unsigned short)f2bf(t[c4+0][n]);
    o[1]=(unsigned short)f2bf(t[c4+1][n]);
    o[2]=(unsigned short)f2bf(t[c4+2][n]);
    o[3]=(unsigned short)f2bf(t[c4+3][n]);
    *(ushort4_t*)(WT + (size_t)(n0+n)*DM + k0 + c4) = o;
  }
}

// ---------------- mask -> prescaled, TRANSPOSED-fragment layout ----------------
// maskP flat = qg*16384 + kvt*1024 + lane*16 + nf*4 + j
//   value = mask[qg*16 + li][kvt*64 + nf*16 + lg*4 + j] * LOG2E - 17.3123405
// (C/D of swapped QK^T: col=li -> q, row=lg*4+j -> kv)
__global__ __launch_bounds__(256) void k_maskp(const float* __restrict__ mask,
                                               float* __restrict__ maskP){
  int gid = blockIdx.x*256 + threadIdx.x;        // 262144 threads, 4 floats each
  int nf  = gid & 3;
  int lane= (gid>>2) & 63;
  int kvt = (gid>>8) & 15;
  int qg  = gid>>12;
  int li = lane & 15, lg = lane >> 4;
  int row = qg*16 + li;
  int col = kvt*64 + nf*16 + lg*4;
  float4_t m = *(const float4_t*)(mask + (size_t)row*1024 + col);
  float4_t o;
  #pragma unroll
  for (int j=0;j<4;++j) o[j] = fmaf(m[j], LOG2E, -17.3123405f);
  ((float4_t*)maskP)[gid] = o;
}

// ---------------- GEMM1: xb[8192,512] @ WqkvT[1536,512]^T + bqkv -> scatter Q/K/VT bf16 ----------------
// Q is pre-scaled by 0.125*log2(e) so attention logits come out of MFMA ready for exp2.
__global__ __launch_bounds__(256) void k_gemm_qkv(
    const short* __restrict__ A, const short* __restrict__ Bt,
    const float* __restrict__ bias,
    short* __restrict__ Qo, short* __restrict__ Ko, short* __restrict__ VTo)
{
  __shared__ __align__(16) short As[2][128*40];
  __shared__ __align__(16) short Bs[2][128*40];
  const int m0 = blockIdx.x*128, n0 = blockIdx.y*128;
  const int tid = threadIdx.x;
  const int w = tid>>6, lane = tid&63, li = lane&15, lg = lane>>4;
  const int wr = (w>>1)*64, wc = (w&1)*64;

  int row[2], seg[2];
  #pragma unroll
  for (int c=0;c<2;++c){ int s = tid + c*256; row[c]=s>>2; seg[c]=s&3; }

  short8 ga[2], gb[2];
  #pragma unroll
  for (int c=0;c<2;++c){
    ga[c] = *(const short8*)(A  + (size_t)(m0+row[c])*DM + seg[c]*8);
    gb[c] = *(const short8*)(Bt + (size_t)(n0+row[c])*DM + seg[c]*8);
  }

  const f32x4 fz = {0.f,0.f,0.f,0.f};
  f32x4 acc[4][4];
  #pragma unroll
  for (int i=0;i<4;++i)
    #pragma unroll
    for (int j=0;j<4;++j) acc[i][j] = fz;

  for (int kt=0; kt<16; ++kt){
    short* as = As[kt&1]; short* bs = Bs[kt&1];
    #pragma unroll
    for (int c=0;c<2;++c){
      *(short8*)&as[row[c]*40 + seg[c]*8] = ga[c];
      *(short8*)&bs[row[c]*40 + seg[c]*8] = gb[c];
    }
    __syncthreads();
    if (kt < 15){
      int k0 = (kt+1)*32;
      #pragma unroll
      for (int c=0;c<2;++c){
        ga[c] = *(const short8*)(A  + (size_t)(m0+row[c])*DM + k0 + seg[c]*8);
        gb[c] = *(const short8*)(Bt + (size_t)(n0+row[c])*DM + k0 + seg[c]*8);
      }
    }
    short8 bfr[4];
    #pragma unroll
    for (int nf=0;nf<4;++nf)
      bfr[nf] = *(const short8*)&bs[(wc + nf*16 + li)*40 + lg*8];
    __builtin_amdgcn_s_setprio(1);
    #pragma unroll
    for (int mf=0;mf<4;++mf){
      short8 af = *(const short8*)&as[(wr + mf*16 + li)*40 + lg*8];
      #pragma unroll
      for (int nf=0;nf<4;++nf)
        acc[mf][nf] = MFMA16(af, bfr[nf], acc[mf][nf]);
    }
    __builtin_amdgcn_s_setprio(0);
    __syncthreads();
  }

  // epilogue: col n -> head h = n/192; within: [0,64)=Q, [64,128)=K, [128,192)=V(transposed store)
  #pragma unroll
  for (int nf=0;nf<4;++nf){
    int n = n0 + wc + nf*16 + li;
    float bv = bias[n];
    unsigned h  = (unsigned)n / 192u;
    unsigned wn = (unsigned)n % 192u;
    unsigned typ = wn >> 6, d = wn & 63u;
    #pragma unroll
    for (int mf=0;mf<4;++mf){
      #pragma unroll
      for (int j=0;j<4;++j){
        int m  = m0 + wr + mf*16 + lg*4 + j;
        int b  = m >> 10, lp = m & 1023;
        size_t bh = (size_t)(b*8 + (int)h);
        float vf = acc[mf][nf][j] + bv;
        if (typ == 0)      Qo [(bh<<16) + ((size_t)lp<<6)  + d]  = f2bf_fast(vf * 0.18033688f); // 0.125*log2e
        else if (typ == 1) Ko [(bh<<16) + ((size_t)lp<<6)  + d]  = f2bf_fast(vf);
        else               VTo[(bh<<16) + ((size_t)d<<10)  + lp] = f2bf_fast(vf);
      }
    }
  }
}

// ---------------- flash attention: 4 waves x 32 q-rows, swapped QK^T, packed P, dbuf K/V ----------------
__global__ __launch_bounds__(256, 2) void k_attn(
    const short* __restrict__ Q, const short* __restrict__ Kb,
    const short* __restrict__ VT, const float* __restrict__ maskP,
    short* __restrict__ O2)
{
  __shared__ __align__(16) short Ks[2][64*72];
  __shared__ __align__(16) short Vs[2][64*72];
  __shared__ __align__(16) short Ps[4][32*72];
  const int bh = blockIdx.y;
  const int q0 = blockIdx.x*128;
  const int tid = threadIdx.x, w = tid>>6, lane = tid&63, li = lane&15, lg = lane>>4;
  const int qw = q0 + w*32;

  const short* Qp = Q  + ((size_t)bh<<16);
  const short* Kp = Kb + ((size_t)bh<<16);
  const short* Vp = VT + ((size_t)bh<<16);

  // Q as B-operand (col=q=li, k=d), two m-blocks; Q pre-scaled in GEMM1
  short8 qf[2][2];
  #pragma unroll
  for (int mb=0;mb<2;++mb)
    #pragma unroll
    for (int t=0;t<2;++t)
      qf[mb][t] = *(const short8*)(Qp + ((size_t)(qw+mb*16+li)<<6) + t*32 + lg*8);

  short8 ones8;
  #pragma unroll
  for (int e=0;e<8;++e) ones8[e] = (short)0x3f80;   // bf16 1.0

  const f32x4 fz = {0.f,0.f,0.f,0.f};
  f32x4 o[2][4], osum[2];
  #pragma unroll
  for (int mb=0;mb<2;++mb){
    osum[mb] = fz;
    #pragma unroll
    for (int df=0;df<4;++df) o[mb][df] = fz;
  }

  // staging: 256 threads x 2 chunks cover one 64x64 bf16 tile
  int srow[2], sseg[2];
  #pragma unroll
  for (int c=0;c<2;++c){ int f = tid + c*256; srow[c]=f>>3; sseg[c]=(f&7)*8; }

  short8 gk[2], gv[2];
  #pragma unroll
  for (int c=0;c<2;++c){
    gk[c] = *(const short8*)(Kp + ((size_t)srow[c]<<6)  + sseg[c]);
    gv[c] = *(const short8*)(Vp + ((size_t)srow[c]<<10) + sseg[c]);
  }
  #pragma unroll
  for (int c=0;c<2;++c){
    *(short8*)&Ks[0][srow[c]*72 + sseg[c]] = gk[c];
    *(short8*)&Vs[0][srow[c]*72 + sseg[c]] = gv[c];
  }
  #pragma unroll
  for (int c=0;c<2;++c){
    gk[c] = *(const short8*)(Kp + ((size_t)(64+srow[c])<<6) + sseg[c]);
    gv[c] = *(const short8*)(Vp + ((size_t)srow[c]<<10) + 64 + sseg[c]);
  }

  // mask (transposed-fragment, prescaled); register prefetch one tile ahead
  const float* mpb[2];
  #pragma unroll
  for (int mb=0;mb<2;++mb)
    mpb[mb] = maskP + ((size_t)((qw>>4)+mb)<<14) + lane*16;
  f32x4 mnx[2][4];
  #pragma unroll
  for (int mb=0;mb<2;++mb)
    #pragma unroll
    for (int nf=0;nf<4;++nf)
      mnx[mb][nf] = *(const float4_t*)(mpb[mb] + nf*4);

  __syncthreads();

  short* pw = Ps[w];

  for (int kvt=0; kvt<16; ++kvt){
    const short* ks = Ks[kvt&1];
    const short* vs = Vs[kvt&1];
    if (kvt < 15){
      short* kd = Ks[(kvt&1)^1]; short* vd = Vs[(kvt&1)^1];
      #pragma unroll
      for (int c=0;c<2;++c){
        *(short8*)&kd[srow[c]*72 + sseg[c]] = gk[c];
        *(short8*)&vd[srow[c]*72 + sseg[c]] = gv[c];
      }
    }
    if (kvt < 14){
      int nx = (kvt+2)*64;
      #pragma unroll
      for (int c=0;c<2;++c){
        gk[c] = *(const short8*)(Kp + ((size_t)(nx+srow[c])<<6) + sseg[c]);
        gv[c] = *(const short8*)(Vp + ((size_t)srow[c]<<10) + nx + sseg[c]);
      }
    }

    // swapped QK^T: S^T[kv][q] tiles; C-init = prefetched mask regs
    f32x4 s[2][4];
    __builtin_amdgcn_s_setprio(1);
    #pragma unroll
    for (int nf=0;nf<4;++nf){
      short8 kf0 = *(const short8*)&ks[(nf*16+li)*72 + lg*8];
      short8 kf1 = *(const short8*)&ks[(nf*16+li)*72 + 32 + lg*8];
      #pragma unroll
      for (int mb=0;mb<2;++mb){
        s[mb][nf] = MFMA16(kf0, qf[mb][0], mnx[mb][nf]);
        s[mb][nf] = MFMA16(kf1, qf[mb][1], s[mb][nf]);
      }
    }
    __builtin_amdgcn_s_setprio(0);

    // prefetch next tile's mask (consumed next iteration)
    if (kvt < 15){
      #pragma unroll
      for (int mb=0;mb<2;++mb)
        #pragma unroll
        for (int nf=0;nf<4;++nf)
          mnx[mb][nf] = *(const float4_t*)(mpb[mb] + (kvt+1)*1024 + nf*4);
    }

    // p = exp2(s) -> packed bf16 pairs -> Ps[q][kv] (4 b64 writes per mb)
    #pragma unroll
    for (int mb=0;mb<2;++mb){
      #pragma unroll
      for (int nf=0;nf<4;++nf){
        float e0 = exp2f(s[mb][nf][0]), e1 = exp2f(s[mb][nf][1]);
        float e2 = exp2f(s[mb][nf][2]), e3 = exp2f(s[mb][nf][3]);
        unsigned p01, p23;
        asm("v_cvt_pk_bf16_f32 %0, %1, %2" : "=v"(p01) : "v"(e0), "v"(e1));
        asm("v_cvt_pk_bf16_f32 %0, %1, %2" : "=v"(p23) : "v"(e2), "v"(e3));
        u32x2 pv; pv[0]=p01; pv[1]=p23;
        *(u32x2*)&pw[(mb*16+li)*72 + nf*16 + lg*4] = pv;
      }
    }

    // PV: O[32q x 64d] += P @ V ; V-frags shared across both m-blocks
    __builtin_amdgcn_s_setprio(1);
    #pragma unroll
    for (int t=0;t<2;++t){
      short8 pf0 = *(const short8*)&pw[(   li)*72 + t*32 + lg*8];
      short8 pf1 = *(const short8*)&pw[(16+li)*72 + t*32 + lg*8];
      osum[0] = MFMA16(pf0, ones8, osum[0]);
      osum[1] = MFMA16(pf1, ones8, osum[1]);
      #pragma unroll
      for (int df=0;df<4;++df){
        short8 vf = *(const short8*)&vs[(df*16+li)*72 + t*32 + lg*8];
        o[0][df] = MFMA16(pf0, vf, o[0][df]);
        o[1][df] = MFMA16(pf1, vf, o[1][df]);
      }
    }
    __builtin_amdgcn_s_setprio(0);

    __syncthreads();   // buf[cur] reads done + buf[cur^1] stores visible
  }

  // epilogue: O2[b, l, h*64+d] bf16
  int b = bh >> 3, h = bh & 7;
  #pragma unroll
  for (int mb=0;mb<2;++mb){
    float rl[4];
    #pragma unroll
    for (int j=0;j<4;++j) rl[j] = 1.0f / osum[mb][j];
    #pragma unroll
    for (int df=0;df<4;++df)
      #pragma unroll
      for (int j=0;j<4;++j){
        int m   = b*1024 + qw + mb*16 + lg*4 + j;
        int col = h*64 + df*16 + li;
        O2[(size_t)m*512 + col] = f2bf_fast(o[mb][df][j] * rl[j]);
      }
  }
}

// ---------------- GEMM2: O2[8192,512] @ WoT[512,512]^T + bo -> out fp32 ----------------
__global__ __launch_bounds__(256) void k_gemm_out(
    const short* __restrict__ A, const short* __restrict__ Bt,
    const float* __restrict__ bias, float* __restrict__ out)
{
  __shared__ __align__(16) short As[2][128*40];
  __shared__ __align__(16) short Bs[2][128*40];
  const int m0 = blockIdx.x*128, n0 = blockIdx.y*128;
  const int tid = threadIdx.x;
  const int w = tid>>6, lane = tid&63, li = lane&15, lg = lane>>4;
  const int wr = (w>>1)*64, wc = (w&1)*64;

  int row[2], seg[2];
  #pragma unroll
  for (int c=0;c<2;++c){ int s = tid + c*256; row[c]=s>>2; seg[c]=s&3; }

  short8 ga[2], gb[2];
  #pragma unroll
  for (int c=0;c<2;++c){
    ga[c] = *(const short8*)(A  + (size_t)(m0+row[c])*DM + seg[c]*8);
    gb[c] = *(const short8*)(Bt + (size_t)(n0+row[c])*DM + seg[c]*8);
  }

  const f32x4 fz = {0.f,0.f,0.f,0.f};
  f32x4 acc[4][4];
  #pragma unroll
  for (int i=0;i<4;++i)
    #pragma unroll
    for (int j=0;j<4;++j) acc[i][j] = fz;

  for (int kt=0; kt<16; ++kt){
    short* as = As[kt&1]; short* bs = Bs[kt&1];
    #pragma unroll
    for (int c=0;c<2;++c){
      *(short8*)&as[row[c]*40 + seg[c]*8] = ga[c];
      *(short8*)&bs[row[c]*40 + seg[c]*8] = gb[c];
    }
    __syncthreads();
    if (kt < 15){
      int k0 = (kt+1)*32;
      #pragma unroll
      for (int c=0;c<2;++c){
        ga[c] = *(const short8*)(A  + (size_t)(m0+row[c])*DM + k0 + seg[c]*8);
        gb[c] = *(const short8*)(Bt + (size_t)(n0+row[c])*DM + k0 + seg[c]*8);
      }
    }
    short8 bfr[4];
    #pragma unroll
    for (int nf=0;nf<4;++nf)
      bfr[nf] = *(const short8*)&bs[(wc + nf*16 + li)*40 + lg*8];
    __builtin_amdgcn_s_setprio(1);
    #pragma unroll
    for (int mf=0;mf<4;++mf){
      short8 af = *(const short8*)&as[(wr + mf*16 + li)*40 + lg*8];
      #pragma unroll
      for (int nf=0;nf<4;++nf)
        acc[mf][nf] = MFMA16(af, bfr[nf], acc[mf][nf]);
    }
    __builtin_amdgcn_s_setprio(0);
    __syncthreads();
  }

  #pragma unroll
  for (int nf=0;nf<4;++nf){
    int n = n0 + wc + nf*16 + li;
    float bv = bias[n];
    #pragma unroll
    for (int mf=0;mf<4;++mf){
      #pragma unroll
      for (int j=0;j<4;++j){
        int m = m0 + wr + mf*16 + lg*4 + j;
        out[(size_t)m*DM + n] = acc[mf][nf][j] + bv;
      }
    }
  }
}

extern "C" void kernel_launch(void* const* d_in, const int* in_sizes, int n_in,
                              void* d_out, int out_size, void* d_ws, size_t ws_size,
                              hipStream_t stream)
{
  (void)in_sizes; (void)n_in; (void)out_size; (void)ws_size;
  const float* x    = (const float*)d_in[0];
  const float* mask = (const float*)d_in[1];
  const float* Wqkv = (const float*)d_in[2];
  const float* bqkv = (const float*)d_in[3];
  const float* Wo   = (const float*)d_in[4];
  const float* bo   = (const float*)d_in[5];
  float* out = (float*)d_out;

  short* xb    = (short*)d_ws;                    // [8192,512] bf16 (dead after GEMM1)
  short* WqkvT = xb    + (size_t)M_T*DM;          // [1536,512] bf16
  short* WoT   = WqkvT + (size_t)N3*DM;           // [512,512]  bf16
  short* Qb    = WoT   + (size_t)DM*DM;           // [64][1024][64] bf16 (pre-scaled)
  short* Kbf   = Qb    + (size_t)64*1024*64;      // [64][1024][64] bf16
  short* VTb   = Kbf   + (size_t)64*1024*64;      // [64][64][1024] bf16 (V^T)
  short* O2    = VTb   + (size_t)64*1024*64;      // [8192,512] bf16
  float* maskP = (float*)xb;                      // 4MB, aliases xb AFTER GEMM1 consumed it

  k_cvt<<<2048, 256, 0, stream>>>(x, xb, (M_T*DM)/8);
  k_tr2<<<dim3(32, 8), 256, 0, stream>>>(Wqkv, WqkvT, Wo, WoT);
  k_gemm_qkv<<<dim3(M_T/128, N3/128), 256, 0, stream>>>(xb, WqkvT, bqkv, Qb, Kbf, VTb);
  k_maskp<<<1024, 256, 0, stream>>>(mask, maskP);
  k_attn    <<<dim3(L_/128, B_*H_),   256, 0, stream>>>(Qb, Kbf, VTb, maskP, O2);
  k_gemm_out<<<dim3(M_T/128, DM/128), 256, 0, stream>>>(O2, WoT, bo, out);
}

// Round 6
// 84.445 us; speedup vs baseline: 1.4176x; 1.0642x over previous
//
#include <hip/hip_runtime.h>
#include <hip/hip_bf16.h>
#include <stdint.h>

#define B_ 8
#define L_ 1024
#define DM 512
#define H_ 8
#define HD 64
#define N3 1536
#define M_T (B_*L_)        // 8192
#define LOG2E 1.44269504f

typedef __attribute__((ext_vector_type(8))) short short8;    // 8 x bf16 (4 VGPRs)
typedef __attribute__((ext_vector_type(4))) float f32x4;
typedef __attribute__((ext_vector_type(4))) float float4_t;
typedef __attribute__((ext_vector_type(4))) unsigned short ushort4_t;
typedef __attribute__((ext_vector_type(2))) unsigned int u32x2;

#define MFMA16(a,b,c) __builtin_amdgcn_mfma_f32_16x16x32_bf16((a),(b),(c),0,0,0)

// global -> LDS 16B DMA (wave-uniform LDS base + lane*16; per-lane global src)
#define GLL(gp, lp) __builtin_amdgcn_global_load_lds( \
    (const __attribute__((address_space(1))) void*)(gp), \
    (__attribute__((address_space(3))) void*)(lp), 16, 0, 0)

__device__ __forceinline__ short f2bf(float f){            // manual RNE (prep kernels)
  union { float f; unsigned u; } v; v.f = f;
  unsigned r = v.u + 0x7fffu + ((v.u >> 16) & 1u);
  return (short)(r >> 16);
}

__device__ __forceinline__ short f2bf_fast(float f){       // native cvt (hot paths)
  __hip_bfloat16 h = __float2bfloat16(f);
  short s; __builtin_memcpy(&s, &h, 2); return s;
}

// ---------------- x fp32 -> bf16 (vectorized) ----------------
__global__ __launch_bounds__(256) void k_cvt(const float* __restrict__ x,
                                             short* __restrict__ xb, int n8){
  int i = blockIdx.x*256 + threadIdx.x;
  if (i >= n8) return;
  const float4_t* p = (const float4_t*)x + (size_t)i*2;
  float4_t a = p[0], b = p[1];
  short8 o;
  o[0]=f2bf(a[0]); o[1]=f2bf(a[1]); o[2]=f2bf(a[2]); o[3]=f2bf(a[3]);
  o[4]=f2bf(b[0]); o[5]=f2bf(b[1]); o[6]=f2bf(b[2]); o[7]=f2bf(b[3]);
  *((short8*)xb + i) = o;
}

// ---------------- both weight transposes in one launch: W [512][N] fp32 -> WT [N][512] bf16 ----------------
__global__ __launch_bounds__(256) void k_tr2(const float* __restrict__ W0, short* __restrict__ WT0,
                                             const float* __restrict__ W1, short* __restrict__ WT1){
  __shared__ float t[64][65];
  const float* W; short* WT; int N, n0;
  if (blockIdx.x < 24){ W = W0; WT = WT0; N = N3; n0 = blockIdx.x*64; }
  else                { W = W1; WT = WT1; N = DM; n0 = (blockIdx.x-24)*64; }
  int k0 = blockIdx.y*64;
  int tid = threadIdx.x;
  int r = tid >> 4, c4 = (tid & 15) * 4;
  #pragma unroll
  for (int it=0; it<4; ++it){
    int rr = r + it*16;
    float4_t v = *(const float4_t*)(W + (size_t)(k0+rr)*N + n0 + c4);
    t[rr][c4+0]=v[0]; t[rr][c4+1]=v[1]; t[rr][c4+2]=v[2]; t[rr][c4+3]=v[3];
  }
  __syncthreads();
  #pragma unroll
  for (int it=0; it<4; ++it){
    int n = r + it*16;
    ushort4_t o;
    o[0]=(unsigned short)f2bf(t[c4+0][n]);
    o[1]=(unsigned short)f2bf(t[c4+1][n]);
    o[2]=(unsigned short)f2bf(t[c4+2][n]);
    o[3]=(unsigned short)f2bf(t[c4+3][n]);
    *(ushort4_t*)(WT + (size_t)(n0+n)*DM + k0 + c4) = o;
  }
}

// ---------------- mask -> prescaled, TRANSPOSED-fragment layout ----------------
// maskP flat = qg*16384 + kvt*1024 + lane*16 + nf*4 + j
//   value = mask[qg*16 + li][kvt*64 + nf*16 + lg*4 + j] * LOG2E - 17.3123405
__global__ __launch_bounds__(256) void k_maskp(const float* __restrict__ mask,
                                               float* __restrict__ maskP){
  int gid = blockIdx.x*256 + threadIdx.x;        // 262144 threads, 4 floats each
  int nf  = gid & 3;
  int lane= (gid>>2) & 63;
  int kvt = (gid>>8) & 15;
  int qg  = gid>>12;
  int li = lane & 15, lg = lane >> 4;
  int row = qg*16 + li;
  int col = kvt*64 + nf*16 + lg*4;
  float4_t m = *(const float4_t*)(mask + (size_t)row*1024 + col);
  float4_t o;
  #pragma unroll
  for (int j=0;j<4;++j) o[j] = fmaf(m[j], LOG2E, -17.3123405f);
  ((float4_t*)maskP)[gid] = o;
}

// ---------------- GEMM1: m97-style, global_load_lds staging, 1 barrier/K-step ----------------
__global__ __launch_bounds__(256) void k_gemm_qkv(
    const short* __restrict__ A, const short* __restrict__ Bt,
    const float* __restrict__ bias,
    short* __restrict__ Qo, short* __restrict__ Ko, short* __restrict__ VTo)
{
  __shared__ __align__(16) short As[2][128*32];
  __shared__ __align__(16) short Bs[2][128*32];
  const int m0 = blockIdx.x*128, n0 = blockIdx.y*128;
  const int tid = threadIdx.x;
  const int w = tid>>6, lane = tid&63, li = lane&15, lg = lane>>4;
  const int wr = (w>>1)*64, wc = (w&1)*64;

  const int srow0 = tid>>2, sslot0 = tid&3;   // chunk0; chunk1 = row+64, same slot

  #define G1_STAGE(buf, kt) do { \
    GLL(A  + (size_t)(m0+srow0   )*DM + (kt)*32 + sslot0*8, &As[buf][tid*8]); \
    GLL(A  + (size_t)(m0+srow0+64)*DM + (kt)*32 + sslot0*8, &As[buf][(tid+256)*8]); \
    GLL(Bt + (size_t)(n0+srow0   )*DM + (kt)*32 + sslot0*8, &Bs[buf][tid*8]); \
    GLL(Bt + (size_t)(n0+srow0+64)*DM + (kt)*32 + sslot0*8, &Bs[buf][(tid+256)*8]); \
  } while(0)

  const f32x4 fz = {0.f,0.f,0.f,0.f};
  f32x4 acc[4][4];
  #pragma unroll
  for (int i=0;i<4;++i)
    #pragma unroll
    for (int j=0;j<4;++j) acc[i][j] = fz;

  G1_STAGE(0, 0);
  __syncthreads();

  for (int kt=0; kt<16; ++kt){
    const short* as = As[kt&1]; const short* bs = Bs[kt&1];
    if (kt < 15) G1_STAGE((kt&1)^1, kt+1);
    short8 bfr[4];
    #pragma unroll
    for (int nf=0;nf<4;++nf)
      bfr[nf] = *(const short8*)&bs[(wc + nf*16 + li)*32 + lg*8];
    __builtin_amdgcn_s_setprio(1);
    #pragma unroll
    for (int mf=0;mf<4;++mf){
      short8 af = *(const short8*)&as[(wr + mf*16 + li)*32 + lg*8];
      #pragma unroll
      for (int nf=0;nf<4;++nf)
        acc[mf][nf] = MFMA16(af, bfr[nf], acc[mf][nf]);
    }
    __builtin_amdgcn_s_setprio(0);
    __syncthreads();
  }

  // epilogue: col n -> head h = n/192; within: [0,64)=Q, [64,128)=K, [128,192)=V(transposed store)
  #pragma unroll
  for (int nf=0;nf<4;++nf){
    int n = n0 + wc + nf*16 + li;
    float bv = bias[n];
    unsigned h  = (unsigned)n / 192u;
    unsigned wn = (unsigned)n % 192u;
    unsigned typ = wn >> 6, d = wn & 63u;
    #pragma unroll
    for (int mf=0;mf<4;++mf){
      #pragma unroll
      for (int j=0;j<4;++j){
        int m  = m0 + wr + mf*16 + lg*4 + j;
        int b  = m >> 10, lp = m & 1023;
        size_t bh = (size_t)(b*8 + (int)h);
        float vf = acc[mf][nf][j] + bv;
        if (typ == 0)      Qo [(bh<<16) + ((size_t)lp<<6)  + d]  = f2bf_fast(vf * 0.18033688f); // 0.125*log2e
        else if (typ == 1) Ko [(bh<<16) + ((size_t)lp<<6)  + d]  = f2bf_fast(vf);
        else               VTo[(bh<<16) + ((size_t)d<<10)  + lp] = f2bf_fast(vf);
      }
    }
  }
  #undef G1_STAGE
}

// ---------------- flash attention: gload_lds K/V staging + XOR swizzle + XCD-local blocks ----------------
__global__ __launch_bounds__(256, 2) void k_attn(
    const short* __restrict__ Q, const short* __restrict__ Kb,
    const short* __restrict__ VT, const float* __restrict__ maskP,
    short* __restrict__ O2)
{
  __shared__ __align__(16) short Ks[2][64*64];   // linear [kv][d], source-swizzled
  __shared__ __align__(16) short Vs[2][64*64];   // linear [d][kv], source-swizzled
  __shared__ __align__(16) short Ps[4][32*72];

  // XCD-local decode: all 8 q-blocks of a bh land on one XCD (hw xcd = id & 7)
  const int id  = blockIdx.x;
  const int bh  = (id & 7)*8 + ((id >> 3) & 7);
  const int q0  = (id >> 6) * 128;

  const int tid = threadIdx.x, w = tid>>6, lane = tid&63, li = lane&15, lg = lane>>4;
  const int qw = q0 + w*32;

  const short* Qp = Q  + ((size_t)bh<<16);
  const short* Kp = Kb + ((size_t)bh<<16);
  const short* Vp = VT + ((size_t)bh<<16);

  // staging chunk geometry: chunk c covers (row=c>>3, lds slot=c&7); global slot = lds slot ^ (row&7)
  const int arow0 = tid>>3;
  const int ags0  = (tid&7) ^ (arow0&7);         // chunk1: row+32 -> same (row&7), same gslot

  #define ATTN_STAGE(buf, nx) do { \
    GLL(Kp + ((size_t)((nx)+arow0   )<<6) + ags0*8, &Ks[buf][tid*8]); \
    GLL(Kp + ((size_t)((nx)+arow0+32)<<6) + ags0*8, &Ks[buf][(tid+256)*8]); \
    GLL(Vp + ((size_t)(arow0   )<<10) + (nx) + ags0*8, &Vs[buf][tid*8]); \
    GLL(Vp + ((size_t)(arow0+32)<<10) + (nx) + ags0*8, &Vs[buf][(tid+256)*8]); \
  } while(0)

  // Q as B-operand (col=q=li, k=d), two m-blocks; Q pre-scaled in GEMM1
  short8 qf[2][2];
  #pragma unroll
  for (int mb=0;mb<2;++mb)
    #pragma unroll
    for (int t=0;t<2;++t)
      qf[mb][t] = *(const short8*)(Qp + ((size_t)(qw+mb*16+li)<<6) + t*32 + lg*8);

  short8 ones8;
  #pragma unroll
  for (int e=0;e<8;++e) ones8[e] = (short)0x3f80;   // bf16 1.0

  const f32x4 fz = {0.f,0.f,0.f,0.f};
  f32x4 o[2][4], osum[2];
  #pragma unroll
  for (int mb=0;mb<2;++mb){
    osum[mb] = fz;
    #pragma unroll
    for (int df=0;df<4;++df) o[mb][df] = fz;
  }

  // mask (transposed-fragment, prescaled); register prefetch one tile ahead
  const float* mpb[2];
  #pragma unroll
  for (int mb=0;mb<2;++mb)
    mpb[mb] = maskP + ((size_t)((qw>>4)+mb)<<14) + lane*16;
  f32x4 mnx[2][4];
  #pragma unroll
  for (int mb=0;mb<2;++mb)
    #pragma unroll
    for (int nf=0;nf<4;++nf)
      mnx[mb][nf] = *(const float4_t*)(mpb[mb] + nf*4);

  ATTN_STAGE(0, 0);
  __syncthreads();     // drains vmcnt -> tile 0 staged

  short* pw = Ps[w];
  const int sw = li & 7;

  for (int kvt=0; kvt<16; ++kvt){
    const short* ks = Ks[kvt&1];
    const short* vs = Vs[kvt&1];
    if (kvt < 15) ATTN_STAGE((kvt&1)^1, (kvt+1)*64);

    // swapped QK^T: S^T[kv][q] tiles; C-init = prefetched mask regs
    f32x4 s[2][4];
    __builtin_amdgcn_s_setprio(1);
    #pragma unroll
    for (int nf=0;nf<4;++nf){
      short8 kf0 = *(const short8*)&ks[(nf*16+li)*64 + ((  lg)^sw)*8];
      short8 kf1 = *(const short8*)&ks[(nf*16+li)*64 + ((4|lg)^sw)*8];
      #pragma unroll
      for (int mb=0;mb<2;++mb){
        s[mb][nf] = MFMA16(kf0, qf[mb][0], mnx[mb][nf]);
        s[mb][nf] = MFMA16(kf1, qf[mb][1], s[mb][nf]);
      }
    }
    __builtin_amdgcn_s_setprio(0);

    // prefetch next tile's mask (consumed next iteration)
    if (kvt < 15){
      #pragma unroll
      for (int mb=0;mb<2;++mb)
        #pragma unroll
        for (int nf=0;nf<4;++nf)
          mnx[mb][nf] = *(const float4_t*)(mpb[mb] + (kvt+1)*1024 + nf*4);
    }

    // p = exp2(s) -> packed bf16 pairs -> Ps[q][kv] (4 b64 writes per mb)
    #pragma unroll
    for (int mb=0;mb<2;++mb){
      #pragma unroll
      for (int nf=0;nf<4;++nf){
        float e0 = __builtin_amdgcn_exp2f(s[mb][nf][0]);
        float e1 = __builtin_amdgcn_exp2f(s[mb][nf][1]);
        float e2 = __builtin_amdgcn_exp2f(s[mb][nf][2]);
        float e3 = __builtin_amdgcn_exp2f(s[mb][nf][3]);
        unsigned p01, p23;
        asm("v_cvt_pk_bf16_f32 %0, %1, %2" : "=v"(p01) : "v"(e0), "v"(e1));
        asm("v_cvt_pk_bf16_f32 %0, %1, %2" : "=v"(p23) : "v"(e2), "v"(e3));
        u32x2 pv; pv[0]=p01; pv[1]=p23;
        *(u32x2*)&pw[(mb*16+li)*72 + nf*16 + lg*4] = pv;
      }
    }

    // PV: O[32q x 64d] += P @ V ; V-frags shared across both m-blocks
    __builtin_amdgcn_s_setprio(1);
    #pragma unroll
    for (int t=0;t<2;++t){
      short8 pf0 = *(const short8*)&pw[(   li)*72 + t*32 + lg*8];
      short8 pf1 = *(const short8*)&pw[(16+li)*72 + t*32 + lg*8];
      osum[0] = MFMA16(pf0, ones8, osum[0]);
      osum[1] = MFMA16(pf1, ones8, osum[1]);
      #pragma unroll
      for (int df=0;df<4;++df){
        short8 vf = *(const short8*)&vs[(df*16+li)*64 + (((t<<2)|lg)^sw)*8];
        o[0][df] = MFMA16(pf0, vf, o[0][df]);
        o[1][df] = MFMA16(pf1, vf, o[1][df]);
      }
    }
    __builtin_amdgcn_s_setprio(0);

    __syncthreads();   // buf[cur] reads done + buf[cur^1] DMA drained (vmcnt 0 at barrier)
  }
  #undef ATTN_STAGE

  // epilogue: O2[b, l, h*64+d] bf16
  int b = bh >> 3, h = bh & 7;
  #pragma unroll
  for (int mb=0;mb<2;++mb){
    float rl[4];
    #pragma unroll
    for (int j=0;j<4;++j) rl[j] = 1.0f / osum[mb][j];
    #pragma unroll
    for (int df=0;df<4;++df)
      #pragma unroll
      for (int j=0;j<4;++j){
        int m   = b*1024 + qw + mb*16 + lg*4 + j;
        int col = h*64 + df*16 + li;
        O2[(size_t)m*512 + col] = f2bf_fast(o[mb][df][j] * rl[j]);
      }
  }
}

// ---------------- GEMM2: O2[8192,512] @ WoT[512,512]^T + bo -> out fp32 ----------------
__global__ __launch_bounds__(256) void k_gemm_out(
    const short* __restrict__ A, const short* __restrict__ Bt,
    const float* __restrict__ bias, float* __restrict__ out)
{
  __shared__ __align__(16) short As[2][128*32];
  __shared__ __align__(16) short Bs[2][128*32];
  const int m0 = blockIdx.x*128, n0 = blockIdx.y*128;
  const int tid = threadIdx.x;
  const int w = tid>>6, lane = tid&63, li = lane&15, lg = lane>>4;
  const int wr = (w>>1)*64, wc = (w&1)*64;

  const int srow0 = tid>>2, sslot0 = tid&3;

  #define G2_STAGE(buf, kt) do { \
    GLL(A  + (size_t)(m0+srow0   )*DM + (kt)*32 + sslot0*8, &As[buf][tid*8]); \
    GLL(A  + (size_t)(m0+srow0+64)*DM + (kt)*32 + sslot0*8, &As[buf][(tid+256)*8]); \
    GLL(Bt + (size_t)(n0+srow0   )*DM + (kt)*32 + sslot0*8, &Bs[buf][tid*8]); \
    GLL(Bt + (size_t)(n0+srow0+64)*DM + (kt)*32 + sslot0*8, &Bs[buf][(tid+256)*8]); \
  } while(0)

  const f32x4 fz = {0.f,0.f,0.f,0.f};
  f32x4 acc[4][4];
  #pragma unroll
  for (int i=0;i<4;++i)
    #pragma unroll
    for (int j=0;j<4;++j) acc[i][j] = fz;

  G2_STAGE(0, 0);
  __syncthreads();

  for (int kt=0; kt<16; ++kt){
    const short* as = As[kt&1]; const short* bs = Bs[kt&1];
    if (kt < 15) G2_STAGE((kt&1)^1, kt+1);
    short8 bfr[4];
    #pragma unroll
    for (int nf=0;nf<4;++nf)
      bfr[nf] = *(const short8*)&bs[(wc + nf*16 + li)*32 + lg*8];
    __builtin_amdgcn_s_setprio(1);
    #pragma unroll
    for (int mf=0;mf<4;++mf){
      short8 af = *(const short8*)&as[(wr + mf*16 + li)*32 + lg*8];
      #pragma unroll
      for (int nf=0;nf<4;++nf)
        acc[mf][nf] = MFMA16(af, bfr[nf], acc[mf][nf]);
    }
    __builtin_amdgcn_s_setprio(0);
    __syncthreads();
  }

  #pragma unroll
  for (int nf=0;nf<4;++nf){
    int n = n0 + wc + nf*16 + li;
    float bv = bias[n];
    #pragma unroll
    for (int mf=0;mf<4;++mf){
      #pragma unroll
      for (int j=0;j<4;++j){
        int m = m0 + wr + mf*16 + lg*4 + j;
        out[(size_t)m*DM + n] = acc[mf][nf][j] + bv;
      }
    }
  }
  #undef G2_STAGE
}

extern "C" void kernel_launch(void* const* d_in, const int* in_sizes, int n_in,
                              void* d_out, int out_size, void* d_ws, size_t ws_size,
                              hipStream_t stream)
{
  (void)in_sizes; (void)n_in; (void)out_size; (void)ws_size;
  const float* x    = (const float*)d_in[0];
  const float* mask = (const float*)d_in[1];
  const float* Wqkv = (const float*)d_in[2];
  const float* bqkv = (const float*)d_in[3];
  const float* Wo   = (const float*)d_in[4];
  const float* bo   = (const float*)d_in[5];
  float* out = (float*)d_out;

  short* xb    = (short*)d_ws;                    // [8192,512] bf16 (dead after GEMM1)
  short* WqkvT = xb    + (size_t)M_T*DM;          // [1536,512] bf16
  short* WoT   = WqkvT + (size_t)N3*DM;           // [512,512]  bf16
  short* Qb    = WoT   + (size_t)DM*DM;           // [64][1024][64] bf16 (pre-scaled)
  short* Kbf   = Qb    + (size_t)64*1024*64;      // [64][1024][64] bf16
  short* VTb   = Kbf   + (size_t)64*1024*64;      // [64][64][1024] bf16 (V^T)
  short* O2    = VTb   + (size_t)64*1024*64;      // [8192,512] bf16
  float* maskP = (float*)xb;                      // 4MB, aliases xb AFTER GEMM1 consumed it

  k_cvt<<<2048, 256, 0, stream>>>(x, xb, (M_T*DM)/8);
  k_tr2<<<dim3(32, 8), 256, 0, stream>>>(Wqkv, WqkvT, Wo, WoT);
  k_gemm_qkv<<<dim3(M_T/128, N3/128), 256, 0, stream>>>(xb, WqkvT, bqkv, Qb, Kbf, VTb);
  k_maskp<<<1024, 256, 0, stream>>>(mask, maskP);
  k_attn    <<<512, 256, 0, stream>>>(Qb, Kbf, VTb, maskP, O2);
  k_gemm_out<<<dim3(M_T/128, DM/128), 256, 0, stream>>>(O2, WoT, bo, out);
}

// Round 9
// 82.297 us; speedup vs baseline: 1.4545x; 1.0261x over previous
//
#include <hip/hip_runtime.h>
#include <hip/hip_bf16.h>
#include <stdint.h>

#define B_ 8
#define L_ 1024
#define DM 512
#define H_ 8
#define HD 64
#define N3 1536
#define M_T (B_*L_)        // 8192
#define LOG2E 1.44269504f

typedef __attribute__((ext_vector_type(8))) short short8;    // 8 x bf16 (4 VGPRs)
typedef __attribute__((ext_vector_type(4))) float f32x4;
typedef __attribute__((ext_vector_type(4))) float float4_t;
typedef __attribute__((ext_vector_type(4))) unsigned short ushort4_t;
typedef __attribute__((ext_vector_type(2))) unsigned int u32x2;

#define MFMA16(a,b,c) __builtin_amdgcn_mfma_f32_16x16x32_bf16((a),(b),(c),0,0,0)

// global -> LDS 16B DMA (wave-uniform LDS base + lane*16; per-lane global src)
#define GLL(gp, lp) __builtin_amdgcn_global_load_lds( \
    (const __attribute__((address_space(1))) void*)(gp), \
    (__attribute__((address_space(3))) void*)(lp), 16, 0, 0)

__device__ __forceinline__ short f2bf(float f){            // manual RNE (prep)
  union { float f; unsigned u; } v; v.f = f;
  unsigned r = v.u + 0x7fffu + ((v.u >> 16) & 1u);
  return (short)(r >> 16);
}

__device__ __forceinline__ short f2bf_fast(float f){       // native cvt (hot paths)
  __hip_bfloat16 h = __float2bfloat16(f);
  short s; __builtin_memcpy(&s, &h, 2); return s;
}

// ---------------- fused prep: x->bf16 | both weight transposes ----------------
// blocks [0,2048): cvt; [2048,2304): transposes
__global__ __launch_bounds__(256) void k_prep(
    const float* __restrict__ x,  short* __restrict__ xb,
    const float* __restrict__ W0, short* __restrict__ WT0,
    const float* __restrict__ W1, short* __restrict__ WT1)
{
  __shared__ float t[64][65];
  const int blk = blockIdx.x, tid = threadIdx.x;

  if (blk < 2048){                                  // ---- x fp32 -> bf16
    int i = blk*256 + tid;
    const float4_t* p = (const float4_t*)x + (size_t)i*2;
    float4_t a = p[0], b = p[1];
    short8 o;
    o[0]=f2bf(a[0]); o[1]=f2bf(a[1]); o[2]=f2bf(a[2]); o[3]=f2bf(a[3]);
    o[4]=f2bf(b[0]); o[5]=f2bf(b[1]); o[6]=f2bf(b[2]); o[7]=f2bf(b[3]);
    *((short8*)xb + i) = o;
    return;
  }
  // ---- W [512][N] fp32 -> WT [N][512] bf16 (both weights)
  int idx = blk - 2048;                             // [0,256)
  int bx = idx & 31, by = idx >> 5;
  const float* W; short* WT; int N, n0;
  if (bx < 24){ W = W0; WT = WT0; N = N3; n0 = bx*64; }
  else        { W = W1; WT = WT1; N = DM; n0 = (bx-24)*64; }
  int k0 = by*64;
  int r = tid >> 4, c4 = (tid & 15) * 4;
  #pragma unroll
  for (int it=0; it<4; ++it){
    int rr = r + it*16;
    float4_t v = *(const float4_t*)(W + (size_t)(k0+rr)*N + n0 + c4);
    t[rr][c4+0]=v[0]; t[rr][c4+1]=v[1]; t[rr][c4+2]=v[2]; t[rr][c4+3]=v[3];
  }
  __syncthreads();
  #pragma unroll
  for (int it=0; it<4; ++it){
    int n = r + it*16;
    ushort4_t o;
    o[0]=(unsigned short)f2bf(t[c4+0][n]);
    o[1]=(unsigned short)f2bf(t[c4+1][n]);
    o[2]=(unsigned short)f2bf(t[c4+2][n]);
    o[3]=(unsigned short)f2bf(t[c4+3][n]);
    *(ushort4_t*)(WT + (size_t)(n0+n)*DM + k0 + c4) = o;
  }
}

// ---------------- mask -> prescaled, TRANSPOSED-fragment layout ----------------
// maskP flat = qg*16384 + kvt*1024 + lane*16 + nf*4 + j
//   value = mask[qg*16 + li][kvt*64 + nf*16 + lg*4 + j] * LOG2E - 17.3123405
__global__ __launch_bounds__(256) void k_maskp(const float* __restrict__ mask,
                                               float* __restrict__ maskP){
  int gid = blockIdx.x*256 + threadIdx.x;        // 262144 threads, 4 floats each
  int nf  = gid & 3;
  int lane= (gid>>2) & 63;
  int kvt = (gid>>8) & 15;
  int qg  = gid>>12;
  int li = lane & 15, lg = lane >> 4;
  int row = qg*16 + li;
  int col = kvt*64 + nf*16 + lg*4;
  float4_t m = *(const float4_t*)(mask + (size_t)row*1024 + col);
  float4_t o;
  #pragma unroll
  for (int j=0;j<4;++j) o[j] = fmaf(m[j], LOG2E, -17.3123405f);
  ((float4_t*)maskP)[gid] = o;
}

// ---------------- GEMM1: gload_lds staging + XOR-4 LDS swizzle, 1 barrier/K-step ----------------
__global__ __launch_bounds__(256) void k_gemm_qkv(
    const short* __restrict__ A, const short* __restrict__ Bt,
    const float* __restrict__ bias,
    short* __restrict__ Qo, short* __restrict__ Ko, short* __restrict__ VTo)
{
  __shared__ __align__(16) short As[2][128*32];
  __shared__ __align__(16) short Bs[2][128*32];
  const int m0 = blockIdx.x*128, n0 = blockIdx.y*128;
  const int tid = threadIdx.x;
  const int w = tid>>6, lane = tid&63, li = lane&15, lg = lane>>4;
  const int wr = (w>>1)*64, wc = (w&1)*64;

  // staging: chunk c -> lds row c>>2, lds slot c&3; global slot = (c&3)^(row&3)
  const int r0 = tid>>2;
  const int s0 = (tid&3) ^ (r0&3);       // chunk1 (row+64): row&3 identical -> same s0
  const int swz = li&3;                  // read-side xor

  #define G1_STAGE(buf, kt) do { \
    GLL(A  + (size_t)(m0+r0   )*DM + (kt)*32 + s0*8, &As[buf][tid*8]); \
    GLL(A  + (size_t)(m0+r0+64)*DM + (kt)*32 + s0*8, &As[buf][(tid+256)*8]); \
    GLL(Bt + (size_t)(n0+r0   )*DM + (kt)*32 + s0*8, &Bs[buf][tid*8]); \
    GLL(Bt + (size_t)(n0+r0+64)*DM + (kt)*32 + s0*8, &Bs[buf][(tid+256)*8]); \
  } while(0)

  const f32x4 fz = {0.f,0.f,0.f,0.f};
  f32x4 acc[4][4];
  #pragma unroll
  for (int i=0;i<4;++i)
    #pragma unroll
    for (int j=0;j<4;++j) acc[i][j] = fz;

  G1_STAGE(0, 0);
  __syncthreads();

  for (int kt=0; kt<16; ++kt){
    const short* as = As[kt&1]; const short* bs = Bs[kt&1];
    if (kt < 15) G1_STAGE((kt&1)^1, kt+1);
    short8 bfr[4];
    #pragma unroll
    for (int nf=0;nf<4;++nf)
      bfr[nf] = *(const short8*)&bs[(wc + nf*16 + li)*32 + (lg^swz)*8];
    __builtin_amdgcn_s_setprio(1);
    #pragma unroll
    for (int mf=0;mf<4;++mf){
      short8 af = *(const short8*)&as[(wr + mf*16 + li)*32 + (lg^swz)*8];
      #pragma unroll
      for (int nf=0;nf<4;++nf)
        acc[mf][nf] = MFMA16(af, bfr[nf], acc[mf][nf]);
    }
    __builtin_amdgcn_s_setprio(0);
    __syncthreads();
  }

  // epilogue: col n -> head h = n/192; within: [0,64)=Q, [64,128)=K, [128,192)=V(transposed store)
  #pragma unroll
  for (int nf=0;nf<4;++nf){
    int n = n0 + wc + nf*16 + li;
    float bv = bias[n];
    unsigned h  = (unsigned)n / 192u;
    unsigned wn = (unsigned)n % 192u;
    unsigned typ = wn >> 6, d = wn & 63u;
    #pragma unroll
    for (int mf=0;mf<4;++mf){
      #pragma unroll
      for (int j=0;j<4;++j){
        int m  = m0 + wr + mf*16 + lg*4 + j;
        int b  = m >> 10, lp = m & 1023;
        size_t bh = (size_t)(b*8 + (int)h);
        float vf = acc[mf][nf][j] + bv;
        if (typ == 0)      Qo [(bh<<16) + ((size_t)lp<<6)  + d]  = f2bf_fast(vf * 0.18033688f); // 0.125*log2e
        else if (typ == 1) Ko [(bh<<16) + ((size_t)lp<<6)  + d]  = f2bf_fast(vf);
        else               VTo[(bh<<16) + ((size_t)d<<10)  + lp] = f2bf_fast(vf);
      }
    }
  }
  #undef G1_STAGE
}

// ---------------- flash attention (R6-proven): gload_lds K/V + XOR swizzle + XCD-local, P via LDS ----------------
__global__ __launch_bounds__(256, 2) void k_attn(
    const short* __restrict__ Q, const short* __restrict__ Kb,
    const short* __restrict__ VT, const float* __restrict__ maskP,
    short* __restrict__ O2)
{
  __shared__ __align__(16) short Ks[2][64*64];   // linear [kv][d], source-swizzled
  __shared__ __align__(16) short Vs[2][64*64];   // linear [d][kv], source-swizzled
  __shared__ __align__(16) short Ps[4][32*72];

  // XCD-local decode: all 8 q-blocks of a bh land on one XCD (hw xcd = id & 7)
  const int id  = blockIdx.x;
  const int bh  = (id & 7)*8 + ((id >> 3) & 7);
  const int q0  = (id >> 6) * 128;

  const int tid = threadIdx.x, w = tid>>6, lane = tid&63, li = lane&15, lg = lane>>4;
  const int qw = q0 + w*32;

  const short* Qp = Q  + ((size_t)bh<<16);
  const short* Kp = Kb + ((size_t)bh<<16);
  const short* Vp = VT + ((size_t)bh<<16);

  // staging chunk geometry: chunk c covers (row=c>>3, lds slot=c&7); global slot = lds slot ^ (row&7)
  const int arow0 = tid>>3;
  const int ags0  = (tid&7) ^ (arow0&7);         // chunk1: row+32 -> same (row&7), same gslot

  #define ATTN_STAGE(buf, nx) do { \
    GLL(Kp + ((size_t)((nx)+arow0   )<<6) + ags0*8, &Ks[buf][tid*8]); \
    GLL(Kp + ((size_t)((nx)+arow0+32)<<6) + ags0*8, &Ks[buf][(tid+256)*8]); \
    GLL(Vp + ((size_t)(arow0   )<<10) + (nx) + ags0*8, &Vs[buf][tid*8]); \
    GLL(Vp + ((size_t)(arow0+32)<<10) + (nx) + ags0*8, &Vs[buf][(tid+256)*8]); \
  } while(0)

  // Q as B-operand (col=q=li, k=d), two m-blocks; Q pre-scaled in GEMM1
  short8 qf[2][2];
  #pragma unroll
  for (int mb=0;mb<2;++mb)
    #pragma unroll
    for (int t=0;t<2;++t)
      qf[mb][t] = *(const short8*)(Qp + ((size_t)(qw+mb*16+li)<<6) + t*32 + lg*8);

  short8 ones8;
  #pragma unroll
  for (int e=0;e<8;++e) ones8[e] = (short)0x3f80;   // bf16 1.0

  const f32x4 fz = {0.f,0.f,0.f,0.f};
  f32x4 o[2][4], osum[2];
  #pragma unroll
  for (int mb=0;mb<2;++mb){
    osum[mb] = fz;
    #pragma unroll
    for (int df=0;df<4;++df) o[mb][df] = fz;
  }

  // mask (transposed-fragment, prescaled); register prefetch one tile ahead
  const float* mpb[2];
  #pragma unroll
  for (int mb=0;mb<2;++mb)
    mpb[mb] = maskP + ((size_t)((qw>>4)+mb)<<14) + lane*16;
  f32x4 mnx[2][4];
  #pragma unroll
  for (int mb=0;mb<2;++mb)
    #pragma unroll
    for (int nf=0;nf<4;++nf)
      mnx[mb][nf] = *(const float4_t*)(mpb[mb] + nf*4);

  ATTN_STAGE(0, 0);
  __syncthreads();     // drains vmcnt -> tile 0 staged

  const int sw = li & 7;
  short* pw = Ps[w];

  for (int kvt=0; kvt<16; ++kvt){
    const short* ks = Ks[kvt&1];
    const short* vs = Vs[kvt&1];
    if (kvt < 15) ATTN_STAGE((kvt&1)^1, (kvt+1)*64);

    // swapped QK^T: S^T[kv][q] tiles; C-init = prefetched mask regs
    f32x4 s[2][4];
    __builtin_amdgcn_s_setprio(1);
    #pragma unroll
    for (int nf=0;nf<4;++nf){
      short8 kf0 = *(const short8*)&ks[(nf*16+li)*64 + ((  lg)^sw)*8];
      short8 kf1 = *(const short8*)&ks[(nf*16+li)*64 + ((4|lg)^sw)*8];
      #pragma unroll
      for (int mb=0;mb<2;++mb){
        s[mb][nf] = MFMA16(kf0, qf[mb][0], mnx[mb][nf]);
        s[mb][nf] = MFMA16(kf1, qf[mb][1], s[mb][nf]);
      }
    }
    __builtin_amdgcn_s_setprio(0);

    // prefetch next tile's mask (consumed next iteration)
    if (kvt < 15){
      #pragma unroll
      for (int mb=0;mb<2;++mb)
        #pragma unroll
        for (int nf=0;nf<4;++nf)
          mnx[mb][nf] = *(const float4_t*)(mpb[mb] + (kvt+1)*1024 + nf*4);
    }

    // p = exp2(s) -> packed bf16 pairs -> Ps[q][kv] (b64 writes)
    #pragma unroll
    for (int mb=0;mb<2;++mb){
      #pragma unroll
      for (int nf=0;nf<4;++nf){
        float e0 = __builtin_amdgcn_exp2f(s[mb][nf][0]);
        float e1 = __builtin_amdgcn_exp2f(s[mb][nf][1]);
        float e2 = __builtin_amdgcn_exp2f(s[mb][nf][2]);
        float e3 = __builtin_amdgcn_exp2f(s[mb][nf][3]);
        unsigned p01, p23;
        asm("v_cvt_pk_bf16_f32 %0, %1, %2" : "=v"(p01) : "v"(e0), "v"(e1));
        asm("v_cvt_pk_bf16_f32 %0, %1, %2" : "=v"(p23) : "v"(e2), "v"(e3));
        u32x2 pv; pv[0]=p01; pv[1]=p23;
        *(u32x2*)&pw[(mb*16+li)*72 + nf*16 + lg*4] = pv;
      }
    }

    // PV: O[32q x 64d] += P @ V ; V-frags shared across both m-blocks
    __builtin_amdgcn_s_setprio(1);
    #pragma unroll
    for (int t=0;t<2;++t){
      short8 pf0 = *(const short8*)&pw[(   li)*72 + t*32 + lg*8];
      short8 pf1 = *(const short8*)&pw[(16+li)*72 + t*32 + lg*8];
      osum[0] = MFMA16(pf0, ones8, osum[0]);
      osum[1] = MFMA16(pf1, ones8, osum[1]);
      #pragma unroll
      for (int df=0;df<4;++df){
        short8 vf = *(const short8*)&vs[(df*16+li)*64 + (((t<<2)|lg)^sw)*8];
        o[0][df] = MFMA16(pf0, vf, o[0][df]);
        o[1][df] = MFMA16(pf1, vf, o[1][df]);
      }
    }
    __builtin_amdgcn_s_setprio(0);

    __syncthreads();   // buf[cur] reads done + buf[cur^1] DMA drained (vmcnt 0 at barrier)
  }
  #undef ATTN_STAGE

  // epilogue: O2[b, l, h*64+d] bf16
  int b = bh >> 3, h = bh & 7;
  #pragma unroll
  for (int mb=0;mb<2;++mb){
    float rl[4];
    #pragma unroll
    for (int j=0;j<4;++j) rl[j] = 1.0f / osum[mb][j];
    #pragma unroll
    for (int df=0;df<4;++df)
      #pragma unroll
      for (int j=0;j<4;++j){
        int m   = b*1024 + qw + mb*16 + lg*4 + j;
        int col = h*64 + df*16 + li;
        O2[(size_t)m*512 + col] = f2bf_fast(o[mb][df][j] * rl[j]);
      }
  }
}

// ---------------- GEMM2: O2[8192,512] @ WoT[512,512]^T + bo -> out fp32 ----------------
__global__ __launch_bounds__(256) void k_gemm_out(
    const short* __restrict__ A, const short* __restrict__ Bt,
    const float* __restrict__ bias, float* __restrict__ out)
{
  __shared__ __align__(16) short As[2][128*32];
  __shared__ __align__(16) short Bs[2][128*32];
  const int m0 = blockIdx.x*128, n0 = blockIdx.y*128;
  const int tid = threadIdx.x;
  const int w = tid>>6, lane = tid&63, li = lane&15, lg = lane>>4;
  const int wr = (w>>1)*64, wc = (w&1)*64;

  const int r0 = tid>>2;
  const int s0 = (tid&3) ^ (r0&3);
  const int swz = li&3;

  #define G2_STAGE(buf, kt) do { \
    GLL(A  + (size_t)(m0+r0   )*DM + (kt)*32 + s0*8, &As[buf][tid*8]); \
    GLL(A  + (size_t)(m0+r0+64)*DM + (kt)*32 + s0*8, &As[buf][(tid+256)*8]); \
    GLL(Bt + (size_t)(n0+r0   )*DM + (kt)*32 + s0*8, &Bs[buf][tid*8]); \
    GLL(Bt + (size_t)(n0+r0+64)*DM + (kt)*32 + s0*8, &Bs[buf][(tid+256)*8]); \
  } while(0)

  const f32x4 fz = {0.f,0.f,0.f,0.f};
  f32x4 acc[4][4];
  #pragma unroll
  for (int i=0;i<4;++i)
    #pragma unroll
    for (int j=0;j<4;++j) acc[i][j] = fz;

  G2_STAGE(0, 0);
  __syncthreads();

  for (int kt=0; kt<16; ++kt){
    const short* as = As[kt&1]; const short* bs = Bs[kt&1];
    if (kt < 15) G2_STAGE((kt&1)^1, kt+1);
    short8 bfr[4];
    #pragma unroll
    for (int nf=0;nf<4;++nf)
      bfr[nf] = *(const short8*)&bs[(wc + nf*16 + li)*32 + (lg^swz)*8];
    __builtin_amdgcn_s_setprio(1);
    #pragma unroll
    for (int mf=0;mf<4;++mf){
      short8 af = *(const short8*)&as[(wr + mf*16 + li)*32 + (lg^swz)*8];
      #pragma unroll
      for (int nf=0;nf<4;++nf)
        acc[mf][nf] = MFMA16(af, bfr[nf], acc[mf][nf]);
    }
    __builtin_amdgcn_s_setprio(0);
    __syncthreads();
  }

  #pragma unroll
  for (int nf=0;nf<4;++nf){
    int n = n0 + wc + nf*16 + li;
    float bv = bias[n];
    #pragma unroll
    for (int mf=0;mf<4;++mf){
      #pragma unroll
      for (int j=0;j<4;++j){
        int m = m0 + wr + mf*16 + lg*4 + j;
        out[(size_t)m*DM + n] = acc[mf][nf][j] + bv;
      }
    }
  }
  #undef G2_STAGE
}

extern "C" void kernel_launch(void* const* d_in, const int* in_sizes, int n_in,
                              void* d_out, int out_size, void* d_ws, size_t ws_size,
                              hipStream_t stream)
{
  (void)in_sizes; (void)n_in; (void)out_size; (void)ws_size;
  const float* x    = (const float*)d_in[0];
  const float* mask = (const float*)d_in[1];
  const float* Wqkv = (const float*)d_in[2];
  const float* bqkv = (const float*)d_in[3];
  const float* Wo   = (const float*)d_in[4];
  const float* bo   = (const float*)d_in[5];
  float* out = (float*)d_out;

  short* xb    = (short*)d_ws;                    // [8192,512] bf16 (dead after GEMM1)
  short* WqkvT = xb    + (size_t)M_T*DM;          // [1536,512] bf16
  short* WoT   = WqkvT + (size_t)N3*DM;           // [512,512]  bf16
  short* Qb    = WoT   + (size_t)DM*DM;           // [64][1024][64] bf16 (pre-scaled)
  short* Kbf   = Qb    + (size_t)64*1024*64;      // [64][1024][64] bf16
  short* VTb   = Kbf   + (size_t)64*1024*64;      // [64][64][1024] bf16 (V^T)
  short* O2    = VTb   + (size_t)64*1024*64;      // [8192,512] bf16
  float* maskP = (float*)xb;                      // 4MB, aliases xb AFTER GEMM1 consumed it

  k_prep<<<2304, 256, 0, stream>>>(x, xb, Wqkv, WqkvT, Wo, WoT);
  k_gemm_qkv<<<dim3(M_T/128, N3/128), 256, 0, stream>>>(xb, WqkvT, bqkv, Qb, Kbf, VTb);
  k_maskp<<<1024, 256, 0, stream>>>(mask, maskP);
  k_attn    <<<512, 256, 0, stream>>>(Qb, Kbf, VTb, maskP, O2);
  k_gemm_out<<<dim3(M_T/128, DM/128), 256, 0, stream>>>(O2, WoT, bo, out);
}

// Round 10
// 80.150 us; speedup vs baseline: 1.4935x; 1.0268x over previous
//
#include <hip/hip_runtime.h>
#include <hip/hip_bf16.h>
#include <stdint.h>

#define B_ 8
#define L_ 1024
#define DM 512
#define H_ 8
#define HD 64
#define N3 1536
#define M_T (B_*L_)        // 8192
#define LOG2E 1.44269504f

typedef __attribute__((ext_vector_type(8))) short short8;    // 8 x bf16 (4 VGPRs)
typedef __attribute__((ext_vector_type(4))) float f32x4;
typedef __attribute__((ext_vector_type(4))) float float4_t;
typedef __attribute__((ext_vector_type(4))) unsigned short ushort4_t;
typedef __attribute__((ext_vector_type(2))) unsigned int u32x2;

#define MFMA16(a,b,c) __builtin_amdgcn_mfma_f32_16x16x32_bf16((a),(b),(c),0,0,0)

// global -> LDS 16B DMA (wave-uniform LDS base + lane*16; per-lane global src)
#define GLL(gp, lp) __builtin_amdgcn_global_load_lds( \
    (const __attribute__((address_space(1))) void*)(gp), \
    (__attribute__((address_space(3))) void*)(lp), 16, 0, 0)

__device__ __forceinline__ short f2bf(float f){            // manual RNE (prep)
  union { float f; unsigned u; } v; v.f = f;
  unsigned r = v.u + 0x7fffu + ((v.u >> 16) & 1u);
  return (short)(r >> 16);
}

__device__ __forceinline__ short f2bf_fast(float f){       // native cvt (hot paths)
  __hip_bfloat16 h = __float2bfloat16(f);
  short s; __builtin_memcpy(&s, &h, 2); return s;
}

// ---------------- fused prep: x->bf16 | mask prescale/tile | both weight transposes ----------------
// blocks [0,2048): cvt; [2048,3072): maskP; [3072,3328): transposes
__global__ __launch_bounds__(256) void k_prep(
    const float* __restrict__ x,  short* __restrict__ xb,
    const float* __restrict__ mask, float* __restrict__ maskP,
    const float* __restrict__ W0, short* __restrict__ WT0,
    const float* __restrict__ W1, short* __restrict__ WT1)
{
  __shared__ float t[64][65];
  const int blk = blockIdx.x, tid = threadIdx.x;

  if (blk < 2048){                                  // ---- x fp32 -> bf16
    int i = blk*256 + tid;
    const float4_t* p = (const float4_t*)x + (size_t)i*2;
    float4_t a = p[0], b = p[1];
    short8 o;
    o[0]=f2bf(a[0]); o[1]=f2bf(a[1]); o[2]=f2bf(a[2]); o[3]=f2bf(a[3]);
    o[4]=f2bf(b[0]); o[5]=f2bf(b[1]); o[6]=f2bf(b[2]); o[7]=f2bf(b[3]);
    *((short8*)xb + i) = o;
    return;
  }
  if (blk < 3072){                                  // ---- mask -> prescaled transposed-fragment tiles
    // maskP flat = qg*16384 + kvt*1024 + lane*16 + nf*4 + j
    //   value = mask[qg*16 + li][kvt*64 + nf*16 + lg*4 + j] * LOG2E - 17.3123405
    int gid = (blk-2048)*256 + tid;
    int nf  = gid & 3;
    int lane= (gid>>2) & 63;
    int kvt = (gid>>8) & 15;
    int qg  = gid>>12;
    int li = lane & 15, lg = lane >> 4;
    int row = qg*16 + li;
    int col = kvt*64 + nf*16 + lg*4;
    float4_t m = *(const float4_t*)(mask + (size_t)row*1024 + col);
    float4_t o;
    #pragma unroll
    for (int j=0;j<4;++j) o[j] = fmaf(m[j], LOG2E, -17.3123405f);
    ((float4_t*)maskP)[gid] = o;
    return;
  }
  // ---- W [512][N] fp32 -> WT [N][512] bf16 (both weights)
  int idx = blk - 3072;                             // [0,256)
  int bx = idx & 31, by = idx >> 5;
  const float* W; short* WT; int N, n0;
  if (bx < 24){ W = W0; WT = WT0; N = N3; n0 = bx*64; }
  else        { W = W1; WT = WT1; N = DM; n0 = (bx-24)*64; }
  int k0 = by*64;
  int r = tid >> 4, c4 = (tid & 15) * 4;
  #pragma unroll
  for (int it=0; it<4; ++it){
    int rr = r + it*16;
    float4_t v = *(const float4_t*)(W + (size_t)(k0+rr)*N + n0 + c4);
    t[rr][c4+0]=v[0]; t[rr][c4+1]=v[1]; t[rr][c4+2]=v[2]; t[rr][c4+3]=v[3];
  }
  __syncthreads();
  #pragma unroll
  for (int it=0; it<4; ++it){
    int n = r + it*16;
    ushort4_t o;
    o[0]=(unsigned short)f2bf(t[c4+0][n]);
    o[1]=(unsigned short)f2bf(t[c4+1][n]);
    o[2]=(unsigned short)f2bf(t[c4+2][n]);
    o[3]=(unsigned short)f2bf(t[c4+3][n]);
    *(ushort4_t*)(WT + (size_t)(n0+n)*DM + k0 + c4) = o;
  }
}

// ---------------- GEMM1: gload_lds staging + XOR-4 LDS swizzle, 1 barrier/K-step ----------------
__global__ __launch_bounds__(256) void k_gemm_qkv(
    const short* __restrict__ A, const short* __restrict__ Bt,
    const float* __restrict__ bias,
    short* __restrict__ Qo, short* __restrict__ Ko, short* __restrict__ VTo)
{
  __shared__ __align__(16) short As[2][128*32];
  __shared__ __align__(16) short Bs[2][128*32];
  const int m0 = blockIdx.x*128, n0 = blockIdx.y*128;
  const int tid = threadIdx.x;
  const int w = tid>>6, lane = tid&63, li = lane&15, lg = lane>>4;
  const int wr = (w>>1)*64, wc = (w&1)*64;

  // staging: chunk c -> lds row c>>2, lds slot c&3; global slot = (c&3)^(row&3)
  const int r0 = tid>>2;
  const int s0 = (tid&3) ^ (r0&3);       // chunk1 (row+64): row&3 identical -> same s0
  const int swz = li&3;                  // read-side xor

  #define G1_STAGE(buf, kt) do { \
    GLL(A  + (size_t)(m0+r0   )*DM + (kt)*32 + s0*8, &As[buf][tid*8]); \
    GLL(A  + (size_t)(m0+r0+64)*DM + (kt)*32 + s0*8, &As[buf][(tid+256)*8]); \
    GLL(Bt + (size_t)(n0+r0   )*DM + (kt)*32 + s0*8, &Bs[buf][tid*8]); \
    GLL(Bt + (size_t)(n0+r0+64)*DM + (kt)*32 + s0*8, &Bs[buf][(tid+256)*8]); \
  } while(0)

  const f32x4 fz = {0.f,0.f,0.f,0.f};
  f32x4 acc[4][4];
  #pragma unroll
  for (int i=0;i<4;++i)
    #pragma unroll
    for (int j=0;j<4;++j) acc[i][j] = fz;

  G1_STAGE(0, 0);
  __syncthreads();

  for (int kt=0; kt<16; ++kt){
    const short* as = As[kt&1]; const short* bs = Bs[kt&1];
    if (kt < 15) G1_STAGE((kt&1)^1, kt+1);
    short8 bfr[4];
    #pragma unroll
    for (int nf=0;nf<4;++nf)
      bfr[nf] = *(const short8*)&bs[(wc + nf*16 + li)*32 + (lg^swz)*8];
    __builtin_amdgcn_s_setprio(1);
    #pragma unroll
    for (int mf=0;mf<4;++mf){
      short8 af = *(const short8*)&as[(wr + mf*16 + li)*32 + (lg^swz)*8];
      #pragma unroll
      for (int nf=0;nf<4;++nf)
        acc[mf][nf] = MFMA16(af, bfr[nf], acc[mf][nf]);
    }
    __builtin_amdgcn_s_setprio(0);
    __syncthreads();
  }

  // epilogue: col n -> head h = n/192; within: [0,64)=Q, [64,128)=K, [128,192)=V(transposed store)
  #pragma unroll
  for (int nf=0;nf<4;++nf){
    int n = n0 + wc + nf*16 + li;
    float bv = bias[n];
    unsigned h  = (unsigned)n / 192u;
    unsigned wn = (unsigned)n % 192u;
    unsigned typ = wn >> 6, d = wn & 63u;
    #pragma unroll
    for (int mf=0;mf<4;++mf){
      #pragma unroll
      for (int j=0;j<4;++j){
        int m  = m0 + wr + mf*16 + lg*4 + j;
        int b  = m >> 10, lp = m & 1023;
        size_t bh = (size_t)(b*8 + (int)h);
        float vf = acc[mf][nf][j] + bv;
        if (typ == 0)      Qo [(bh<<16) + ((size_t)lp<<6)  + d]  = f2bf_fast(vf * 0.18033688f); // 0.125*log2e
        else if (typ == 1) Ko [(bh<<16) + ((size_t)lp<<6)  + d]  = f2bf_fast(vf);
        else               VTo[(bh<<16) + ((size_t)d<<10)  + lp] = f2bf_fast(vf);
      }
    }
  }
  #undef G1_STAGE
}

// ---------------- flash attention (R6-proven): gload_lds K/V + XOR swizzle + XCD-local, P via LDS ----------------
__global__ __launch_bounds__(256, 2) void k_attn(
    const short* __restrict__ Q, const short* __restrict__ Kb,
    const short* __restrict__ VT, const float* __restrict__ maskP,
    short* __restrict__ O2)
{
  __shared__ __align__(16) short Ks[2][64*64];   // linear [kv][d], source-swizzled
  __shared__ __align__(16) short Vs[2][64*64];   // linear [d][kv], source-swizzled
  __shared__ __align__(16) short Ps[4][32*72];

  // XCD-local decode: all 8 q-blocks of a bh land on one XCD (hw xcd = id & 7)
  const int id  = blockIdx.x;
  const int bh  = (id & 7)*8 + ((id >> 3) & 7);
  const int q0  = (id >> 6) * 128;

  const int tid = threadIdx.x, w = tid>>6, lane = tid&63, li = lane&15, lg = lane>>4;
  const int qw = q0 + w*32;

  const short* Qp = Q  + ((size_t)bh<<16);
  const short* Kp = Kb + ((size_t)bh<<16);
  const short* Vp = VT + ((size_t)bh<<16);

  // staging chunk geometry: chunk c covers (row=c>>3, lds slot=c&7); global slot = lds slot ^ (row&7)
  const int arow0 = tid>>3;
  const int ags0  = (tid&7) ^ (arow0&7);         // chunk1: row+32 -> same (row&7), same gslot

  #define ATTN_STAGE(buf, nx) do { \
    GLL(Kp + ((size_t)((nx)+arow0   )<<6) + ags0*8, &Ks[buf][tid*8]); \
    GLL(Kp + ((size_t)((nx)+arow0+32)<<6) + ags0*8, &Ks[buf][(tid+256)*8]); \
    GLL(Vp + ((size_t)(arow0   )<<10) + (nx) + ags0*8, &Vs[buf][tid*8]); \
    GLL(Vp + ((size_t)(arow0+32)<<10) + (nx) + ags0*8, &Vs[buf][(tid+256)*8]); \
  } while(0)

  // Q as B-operand (col=q=li, k=d), two m-blocks; Q pre-scaled in GEMM1
  short8 qf[2][2];
  #pragma unroll
  for (int mb=0;mb<2;++mb)
    #pragma unroll
    for (int t=0;t<2;++t)
      qf[mb][t] = *(const short8*)(Qp + ((size_t)(qw+mb*16+li)<<6) + t*32 + lg*8);

  short8 ones8;
  #pragma unroll
  for (int e=0;e<8;++e) ones8[e] = (short)0x3f80;   // bf16 1.0

  const f32x4 fz = {0.f,0.f,0.f,0.f};
  f32x4 o[2][4], osum[2];
  #pragma unroll
  for (int mb=0;mb<2;++mb){
    osum[mb] = fz;
    #pragma unroll
    for (int df=0;df<4;++df) o[mb][df] = fz;
  }

  // mask (transposed-fragment, prescaled); register prefetch one tile ahead
  const float* mpb[2];
  #pragma unroll
  for (int mb=0;mb<2;++mb)
    mpb[mb] = maskP + ((size_t)((qw>>4)+mb)<<14) + lane*16;
  f32x4 mnx[2][4];
  #pragma unroll
  for (int mb=0;mb<2;++mb)
    #pragma unroll
    for (int nf=0;nf<4;++nf)
      mnx[mb][nf] = *(const float4_t*)(mpb[mb] + nf*4);

  ATTN_STAGE(0, 0);
  __syncthreads();     // drains vmcnt -> tile 0 staged

  const int sw = li & 7;
  short* pw = Ps[w];

  for (int kvt=0; kvt<16; ++kvt){
    const short* ks = Ks[kvt&1];
    const short* vs = Vs[kvt&1];
    if (kvt < 15) ATTN_STAGE((kvt&1)^1, (kvt+1)*64);

    // swapped QK^T: S^T[kv][q] tiles; C-init = prefetched mask regs
    f32x4 s[2][4];
    __builtin_amdgcn_s_setprio(1);
    #pragma unroll
    for (int nf=0;nf<4;++nf){
      short8 kf0 = *(const short8*)&ks[(nf*16+li)*64 + ((  lg)^sw)*8];
      short8 kf1 = *(const short8*)&ks[(nf*16+li)*64 + ((4|lg)^sw)*8];
      #pragma unroll
      for (int mb=0;mb<2;++mb){
        s[mb][nf] = MFMA16(kf0, qf[mb][0], mnx[mb][nf]);
        s[mb][nf] = MFMA16(kf1, qf[mb][1], s[mb][nf]);
      }
    }
    __builtin_amdgcn_s_setprio(0);

    // prefetch next tile's mask (consumed next iteration)
    if (kvt < 15){
      #pragma unroll
      for (int mb=0;mb<2;++mb)
        #pragma unroll
        for (int nf=0;nf<4;++nf)
          mnx[mb][nf] = *(const float4_t*)(mpb[mb] + (kvt+1)*1024 + nf*4);
    }

    // p = exp2(s) -> packed bf16 pairs -> Ps[q][kv] (b64 writes)
    #pragma unroll
    for (int mb=0;mb<2;++mb){
      #pragma unroll
      for (int nf=0;nf<4;++nf){
        float e0 = __builtin_amdgcn_exp2f(s[mb][nf][0]);
        float e1 = __builtin_amdgcn_exp2f(s[mb][nf][1]);
        float e2 = __builtin_amdgcn_exp2f(s[mb][nf][2]);
        float e3 = __builtin_amdgcn_exp2f(s[mb][nf][3]);
        unsigned p01, p23;
        asm("v_cvt_pk_bf16_f32 %0, %1, %2" : "=v"(p01) : "v"(e0), "v"(e1));
        asm("v_cvt_pk_bf16_f32 %0, %1, %2" : "=v"(p23) : "v"(e2), "v"(e3));
        u32x2 pv; pv[0]=p01; pv[1]=p23;
        *(u32x2*)&pw[(mb*16+li)*72 + nf*16 + lg*4] = pv;
      }
    }

    // PV: O[32q x 64d] += P @ V ; V-frags shared across both m-blocks
    __builtin_amdgcn_s_setprio(1);
    #pragma unroll
    for (int t=0;t<2;++t){
      short8 pf0 = *(const short8*)&pw[(   li)*72 + t*32 + lg*8];
      short8 pf1 = *(const short8*)&pw[(16+li)*72 + t*32 + lg*8];
      osum[0] = MFMA16(pf0, ones8, osum[0]);
      osum[1] = MFMA16(pf1, ones8, osum[1]);
      #pragma unroll
      for (int df=0;df<4;++df){
        short8 vf = *(const short8*)&vs[(df*16+li)*64 + (((t<<2)|lg)^sw)*8];
        o[0][df] = MFMA16(pf0, vf, o[0][df]);
        o[1][df] = MFMA16(pf1, vf, o[1][df]);
      }
    }
    __builtin_amdgcn_s_setprio(0);

    __syncthreads();   // buf[cur] reads done + buf[cur^1] DMA drained (vmcnt 0 at barrier)
  }
  #undef ATTN_STAGE

  // epilogue: O2[b, l, h*64+d] bf16
  int b = bh >> 3, h = bh & 7;
  #pragma unroll
  for (int mb=0;mb<2;++mb){
    float rl[4];
    #pragma unroll
    for (int j=0;j<4;++j) rl[j] = 1.0f / osum[mb][j];
    #pragma unroll
    for (int df=0;df<4;++df)
      #pragma unroll
      for (int j=0;j<4;++j){
        int m   = b*1024 + qw + mb*16 + lg*4 + j;
        int col = h*64 + df*16 + li;
        O2[(size_t)m*512 + col] = f2bf_fast(o[mb][df][j] * rl[j]);
      }
  }
}

// ---------------- GEMM2: 64x128 tiles (2 blocks/CU), gload_lds + XOR-4 swizzle ----------------
__global__ __launch_bounds__(256) void k_gemm_out(
    const short* __restrict__ A, const short* __restrict__ Bt,
    const float* __restrict__ bias, float* __restrict__ out)
{
  __shared__ __align__(16) short As[2][64*32];
  __shared__ __align__(16) short Bs[2][128*32];
  const int m0 = blockIdx.x*64, n0 = blockIdx.y*128;
  const int tid = threadIdx.x;
  const int w = tid>>6, lane = tid&63, li = lane&15, lg = lane>>4;
  const int wc = w*32;                  // wave covers cols [wc, wc+32), all 64 rows

  const int r0 = tid>>2;
  const int s0 = (tid&3) ^ (r0&3);
  const int swz = li&3;
  const int ra = tid>>2;                // A: 64 rows x 4 slots = 256 chunks (1 GLL)

  #define G2_STAGE(buf, kt) do { \
    GLL(A  + (size_t)(m0+ra    )*DM + (kt)*32 + s0*8, &As[buf][tid*8]); \
    GLL(Bt + (size_t)(n0+r0    )*DM + (kt)*32 + s0*8, &Bs[buf][tid*8]); \
    GLL(Bt + (size_t)(n0+r0+64 )*DM + (kt)*32 + s0*8, &Bs[buf][(tid+256)*8]); \
  } while(0)

  const f32x4 fz = {0.f,0.f,0.f,0.f};
  f32x4 acc[4][2];
  #pragma unroll
  for (int i=0;i<4;++i)
    #pragma unroll
    for (int j=0;j<2;++j) acc[i][j] = fz;

  G2_STAGE(0, 0);
  __syncthreads();

  for (int kt=0; kt<16; ++kt){
    const short* as = As[kt&1]; const short* bs = Bs[kt&1];
    if (kt < 15) G2_STAGE((kt&1)^1, kt+1);
    short8 bfr[2];
    #pragma unroll
    for (int nf=0;nf<2;++nf)
      bfr[nf] = *(const short8*)&bs[(wc + nf*16 + li)*32 + (lg^swz)*8];
    __builtin_amdgcn_s_setprio(1);
    #pragma unroll
    for (int mf=0;mf<4;++mf){
      short8 af = *(const short8*)&as[(mf*16 + li)*32 + (lg^swz)*8];
      #pragma unroll
      for (int nf=0;nf<2;++nf)
        acc[mf][nf] = MFMA16(af, bfr[nf], acc[mf][nf]);
    }
    __builtin_amdgcn_s_setprio(0);
    __syncthreads();
  }

  #pragma unroll
  for (int nf=0;nf<2;++nf){
    int n = n0 + wc + nf*16 + li;
    float bv = bias[n];
    #pragma unroll
    for (int mf=0;mf<4;++mf){
      #pragma unroll
      for (int j=0;j<4;++j){
        int m = m0 + mf*16 + lg*4 + j;
        out[(size_t)m*DM + n] = acc[mf][nf][j] + bv;
      }
    }
  }
  #undef G2_STAGE
}

extern "C" void kernel_launch(void* const* d_in, const int* in_sizes, int n_in,
                              void* d_out, int out_size, void* d_ws, size_t ws_size,
                              hipStream_t stream)
{
  (void)in_sizes; (void)n_in; (void)out_size; (void)ws_size;
  const float* x    = (const float*)d_in[0];
  const float* mask = (const float*)d_in[1];
  const float* Wqkv = (const float*)d_in[2];
  const float* bqkv = (const float*)d_in[3];
  const float* Wo   = (const float*)d_in[4];
  const float* bo   = (const float*)d_in[5];
  float* out = (float*)d_out;

  short* xb    = (short*)d_ws;                    // [8192,512] bf16
  short* WqkvT = xb    + (size_t)M_T*DM;          // [1536,512] bf16
  short* WoT   = WqkvT + (size_t)N3*DM;           // [512,512]  bf16
  short* Qb    = WoT   + (size_t)DM*DM;           // [64][1024][64] bf16 (pre-scaled)
  short* Kbf   = Qb    + (size_t)64*1024*64;      // [64][1024][64] bf16
  short* VTb   = Kbf   + (size_t)64*1024*64;      // [64][64][1024] bf16 (V^T)
  short* O2    = VTb   + (size_t)64*1024*64;      // [8192,512] bf16
  float* maskP = (float*)(O2 + (size_t)M_T*DM);   // [1024,1024] fp32 prescaled tiles (ws ~268MB, fits)

  k_prep<<<3328, 256, 0, stream>>>(x, xb, mask, maskP, Wqkv, WqkvT, Wo, WoT);
  k_gemm_qkv<<<dim3(M_T/128, N3/128), 256, 0, stream>>>(xb, WqkvT, bqkv, Qb, Kbf, VTb);
  k_attn    <<<512, 256, 0, stream>>>(Qb, Kbf, VTb, maskP, O2);
  k_gemm_out<<<dim3(M_T/64, DM/128), 256, 0, stream>>>(O2, WoT, bo, out);
}

// Round 11
// 80.147 us; speedup vs baseline: 1.4936x; 1.0000x over previous
//
#include <hip/hip_runtime.h>
#include <hip/hip_bf16.h>
#include <stdint.h>

#define B_ 8
#define L_ 1024
#define DM 512
#define H_ 8
#define HD 64
#define N3 1536
#define M_T (B_*L_)        // 8192
#define LOG2E 1.44269504f

typedef __attribute__((ext_vector_type(8))) short short8;    // 8 x bf16 (4 VGPRs)
typedef __attribute__((ext_vector_type(4))) float f32x4;
typedef __attribute__((ext_vector_type(4))) float float4_t;
typedef __attribute__((ext_vector_type(4))) unsigned short ushort4_t;
typedef __attribute__((ext_vector_type(2))) unsigned int u32x2;

#define MFMA16(a,b,c) __builtin_amdgcn_mfma_f32_16x16x32_bf16((a),(b),(c),0,0,0)

// global -> LDS 16B DMA (wave-uniform LDS base + lane*16; per-lane global src)
#define GLL(gp, lp) __builtin_amdgcn_global_load_lds( \
    (const __attribute__((address_space(1))) void*)(gp), \
    (__attribute__((address_space(3))) void*)(lp), 16, 0, 0)

__device__ __forceinline__ short f2bf(float f){            // manual RNE (prep)
  union { float f; unsigned u; } v; v.f = f;
  unsigned r = v.u + 0x7fffu + ((v.u >> 16) & 1u);
  return (short)(r >> 16);
}

__device__ __forceinline__ short f2bf_fast(float f){       // native cvt (hot paths)
  __hip_bfloat16 h = __float2bfloat16(f);
  short s; __builtin_memcpy(&s, &h, 2); return s;
}

// ---------------- fused prep: x->bf16 | mask prescale/tile | both weight transposes ----------------
// blocks [0,2048): cvt; [2048,3072): maskP; [3072,3328): transposes
__global__ __launch_bounds__(256) void k_prep(
    const float* __restrict__ x,  short* __restrict__ xb,
    const float* __restrict__ mask, float* __restrict__ maskP,
    const float* __restrict__ W0, short* __restrict__ WT0,
    const float* __restrict__ W1, short* __restrict__ WT1)
{
  __shared__ float t[64][65];
  const int blk = blockIdx.x, tid = threadIdx.x;

  if (blk < 2048){                                  // ---- x fp32 -> bf16
    int i = blk*256 + tid;
    const float4_t* p = (const float4_t*)x + (size_t)i*2;
    float4_t a = p[0], b = p[1];
    short8 o;
    o[0]=f2bf(a[0]); o[1]=f2bf(a[1]); o[2]=f2bf(a[2]); o[3]=f2bf(a[3]);
    o[4]=f2bf(b[0]); o[5]=f2bf(b[1]); o[6]=f2bf(b[2]); o[7]=f2bf(b[3]);
    *((short8*)xb + i) = o;
    return;
  }
  if (blk < 3072){                                  // ---- mask -> prescaled transposed-fragment tiles
    // maskP flat = qg*16384 + kvt*1024 + lane*16 + nf*4 + j
    //   value = mask[qg*16 + li][kvt*64 + nf*16 + lg*4 + j] * LOG2E - 17.3123405
    int gid = (blk-2048)*256 + tid;
    int nf  = gid & 3;
    int lane= (gid>>2) & 63;
    int kvt = (gid>>8) & 15;
    int qg  = gid>>12;
    int li = lane & 15, lg = lane >> 4;
    int row = qg*16 + li;
    int col = kvt*64 + nf*16 + lg*4;
    float4_t m = *(const float4_t*)(mask + (size_t)row*1024 + col);
    float4_t o;
    #pragma unroll
    for (int j=0;j<4;++j) o[j] = fmaf(m[j], LOG2E, -17.3123405f);
    ((float4_t*)maskP)[gid] = o;
    return;
  }
  // ---- W [512][N] fp32 -> WT [N][512] bf16 (both weights)
  int idx = blk - 3072;                             // [0,256)
  int bx = idx & 31, by = idx >> 5;
  const float* W; short* WT; int N, n0;
  if (bx < 24){ W = W0; WT = WT0; N = N3; n0 = bx*64; }
  else        { W = W1; WT = WT1; N = DM; n0 = (bx-24)*64; }
  int k0 = by*64;
  int r = tid >> 4, c4 = (tid & 15) * 4;
  #pragma unroll
  for (int it=0; it<4; ++it){
    int rr = r + it*16;
    float4_t v = *(const float4_t*)(W + (size_t)(k0+rr)*N + n0 + c4);
    t[rr][c4+0]=v[0]; t[rr][c4+1]=v[1]; t[rr][c4+2]=v[2]; t[rr][c4+3]=v[3];
  }
  __syncthreads();
  #pragma unroll
  for (int it=0; it<4; ++it){
    int n = r + it*16;
    ushort4_t o;
    o[0]=(unsigned short)f2bf(t[c4+0][n]);
    o[1]=(unsigned short)f2bf(t[c4+1][n]);
    o[2]=(unsigned short)f2bf(t[c4+2][n]);
    o[3]=(unsigned short)f2bf(t[c4+3][n]);
    *(ushort4_t*)(WT + (size_t)(n0+n)*DM + k0 + c4) = o;
  }
}

// ---------------- GEMM1: 128x192 tiles, XCD-local A-panels, gload_lds + XOR-4 swizzle ----------------
// grid 1D 512: id = (x&7) + 8*y + 64*(x>>3)  ->  all 8 y-blocks of an A-panel share one XCD (id&7)
__global__ __launch_bounds__(256) void k_gemm_qkv(
    const short* __restrict__ A, const short* __restrict__ Bt,
    const float* __restrict__ bias,
    short* __restrict__ Qo, short* __restrict__ Ko, short* __restrict__ VTo)
{
  __shared__ __align__(16) short As[2][128*32];
  __shared__ __align__(16) short Bs[2][192*32];
  const int id  = blockIdx.x;
  const int xlo = id & 7, yy = (id>>3) & 7, xhi = id >> 6;
  const int m0  = (xhi*8 + xlo)*128, n0 = yy*192;
  const int tid = threadIdx.x;
  const int w = tid>>6, lane = tid&63, li = lane&15, lg = lane>>4;
  const int wr = (w>>1)*64, wc = (w&1)*96;

  // staging: chunk c -> lds row c>>2, lds slot c&3; global slot = (c&3)^(row&3)
  const int r0 = tid>>2;
  const int s0 = (tid&3) ^ (r0&3);       // rows +64/+128: row&3 identical -> same s0
  const int swz = li&3;                  // read-side xor

  #define G1_STAGE(buf, kt) do { \
    GLL(A  + (size_t)(m0+r0    )*DM + (kt)*32 + s0*8, &As[buf][tid*8]); \
    GLL(A  + (size_t)(m0+r0+64 )*DM + (kt)*32 + s0*8, &As[buf][(tid+256)*8]); \
    GLL(Bt + (size_t)(n0+r0    )*DM + (kt)*32 + s0*8, &Bs[buf][tid*8]); \
    GLL(Bt + (size_t)(n0+r0+64 )*DM + (kt)*32 + s0*8, &Bs[buf][(tid+256)*8]); \
    GLL(Bt + (size_t)(n0+r0+128)*DM + (kt)*32 + s0*8, &Bs[buf][(tid+512)*8]); \
  } while(0)

  const f32x4 fz = {0.f,0.f,0.f,0.f};
  f32x4 acc[4][6];
  #pragma unroll
  for (int i=0;i<4;++i)
    #pragma unroll
    for (int j=0;j<6;++j) acc[i][j] = fz;

  G1_STAGE(0, 0);
  __syncthreads();

  for (int kt=0; kt<16; ++kt){
    const short* as = As[kt&1]; const short* bs = Bs[kt&1];
    if (kt < 15) G1_STAGE((kt&1)^1, kt+1);
    short8 bfr[6];
    #pragma unroll
    for (int nf=0;nf<6;++nf)
      bfr[nf] = *(const short8*)&bs[(wc + nf*16 + li)*32 + (lg^swz)*8];
    __builtin_amdgcn_s_setprio(1);
    #pragma unroll
    for (int mf=0;mf<4;++mf){
      short8 af = *(const short8*)&as[(wr + mf*16 + li)*32 + (lg^swz)*8];
      #pragma unroll
      for (int nf=0;nf<6;++nf)
        acc[mf][nf] = MFMA16(af, bfr[nf], acc[mf][nf]);
    }
    __builtin_amdgcn_s_setprio(0);
    __syncthreads();
  }

  // epilogue: col n -> head h = n/192; within: [0,64)=Q, [64,128)=K, [128,192)=V(transposed store)
  #pragma unroll
  for (int nf=0;nf<6;++nf){
    int n = n0 + wc + nf*16 + li;
    float bv = bias[n];
    unsigned h  = (unsigned)n / 192u;
    unsigned wn = (unsigned)n % 192u;
    unsigned typ = wn >> 6, d = wn & 63u;
    #pragma unroll
    for (int mf=0;mf<4;++mf){
      #pragma unroll
      for (int j=0;j<4;++j){
        int m  = m0 + wr + mf*16 + lg*4 + j;
        int b  = m >> 10, lp = m & 1023;
        size_t bh = (size_t)(b*8 + (int)h);
        float vf = acc[mf][nf][j] + bv;
        if (typ == 0)      Qo [(bh<<16) + ((size_t)lp<<6)  + d]  = f2bf_fast(vf * 0.18033688f); // 0.125*log2e
        else if (typ == 1) Ko [(bh<<16) + ((size_t)lp<<6)  + d]  = f2bf_fast(vf);
        else               VTo[(bh<<16) + ((size_t)d<<10)  + lp] = f2bf_fast(vf);
      }
    }
  }
  #undef G1_STAGE
}

// ---------------- flash attention (proven): gload_lds K/V + XOR swizzle + XCD-local, P via LDS ----------------
__global__ __launch_bounds__(256, 2) void k_attn(
    const short* __restrict__ Q, const short* __restrict__ Kb,
    const short* __restrict__ VT, const float* __restrict__ maskP,
    short* __restrict__ O2)
{
  __shared__ __align__(16) short Ks[2][64*64];   // linear [kv][d], source-swizzled
  __shared__ __align__(16) short Vs[2][64*64];   // linear [d][kv], source-swizzled
  __shared__ __align__(16) short Ps[4][32*72];

  // XCD-local decode: all 8 q-blocks of a bh land on one XCD (hw xcd = id & 7)
  const int id  = blockIdx.x;
  const int bh  = (id & 7)*8 + ((id >> 3) & 7);
  const int q0  = (id >> 6) * 128;

  const int tid = threadIdx.x, w = tid>>6, lane = tid&63, li = lane&15, lg = lane>>4;
  const int qw = q0 + w*32;

  const short* Qp = Q  + ((size_t)bh<<16);
  const short* Kp = Kb + ((size_t)bh<<16);
  const short* Vp = VT + ((size_t)bh<<16);

  // staging chunk geometry: chunk c covers (row=c>>3, lds slot=c&7); global slot = lds slot ^ (row&7)
  const int arow0 = tid>>3;
  const int ags0  = (tid&7) ^ (arow0&7);         // chunk1: row+32 -> same (row&7), same gslot

  #define ATTN_STAGE(buf, nx) do { \
    GLL(Kp + ((size_t)((nx)+arow0   )<<6) + ags0*8, &Ks[buf][tid*8]); \
    GLL(Kp + ((size_t)((nx)+arow0+32)<<6) + ags0*8, &Ks[buf][(tid+256)*8]); \
    GLL(Vp + ((size_t)(arow0   )<<10) + (nx) + ags0*8, &Vs[buf][tid*8]); \
    GLL(Vp + ((size_t)(arow0+32)<<10) + (nx) + ags0*8, &Vs[buf][(tid+256)*8]); \
  } while(0)

  // Q as B-operand (col=q=li, k=d), two m-blocks; Q pre-scaled in GEMM1
  short8 qf[2][2];
  #pragma unroll
  for (int mb=0;mb<2;++mb)
    #pragma unroll
    for (int t=0;t<2;++t)
      qf[mb][t] = *(const short8*)(Qp + ((size_t)(qw+mb*16+li)<<6) + t*32 + lg*8);

  short8 ones8;
  #pragma unroll
  for (int e=0;e<8;++e) ones8[e] = (short)0x3f80;   // bf16 1.0

  const f32x4 fz = {0.f,0.f,0.f,0.f};
  f32x4 o[2][4], osum[2];
  #pragma unroll
  for (int mb=0;mb<2;++mb){
    osum[mb] = fz;
    #pragma unroll
    for (int df=0;df<4;++df) o[mb][df] = fz;
  }

  // mask (transposed-fragment, prescaled); register prefetch one tile ahead
  const float* mpb[2];
  #pragma unroll
  for (int mb=0;mb<2;++mb)
    mpb[mb] = maskP + ((size_t)((qw>>4)+mb)<<14) + lane*16;
  f32x4 mnx[2][4];
  #pragma unroll
  for (int mb=0;mb<2;++mb)
    #pragma unroll
    for (int nf=0;nf<4;++nf)
      mnx[mb][nf] = *(const float4_t*)(mpb[mb] + nf*4);

  ATTN_STAGE(0, 0);
  __syncthreads();     // drains vmcnt -> tile 0 staged

  const int sw = li & 7;
  short* pw = Ps[w];

  for (int kvt=0; kvt<16; ++kvt){
    const short* ks = Ks[kvt&1];
    const short* vs = Vs[kvt&1];
    if (kvt < 15) ATTN_STAGE((kvt&1)^1, (kvt+1)*64);

    // swapped QK^T: S^T[kv][q] tiles; C-init = prefetched mask regs
    f32x4 s[2][4];
    __builtin_amdgcn_s_setprio(1);
    #pragma unroll
    for (int nf=0;nf<4;++nf){
      short8 kf0 = *(const short8*)&ks[(nf*16+li)*64 + ((  lg)^sw)*8];
      short8 kf1 = *(const short8*)&ks[(nf*16+li)*64 + ((4|lg)^sw)*8];
      #pragma unroll
      for (int mb=0;mb<2;++mb){
        s[mb][nf] = MFMA16(kf0, qf[mb][0], mnx[mb][nf]);
        s[mb][nf] = MFMA16(kf1, qf[mb][1], s[mb][nf]);
      }
    }
    __builtin_amdgcn_s_setprio(0);

    // prefetch next tile's mask (consumed next iteration)
    if (kvt < 15){
      #pragma unroll
      for (int mb=0;mb<2;++mb)
        #pragma unroll
        for (int nf=0;nf<4;++nf)
          mnx[mb][nf] = *(const float4_t*)(mpb[mb] + (kvt+1)*1024 + nf*4);
    }

    // p = exp2(s) -> packed bf16 pairs -> Ps[q][kv] (b64 writes)
    #pragma unroll
    for (int mb=0;mb<2;++mb){
      #pragma unroll
      for (int nf=0;nf<4;++nf){
        float e0 = __builtin_amdgcn_exp2f(s[mb][nf][0]);
        float e1 = __builtin_amdgcn_exp2f(s[mb][nf][1]);
        float e2 = __builtin_amdgcn_exp2f(s[mb][nf][2]);
        float e3 = __builtin_amdgcn_exp2f(s[mb][nf][3]);
        unsigned p01, p23;
        asm("v_cvt_pk_bf16_f32 %0, %1, %2" : "=v"(p01) : "v"(e0), "v"(e1));
        asm("v_cvt_pk_bf16_f32 %0, %1, %2" : "=v"(p23) : "v"(e2), "v"(e3));
        u32x2 pv; pv[0]=p01; pv[1]=p23;
        *(u32x2*)&pw[(mb*16+li)*72 + nf*16 + lg*4] = pv;
      }
    }

    // PV: O[32q x 64d] += P @ V ; V-frags shared across both m-blocks
    __builtin_amdgcn_s_setprio(1);
    #pragma unroll
    for (int t=0;t<2;++t){
      short8 pf0 = *(const short8*)&pw[(   li)*72 + t*32 + lg*8];
      short8 pf1 = *(const short8*)&pw[(16+li)*72 + t*32 + lg*8];
      osum[0] = MFMA16(pf0, ones8, osum[0]);
      osum[1] = MFMA16(pf1, ones8, osum[1]);
      #pragma unroll
      for (int df=0;df<4;++df){
        short8 vf = *(const short8*)&vs[(df*16+li)*64 + (((t<<2)|lg)^sw)*8];
        o[0][df] = MFMA16(pf0, vf, o[0][df]);
        o[1][df] = MFMA16(pf1, vf, o[1][df]);
      }
    }
    __builtin_amdgcn_s_setprio(0);

    __syncthreads();   // buf[cur] reads done + buf[cur^1] DMA drained (vmcnt 0 at barrier)
  }
  #undef ATTN_STAGE

  // epilogue: O2[b, l, h*64+d] bf16
  int b = bh >> 3, h = bh & 7;
  #pragma unroll
  for (int mb=0;mb<2;++mb){
    float rl[4];
    #pragma unroll
    for (int j=0;j<4;++j) rl[j] = 1.0f / osum[mb][j];
    #pragma unroll
    for (int df=0;df<4;++df)
      #pragma unroll
      for (int j=0;j<4;++j){
        int m   = b*1024 + qw + mb*16 + lg*4 + j;
        int col = h*64 + df*16 + li;
        O2[(size_t)m*512 + col] = f2bf_fast(o[mb][df][j] * rl[j]);
      }
  }
}

// ---------------- GEMM2: 64x128 tiles, XCD-local A-panels, gload_lds + XOR-4 swizzle ----------------
// grid 1D 512: id = (x&7) + 8*y + 32*(x>>3) ; x in [0,128), y in [0,4)
__global__ __launch_bounds__(256) void k_gemm_out(
    const short* __restrict__ A, const short* __restrict__ Bt,
    const float* __restrict__ bias, float* __restrict__ out)
{
  __shared__ __align__(16) short As[2][64*32];
  __shared__ __align__(16) short Bs[2][128*32];
  const int id  = blockIdx.x;
  const int xlo = id & 7, yy = (id>>3) & 3, xhi = id >> 5;
  const int m0  = (xhi*8 + xlo)*64, n0 = yy*128;
  const int tid = threadIdx.x;
  const int w = tid>>6, lane = tid&63, li = lane&15, lg = lane>>4;
  const int wc = w*32;                  // wave covers cols [wc, wc+32), all 64 rows

  const int r0 = tid>>2;
  const int s0 = (tid&3) ^ (r0&3);
  const int swz = li&3;
  const int ra = tid>>2;                // A: 64 rows x 4 slots = 256 chunks (1 GLL)

  #define G2_STAGE(buf, kt) do { \
    GLL(A  + (size_t)(m0+ra    )*DM + (kt)*32 + s0*8, &As[buf][tid*8]); \
    GLL(Bt + (size_t)(n0+r0    )*DM + (kt)*32 + s0*8, &Bs[buf][tid*8]); \
    GLL(Bt + (size_t)(n0+r0+64 )*DM + (kt)*32 + s0*8, &Bs[buf][(tid+256)*8]); \
  } while(0)

  const f32x4 fz = {0.f,0.f,0.f,0.f};
  f32x4 acc[4][2];
  #pragma unroll
  for (int i=0;i<4;++i)
    #pragma unroll
    for (int j=0;j<2;++j) acc[i][j] = fz;

  G2_STAGE(0, 0);
  __syncthreads();

  for (int kt=0; kt<16; ++kt){
    const short* as = As[kt&1]; const short* bs = Bs[kt&1];
    if (kt < 15) G2_STAGE((kt&1)^1, kt+1);
    short8 bfr[2];
    #pragma unroll
    for (int nf=0;nf<2;++nf)
      bfr[nf] = *(const short8*)&bs[(wc + nf*16 + li)*32 + (lg^swz)*8];
    __builtin_amdgcn_s_setprio(1);
    #pragma unroll
    for (int mf=0;mf<4;++mf){
      short8 af = *(const short8*)&as[(mf*16 + li)*32 + (lg^swz)*8];
      #pragma unroll
      for (int nf=0;nf<2;++nf)
        acc[mf][nf] = MFMA16(af, bfr[nf], acc[mf][nf]);
    }
    __builtin_amdgcn_s_setprio(0);
    __syncthreads();
  }

  #pragma unroll
  for (int nf=0;nf<2;++nf){
    int n = n0 + wc + nf*16 + li;
    float bv = bias[n];
    #pragma unroll
    for (int mf=0;mf<4;++mf){
      #pragma unroll
      for (int j=0;j<4;++j){
        int m = m0 + mf*16 + lg*4 + j;
        out[(size_t)m*DM + n] = acc[mf][nf][j] + bv;
      }
    }
  }
  #undef G2_STAGE
}

extern "C" void kernel_launch(void* const* d_in, const int* in_sizes, int n_in,
                              void* d_out, int out_size, void* d_ws, size_t ws_size,
                              hipStream_t stream)
{
  (void)in_sizes; (void)n_in; (void)out_size; (void)ws_size;
  const float* x    = (const float*)d_in[0];
  const float* mask = (const float*)d_in[1];
  const float* Wqkv = (const float*)d_in[2];
  const float* bqkv = (const float*)d_in[3];
  const float* Wo   = (const float*)d_in[4];
  const float* bo   = (const float*)d_in[5];
  float* out = (float*)d_out;

  short* xb    = (short*)d_ws;                    // [8192,512] bf16
  short* WqkvT = xb    + (size_t)M_T*DM;          // [1536,512] bf16
  short* WoT   = WqkvT + (size_t)N3*DM;           // [512,512]  bf16
  short* Qb    = WoT   + (size_t)DM*DM;           // [64][1024][64] bf16 (pre-scaled)
  short* Kbf   = Qb    + (size_t)64*1024*64;      // [64][1024][64] bf16
  short* VTb   = Kbf   + (size_t)64*1024*64;      // [64][64][1024] bf16 (V^T)
  short* O2    = VTb   + (size_t)64*1024*64;      // [8192,512] bf16
  float* maskP = (float*)(O2 + (size_t)M_T*DM);   // [1024,1024] fp32 prescaled tiles (ws ~268MB, fits)

  k_prep<<<3328, 256, 0, stream>>>(x, xb, mask, maskP, Wqkv, WqkvT, Wo, WoT);
  k_gemm_qkv<<<512, 256, 0, stream>>>(xb, WqkvT, bqkv, Qb, Kbf, VTb);
  k_attn    <<<512, 256, 0, stream>>>(Qb, Kbf, VTb, maskP, O2);
  k_gemm_out<<<512, 256, 0, stream>>>(O2, WoT, bo, out);
}

// Round 14
// 79.707 us; speedup vs baseline: 1.5018x; 1.0055x over previous
//
#include <hip/hip_runtime.h>
#include <hip/hip_bf16.h>
#include <stdint.h>

#define B_ 8
#define L_ 1024
#define DM 512
#define H_ 8
#define HD 64
#define N3 1536
#define M_T (B_*L_)        // 8192
#define LOG2E 1.44269504f

typedef __attribute__((ext_vector_type(8))) short short8;    // 8 x bf16 (4 VGPRs)
typedef __attribute__((ext_vector_type(4))) float f32x4;
typedef __attribute__((ext_vector_type(4))) float float4_t;
typedef __attribute__((ext_vector_type(4))) unsigned short ushort4_t;
typedef __attribute__((ext_vector_type(2))) unsigned int u32x2;

#define MFMA16(a,b,c) __builtin_amdgcn_mfma_f32_16x16x32_bf16((a),(b),(c),0,0,0)

// global -> LDS 16B DMA (wave-uniform LDS base + lane*16; per-lane global src)
#define GLL(gp, lp) __builtin_amdgcn_global_load_lds( \
    (const __attribute__((address_space(1))) void*)(gp), \
    (__attribute__((address_space(3))) void*)(lp), 16, 0, 0)

__device__ __forceinline__ short f2bf(float f){            // manual RNE (prep)
  union { float f; unsigned u; } v; v.f = f;
  unsigned r = v.u + 0x7fffu + ((v.u >> 16) & 1u);
  return (short)(r >> 16);
}

__device__ __forceinline__ short f2bf_fast(float f){       // native cvt (hot paths)
  __hip_bfloat16 h = __float2bfloat16(f);
  short s; __builtin_memcpy(&s, &h, 2); return s;
}

// ---------------- fused prep: x->bf16 | mask prescale/tile | both weight transposes ----------------
// blocks [0,2048): cvt; [2048,3072): maskP; [3072,3328): transposes
__global__ __launch_bounds__(256) void k_prep(
    const float* __restrict__ x,  short* __restrict__ xb,
    const float* __restrict__ mask, float* __restrict__ maskP,
    const float* __restrict__ W0, short* __restrict__ WT0,
    const float* __restrict__ W1, short* __restrict__ WT1)
{
  __shared__ float t[64][65];
  const int blk = blockIdx.x, tid = threadIdx.x;

  if (blk < 2048){                                  // ---- x fp32 -> bf16
    int i = blk*256 + tid;
    const float4_t* p = (const float4_t*)x + (size_t)i*2;
    float4_t a = p[0], b = p[1];
    short8 o;
    o[0]=f2bf(a[0]); o[1]=f2bf(a[1]); o[2]=f2bf(a[2]); o[3]=f2bf(a[3]);
    o[4]=f2bf(b[0]); o[5]=f2bf(b[1]); o[6]=f2bf(b[2]); o[7]=f2bf(b[3]);
    *((short8*)xb + i) = o;
    return;
  }
  if (blk < 3072){                                  // ---- mask -> prescaled transposed-fragment tiles
    // maskP flat = qg*16384 + kvt*1024 + lane*16 + nf*4 + j
    //   value = mask[qg*16 + li][kvt*64 + nf*16 + lg*4 + j] * LOG2E - 17.3123405
    int gid = (blk-2048)*256 + tid;
    int nf  = gid & 3;
    int lane= (gid>>2) & 63;
    int kvt = (gid>>8) & 15;
    int qg  = gid>>12;
    int li = lane & 15, lg = lane >> 4;
    int row = qg*16 + li;
    int col = kvt*64 + nf*16 + lg*4;
    float4_t m = *(const float4_t*)(mask + (size_t)row*1024 + col);
    float4_t o;
    #pragma unroll
    for (int j=0;j<4;++j) o[j] = fmaf(m[j], LOG2E, -17.3123405f);
    ((float4_t*)maskP)[gid] = o;
    return;
  }
  // ---- W [512][N] fp32 -> WT [N][512] bf16 (both weights)
  int idx = blk - 3072;                             // [0,256)
  int bx = idx & 31, by = idx >> 5;
  const float* W; short* WT; int N, n0;
  if (bx < 24){ W = W0; WT = WT0; N = N3; n0 = bx*64; }
  else        { W = W1; WT = WT1; N = DM; n0 = (bx-24)*64; }
  int k0 = by*64;
  int r = tid >> 4, c4 = (tid & 15) * 4;
  #pragma unroll
  for (int it=0; it<4; ++it){
    int rr = r + it*16;
    float4_t v = *(const float4_t*)(W + (size_t)(k0+rr)*N + n0 + c4);
    t[rr][c4+0]=v[0]; t[rr][c4+1]=v[1]; t[rr][c4+2]=v[2]; t[rr][c4+3]=v[3];
  }
  __syncthreads();
  #pragma unroll
  for (int it=0; it<4; ++it){
    int n = r + it*16;
    ushort4_t o;
    o[0]=(unsigned short)f2bf(t[c4+0][n]);
    o[1]=(unsigned short)f2bf(t[c4+1][n]);
    o[2]=(unsigned short)f2bf(t[c4+2][n]);
    o[3]=(unsigned short)f2bf(t[c4+3][n]);
    *(ushort4_t*)(WT + (size_t)(n0+n)*DM + k0 + c4) = o;
  }
}

// ---------------- GEMM1: 128x192 tiles, XCD-local A-panels, gload_lds + XOR-4 swizzle ----------------
// grid 1D 512: id = (x&7) + 8*y + 64*(x>>3)  ->  all 8 y-blocks of an A-panel share one XCD (id&7)
__global__ __launch_bounds__(256) void k_gemm_qkv(
    const short* __restrict__ A, const short* __restrict__ Bt,
    const float* __restrict__ bias,
    short* __restrict__ Qo, short* __restrict__ Ko, short* __restrict__ VTo)
{
  __shared__ __align__(16) short As[2][128*32];
  __shared__ __align__(16) short Bs[2][192*32];
  const int id  = blockIdx.x;
  const int xlo = id & 7, yy = (id>>3) & 7, xhi = id >> 6;
  const int m0  = (xhi*8 + xlo)*128, n0 = yy*192;
  const int tid = threadIdx.x;
  const int w = tid>>6, lane = tid&63, li = lane&15, lg = lane>>4;
  const int wr = (w>>1)*64, wc = (w&1)*96;

  // staging: chunk c -> lds row c>>2, lds slot c&3; global slot = (c&3)^(row&3)
  const int r0 = tid>>2;
  const int s0 = (tid&3) ^ (r0&3);       // rows +64/+128: row&3 identical -> same s0
  const int swz = li&3;                  // read-side xor

  #define G1_STAGE(buf, kt) do { \
    GLL(A  + (size_t)(m0+r0    )*DM + (kt)*32 + s0*8, &As[buf][tid*8]); \
    GLL(A  + (size_t)(m0+r0+64 )*DM + (kt)*32 + s0*8, &As[buf][(tid+256)*8]); \
    GLL(Bt + (size_t)(n0+r0    )*DM + (kt)*32 + s0*8, &Bs[buf][tid*8]); \
    GLL(Bt + (size_t)(n0+r0+64 )*DM + (kt)*32 + s0*8, &Bs[buf][(tid+256)*8]); \
    GLL(Bt + (size_t)(n0+r0+128)*DM + (kt)*32 + s0*8, &Bs[buf][(tid+512)*8]); \
  } while(0)

  const f32x4 fz = {0.f,0.f,0.f,0.f};
  f32x4 acc[4][6];
  #pragma unroll
  for (int i=0;i<4;++i)
    #pragma unroll
    for (int j=0;j<6;++j) acc[i][j] = fz;

  G1_STAGE(0, 0);
  __syncthreads();

  for (int kt=0; kt<16; ++kt){
    const short* as = As[kt&1]; const short* bs = Bs[kt&1];
    if (kt < 15) G1_STAGE((kt&1)^1, kt+1);
    short8 bfr[6];
    #pragma unroll
    for (int nf=0;nf<6;++nf)
      bfr[nf] = *(const short8*)&bs[(wc + nf*16 + li)*32 + (lg^swz)*8];
    __builtin_amdgcn_s_setprio(1);
    #pragma unroll
    for (int mf=0;mf<4;++mf){
      short8 af = *(const short8*)&as[(wr + mf*16 + li)*32 + (lg^swz)*8];
      #pragma unroll
      for (int nf=0;nf<6;++nf)
        acc[mf][nf] = MFMA16(af, bfr[nf], acc[mf][nf]);
    }
    __builtin_amdgcn_s_setprio(0);
    __syncthreads();
  }

  // epilogue: col n -> head h = n/192; within: [0,64)=Q, [64,128)=K, [128,192)=V(transposed store)
  #pragma unroll
  for (int nf=0;nf<6;++nf){
    int n = n0 + wc + nf*16 + li;
    float bv = bias[n];
    unsigned h  = (unsigned)n / 192u;
    unsigned wn = (unsigned)n % 192u;
    unsigned typ = wn >> 6, d = wn & 63u;
    #pragma unroll
    for (int mf=0;mf<4;++mf){
      #pragma unroll
      for (int j=0;j<4;++j){
        int m  = m0 + wr + mf*16 + lg*4 + j;
        int b  = m >> 10, lp = m & 1023;
        size_t bh = (size_t)(b*8 + (int)h);
        float vf = acc[mf][nf][j] + bv;
        if (typ == 0)      Qo [(bh<<16) + ((size_t)lp<<6)  + d]  = f2bf_fast(vf * 0.18033688f); // 0.125*log2e
        else if (typ == 1) Ko [(bh<<16) + ((size_t)lp<<6)  + d]  = f2bf_fast(vf);
        else               VTo[(bh<<16) + ((size_t)d<<10)  + lp] = f2bf_fast(vf);
      }
    }
  }
  #undef G1_STAGE
}

// ---------------- flash attention (proven): gload_lds K/V + XOR swizzle + XCD-local, P via LDS ----------------
__global__ __launch_bounds__(256, 2) void k_attn(
    const short* __restrict__ Q, const short* __restrict__ Kb,
    const short* __restrict__ VT, const float* __restrict__ maskP,
    short* __restrict__ O2)
{
  __shared__ __align__(16) short Ks[2][64*64];   // linear [kv][d], source-swizzled
  __shared__ __align__(16) short Vs[2][64*64];   // linear [d][kv], source-swizzled
  __shared__ __align__(16) short Ps[4][32*72];

  // XCD-local decode: all 8 q-blocks of a bh land on one XCD (hw xcd = id & 7)
  const int id  = blockIdx.x;
  const int bh  = (id & 7)*8 + ((id >> 3) & 7);
  const int q0  = (id >> 6) * 128;

  const int tid = threadIdx.x, w = tid>>6, lane = tid&63, li = lane&15, lg = lane>>4;
  const int qw = q0 + w*32;

  const short* Qp = Q  + ((size_t)bh<<16);
  const short* Kp = Kb + ((size_t)bh<<16);
  const short* Vp = VT + ((size_t)bh<<16);

  // staging chunk geometry: chunk c covers (row=c>>3, lds slot=c&7); global slot = lds slot ^ (row&7)
  const int arow0 = tid>>3;
  const int ags0  = (tid&7) ^ (arow0&7);         // chunk1: row+32 -> same (row&7), same gslot

  #define ATTN_STAGE(buf, nx) do { \
    GLL(Kp + ((size_t)((nx)+arow0   )<<6) + ags0*8, &Ks[buf][tid*8]); \
    GLL(Kp + ((size_t)((nx)+arow0+32)<<6) + ags0*8, &Ks[buf][(tid+256)*8]); \
    GLL(Vp + ((size_t)(arow0   )<<10) + (nx) + ags0*8, &Vs[buf][tid*8]); \
    GLL(Vp + ((size_t)(arow0+32)<<10) + (nx) + ags0*8, &Vs[buf][(tid+256)*8]); \
  } while(0)

  // Q as B-operand (col=q=li, k=d), two m-blocks; Q pre-scaled in GEMM1
  short8 qf[2][2];
  #pragma unroll
  for (int mb=0;mb<2;++mb)
    #pragma unroll
    for (int t=0;t<2;++t)
      qf[mb][t] = *(const short8*)(Qp + ((size_t)(qw+mb*16+li)<<6) + t*32 + lg*8);

  short8 ones8;
  #pragma unroll
  for (int e=0;e<8;++e) ones8[e] = (short)0x3f80;   // bf16 1.0

  const f32x4 fz = {0.f,0.f,0.f,0.f};
  f32x4 o[2][4], osum[2];
  #pragma unroll
  for (int mb=0;mb<2;++mb){
    osum[mb] = fz;
    #pragma unroll
    for (int df=0;df<4;++df) o[mb][df] = fz;
  }

  // mask (transposed-fragment, prescaled); register prefetch one tile ahead
  const float* mpb[2];
  #pragma unroll
  for (int mb=0;mb<2;++mb)
    mpb[mb] = maskP + ((size_t)((qw>>4)+mb)<<14) + lane*16;
  f32x4 mnx[2][4];
  #pragma unroll
  for (int mb=0;mb<2;++mb)
    #pragma unroll
    for (int nf=0;nf<4;++nf)
      mnx[mb][nf] = *(const float4_t*)(mpb[mb] + nf*4);

  ATTN_STAGE(0, 0);
  __syncthreads();     // drains vmcnt -> tile 0 staged

  const int sw = li & 7;
  short* pw = Ps[w];

  for (int kvt=0; kvt<16; ++kvt){
    const short* ks = Ks[kvt&1];
    const short* vs = Vs[kvt&1];
    if (kvt < 15) ATTN_STAGE((kvt&1)^1, (kvt+1)*64);

    // swapped QK^T: S^T[kv][q] tiles; C-init = prefetched mask regs
    f32x4 s[2][4];
    __builtin_amdgcn_s_setprio(1);
    #pragma unroll
    for (int nf=0;nf<4;++nf){
      short8 kf0 = *(const short8*)&ks[(nf*16+li)*64 + ((  lg)^sw)*8];
      short8 kf1 = *(const short8*)&ks[(nf*16+li)*64 + ((4|lg)^sw)*8];
      #pragma unroll
      for (int mb=0;mb<2;++mb){
        s[mb][nf] = MFMA16(kf0, qf[mb][0], mnx[mb][nf]);
        s[mb][nf] = MFMA16(kf1, qf[mb][1], s[mb][nf]);
      }
    }
    __builtin_amdgcn_s_setprio(0);

    // prefetch next tile's mask (consumed next iteration)
    if (kvt < 15){
      #pragma unroll
      for (int mb=0;mb<2;++mb)
        #pragma unroll
        for (int nf=0;nf<4;++nf)
          mnx[mb][nf] = *(const float4_t*)(mpb[mb] + (kvt+1)*1024 + nf*4);
    }

    // p = exp2(s) -> packed bf16 pairs -> Ps[q][kv] (b64 writes)
    #pragma unroll
    for (int mb=0;mb<2;++mb){
      #pragma unroll
      for (int nf=0;nf<4;++nf){
        float e0 = __builtin_amdgcn_exp2f(s[mb][nf][0]);
        float e1 = __builtin_amdgcn_exp2f(s[mb][nf][1]);
        float e2 = __builtin_amdgcn_exp2f(s[mb][nf][2]);
        float e3 = __builtin_amdgcn_exp2f(s[mb][nf][3]);
        unsigned p01, p23;
        asm("v_cvt_pk_bf16_f32 %0, %1, %2" : "=v"(p01) : "v"(e0), "v"(e1));
        asm("v_cvt_pk_bf16_f32 %0, %1, %2" : "=v"(p23) : "v"(e2), "v"(e3));
        u32x2 pv; pv[0]=p01; pv[1]=p23;
        *(u32x2*)&pw[(mb*16+li)*72 + nf*16 + lg*4] = pv;
      }
    }

    // PV: O[32q x 64d] += P @ V ; V-frags shared across both m-blocks
    __builtin_amdgcn_s_setprio(1);
    #pragma unroll
    for (int t=0;t<2;++t){
      short8 pf0 = *(const short8*)&pw[(   li)*72 + t*32 + lg*8];
      short8 pf1 = *(const short8*)&pw[(16+li)*72 + t*32 + lg*8];
      osum[0] = MFMA16(pf0, ones8, osum[0]);
      osum[1] = MFMA16(pf1, ones8, osum[1]);
      #pragma unroll
      for (int df=0;df<4;++df){
        short8 vf = *(const short8*)&vs[(df*16+li)*64 + (((t<<2)|lg)^sw)*8];
        o[0][df] = MFMA16(pf0, vf, o[0][df]);
        o[1][df] = MFMA16(pf1, vf, o[1][df]);
      }
    }
    __builtin_amdgcn_s_setprio(0);

    __syncthreads();   // buf[cur] reads done + buf[cur^1] DMA drained (vmcnt 0 at barrier)
  }
  #undef ATTN_STAGE

  // epilogue: O2[b, l, h*64+d] bf16
  int b = bh >> 3, h = bh & 7;
  #pragma unroll
  for (int mb=0;mb<2;++mb){
    float rl[4];
    #pragma unroll
    for (int j=0;j<4;++j) rl[j] = 1.0f / osum[mb][j];
    #pragma unroll
    for (int df=0;df<4;++df)
      #pragma unroll
      for (int j=0;j<4;++j){
        int m   = b*1024 + qw + mb*16 + lg*4 + j;
        int col = h*64 + df*16 + li;
        O2[(size_t)m*512 + col] = f2bf_fast(o[mb][df][j] * rl[j]);
      }
  }
}

// ---------------- GEMM2: 64x128 tiles, XCD-local A-panels, gload_lds + XOR-4 swizzle ----------------
// grid 1D 512: id = (x&7) + 8*y + 32*(x>>3) ; x in [0,128), y in [0,4)
__global__ __launch_bounds__(256) void k_gemm_out(
    const short* __restrict__ A, const short* __restrict__ Bt,
    const float* __restrict__ bias, float* __restrict__ out)
{
  __shared__ __align__(16) short As[2][64*32];
  __shared__ __align__(16) short Bs[2][128*32];
  const int id  = blockIdx.x;
  const int xlo = id & 7, yy = (id>>3) & 3, xhi = id >> 5;
  const int m0  = (xhi*8 + xlo)*64, n0 = yy*128;
  const int tid = threadIdx.x;
  const int w = tid>>6, lane = tid&63, li = lane&15, lg = lane>>4;
  const int wc = w*32;                  // wave covers cols [wc, wc+32), all 64 rows

  const int r0 = tid>>2;
  const int s0 = (tid&3) ^ (r0&3);
  const int swz = li&3;
  const int ra = tid>>2;                // A: 64 rows x 4 slots = 256 chunks (1 GLL)

  #define G2_STAGE(buf, kt) do { \
    GLL(A  + (size_t)(m0+ra    )*DM + (kt)*32 + s0*8, &As[buf][tid*8]); \
    GLL(Bt + (size_t)(n0+r0    )*DM + (kt)*32 + s0*8, &Bs[buf][tid*8]); \
    GLL(Bt + (size_t)(n0+r0+64 )*DM + (kt)*32 + s0*8, &Bs[buf][(tid+256)*8]); \
  } while(0)

  const f32x4 fz = {0.f,0.f,0.f,0.f};
  f32x4 acc[4][2];
  #pragma unroll
  for (int i=0;i<4;++i)
    #pragma unroll
    for (int j=0;j<2;++j) acc[i][j] = fz;

  G2_STAGE(0, 0);
  __syncthreads();

  for (int kt=0; kt<16; ++kt){
    const short* as = As[kt&1]; const short* bs = Bs[kt&1];
    if (kt < 15) G2_STAGE((kt&1)^1, kt+1);
    short8 bfr[2];
    #pragma unroll
    for (int nf=0;nf<2;++nf)
      bfr[nf] = *(const short8*)&bs[(wc + nf*16 + li)*32 + (lg^swz)*8];
    __builtin_amdgcn_s_setprio(1);
    #pragma unroll
    for (int mf=0;mf<4;++mf){
      short8 af = *(const short8*)&as[(mf*16 + li)*32 + (lg^swz)*8];
      #pragma unroll
      for (int nf=0;nf<2;++nf)
        acc[mf][nf] = MFMA16(af, bfr[nf], acc[mf][nf]);
    }
    __builtin_amdgcn_s_setprio(0);
    __syncthreads();
  }

  #pragma unroll
  for (int nf=0;nf<2;++nf){
    int n = n0 + wc + nf*16 + li;
    float bv = bias[n];
    #pragma unroll
    for (int mf=0;mf<4;++mf){
      #pragma unroll
      for (int j=0;j<4;++j){
        int m = m0 + mf*16 + lg*4 + j;
        out[(size_t)m*DM + n] = acc[mf][nf][j] + bv;
      }
    }
  }
  #undef G2_STAGE
}

extern "C" void kernel_launch(void* const* d_in, const int* in_sizes, int n_in,
                              void* d_out, int out_size, void* d_ws, size_t ws_size,
                              hipStream_t stream)
{
  (void)in_sizes; (void)n_in; (void)out_size; (void)ws_size;
  const float* x    = (const float*)d_in[0];
  const float* mask = (const float*)d_in[1];
  const float* Wqkv = (const float*)d_in[2];
  const float* bqkv = (const float*)d_in[3];
  const float* Wo   = (const float*)d_in[4];
  const float* bo   = (const float*)d_in[5];
  float* out = (float*)d_out;

  short* xb    = (short*)d_ws;                    // [8192,512] bf16
  short* WqkvT = xb    + (size_t)M_T*DM;          // [1536,512] bf16
  short* WoT   = WqkvT + (size_t)N3*DM;           // [512,512]  bf16
  short* Qb    = WoT   + (size_t)DM*DM;           // [64][1024][64] bf16 (pre-scaled)
  short* Kbf   = Qb    + (size_t)64*1024*64;      // [64][1024][64] bf16
  short* VTb   = Kbf   + (size_t)64*1024*64;      // [64][64][1024] bf16 (V^T)
  short* O2    = VTb   + (size_t)64*1024*64;      // [8192,512] bf16
  float* maskP = (float*)(O2 + (size_t)M_T*DM);   // [1024,1024] fp32 prescaled tiles (ws ~268MB, fits)

  k_prep<<<3328, 256, 0, stream>>>(x, xb, mask, maskP, Wqkv, WqkvT, Wo, WoT);
  k_gemm_qkv<<<512, 256, 0, stream>>>(xb, WqkvT, bqkv, Qb, Kbf, VTb);
  k_attn    <<<512, 256, 0, stream>>>(Qb, Kbf, VTb, maskP, O2);
  k_gemm_out<<<512, 256, 0, stream>>>(O2, WoT, bo, out);
}